// Round 8
// baseline (1073.896 us; speedup 1.0000x reference)
//
#include <hip/hip_runtime.h>
#include <hip/hip_bf16.h>

// GCNBlock: TransformerConv(32 heads, dim 8, edge_dim 64) + EdgeResidualLayer
// N=50000, E=400000, D_NODE=256, D_EDGE=64. FP32 in/out, int64 edge_index.
// Internals: bf16 MFMA (16x16x32) with fp32 accumulate.
//
// Round 8: segment-owned aggregation. k2 blocks own 32 consecutive dst nodes
// (edges dst-sorted; range from CSR end-pointers) and aggregate msg/denom in
// an LDS fp32 accumulator -> no global msg/denom, no 57.6MB memset, and the
// k3 finalize (msg/den + skip, leaky, out_x + xnb) folds into k2's epilogue.
// Carried: CSR dst-sort, MFMA everywhere, nt streaming loads/stores,
// contiguous-span k1 store phase.

#define N_NODES 50000
#define N_EDGES 400000
#define D_NODE 256
#define D_EDGE 64
#define HEADS 32
#define LRELU 0.01f
#define SEG 32          // dst nodes per k2 block

typedef __hip_bfloat16 bf16;
typedef __attribute__((ext_vector_type(8))) short short8b;          // 8 bf16
typedef __attribute__((ext_vector_type(4))) float f32x4;
typedef __attribute__((ext_vector_type(4))) unsigned short ushort4v;

__device__ __forceinline__ float bf2f(bf16 v) { return __bfloat162float(v); }
__device__ __forceinline__ bf16 f2bf(float f) { return __float2bfloat16(f); }
__device__ __forceinline__ float bfraw(unsigned short u) {
    return __uint_as_float(((unsigned int)u) << 16);
}
__device__ __forceinline__ unsigned short rawbf(float f) {
    bf16 t = f2bf(f); return *(unsigned short*)&t;
}
__device__ __forceinline__ float leaky(float v) { return v >= 0.f ? v : LRELU * v; }

// ---------------- k0: index width detection (1 wave) ----------------
__global__ void k0_detect(const int* __restrict__ ei, int* __restrict__ flags)
{
    const int lane = threadIdx.x;
    const unsigned long long mz = __ballot(ei[2 * lane + 1] == 0);
    if (lane == 0) flags[0] = (__popcll(mz) >= 48) ? 1 : 0;   // 1 => int64
}

__device__ __forceinline__ void load_edge(const int* ei, int f, int i, int& s, int& d)
{
    if (f) {
        const long long* e64 = (const long long*)ei;
        s = (int)e64[i]; d = (int)e64[N_EDGES + i];
    } else {
        s = ei[i]; d = ei[N_EDGES + i];
    }
}

// ---------------- CSR build ----------------
__global__ __launch_bounds__(256) void kcd_degree(
    const int* __restrict__ ei, const int* __restrict__ flags, int* __restrict__ deg)
{
    const int i = blockIdx.x * 256 + threadIdx.x;
    if (i >= N_EDGES) return;
    int s, d; load_edge(ei, flags[0], i, s, d);
    atomicAdd(&deg[d], 1);
}

__global__ __launch_bounds__(1024) void kcs_scan(int* __restrict__ cur)  // deg -> excl. offsets
{
    __shared__ int ps[1024];
    const int t = threadIdx.x;
    const int CH = (N_NODES + 1023) / 1024;   // 49
    const int base = t * CH;
    int sum = 0;
    for (int i = 0; i < CH; ++i) {
        const int n = base + i;
        if (n < N_NODES) sum += cur[n];
    }
    ps[t] = sum;
    __syncthreads();
    for (int off = 1; off < 1024; off <<= 1) {
        const int v = (t >= off) ? ps[t - off] : 0;
        __syncthreads();
        ps[t] += v;
        __syncthreads();
    }
    int excl = (t == 0) ? 0 : ps[t - 1];
    for (int i = 0; i < CH; ++i) {
        const int n = base + i;
        if (n < N_NODES) {
            const int d = cur[n];
            cur[n] = excl;
            excl += d;
        }
    }
}

__global__ __launch_bounds__(256) void kct_scatter(
    const int* __restrict__ ei, const int* __restrict__ flags, int* __restrict__ cursor,
    int* __restrict__ ssort, int* __restrict__ dsort, int* __restrict__ eidsort)
{
    const int i = blockIdx.x * 256 + threadIdx.x;
    if (i >= N_EDGES) return;
    int s, d; load_edge(ei, flags[0], i, s, d);
    const int pos = atomicAdd(&cursor[d], 1);
    ssort[pos] = s; dsort[pos] = d; eidsort[pos] = i;
    // after this kernel: cursor[n] == end offset of node n (inclusive scan)
}

// ---------------- kT: weight transposes (fp32 -> bf16) ----------------
__global__ __launch_bounds__(256) void kT_transpose(
    const float* __restrict__ We, const float* __restrict__ W1, const float* __restrict__ W2,
    const float* __restrict__ Wq, const float* __restrict__ Wk,
    const float* __restrict__ Wv, const float* __restrict__ Ws,
    bf16* __restrict__ WeT, bf16* __restrict__ W1Tp, bf16* __restrict__ W2T,
    bf16* __restrict__ WT4)
{
    const int gid = blockIdx.x * 256 + threadIdx.x;
    const int gsz = gridDim.x * 256;
    for (int i = gid; i < 256 * 64; i += gsz) {
        const int n = i >> 6, k = i & 63;
        WeT[i] = f2bf(We[k * 256 + n]);
    }
    for (int i = gid; i < 64 * 576; i += gsz) {
        const int n = i / 576, kp = i % 576;
        const int k = (kp < 64) ? (512 + kp) : (kp - 64);
        W1Tp[i] = f2bf(W1[k * 64 + n]);
    }
    for (int i = gid; i < 64 * 64; i += gsz) {
        const int n = i >> 6, k = i & 63;
        W2T[i] = f2bf(W2[k * 64 + n]);
    }
    for (int i = gid; i < 4 * 256 * 256; i += gsz) {
        const int m = i >> 16, rem = i & 65535;
        const int n = rem >> 8, kk = rem & 255;
        const float* W = (m == 0) ? Wq : (m == 1) ? Wk : (m == 2) ? Wv : Ws;
        WT4[i] = f2bf(W[kk * 256 + n]);
    }
}

// ---------------- k1: node linears via MFMA (nt streams, LDS store-bounce) ----------------
#define X_LD 264
__global__ __launch_bounds__(256) void k1_node_mfma(
    const float* __restrict__ x, const bf16* __restrict__ WT4,
    const float* __restrict__ bq, const float* __restrict__ bk,
    const float* __restrict__ bv, const float* __restrict__ bs,
    bf16* __restrict__ qo, bf16* __restrict__ ko, bf16* __restrict__ vo,
    bf16* __restrict__ skipb)
{
    __shared__ unsigned short xs[64 * X_LD];   // 33792 B; reused as result bounce
    const int tid = threadIdx.x;
    const int n0 = blockIdx.x * 64;
    const int e = tid >> 2, t = tid & 3;       // node e, quarter t
    const int nmine = n0 + e;

    { // stage x tile (fp32 -> bf16), nontemporal f32x4 loads
        const f32x4* src = (const f32x4*)(x + (size_t)nmine * 256 + t * 64);
        #pragma unroll
        for (int c = 0; c < 4; ++c) {
            unsigned short tmp[16];
            if (nmine < N_NODES) {
                #pragma unroll
                for (int u = 0; u < 4; ++u) {
                    const f32x4 v = __builtin_nontemporal_load(src + c * 4 + u);
                    tmp[u * 4 + 0] = rawbf(v[0]); tmp[u * 4 + 1] = rawbf(v[1]);
                    tmp[u * 4 + 2] = rawbf(v[2]); tmp[u * 4 + 3] = rawbf(v[3]);
                }
            } else {
                #pragma unroll
                for (int u = 0; u < 16; ++u) tmp[u] = 0;
            }
            *(short8b*)&xs[e * X_LD + t * 64 + c * 16]     = *(short8b*)&tmp[0];
            *(short8b*)&xs[e * X_LD + t * 64 + c * 16 + 8] = *(short8b*)&tmp[8];
        }
    }
    __syncthreads();

    const int w = tid >> 6, l = tid & 63;
    const int row = l & 15, kg = l >> 4;
    short8b af[8];
    #pragma unroll
    for (int kc = 0; kc < 8; ++kc)
        af[kc] = *(const short8b*)&xs[(w * 16 + row) * X_LD + kc * 32 + kg * 8];

    for (int m = 0; m < 4; ++m) {
        const bf16* WT = WT4 + (size_t)m * 65536;
        const float* bias = (m == 0) ? bq : (m == 1) ? bk : (m == 2) ? bv : bs;
        __syncthreads();   // prior LDS reads done
        #pragma unroll 4
        for (int ct = 0; ct < 16; ++ct) {
            const float bvv = bias[ct * 16 + row];
            f32x4 acc = {bvv, bvv, bvv, bvv};
            #pragma unroll
            for (int kc = 0; kc < 8; ++kc) {
                const short8b bfr = *(const short8b*)(WT + (size_t)(ct * 16 + row) * 256 + kc * 32 + kg * 8);
                acc = __builtin_amdgcn_mfma_f32_16x16x32_bf16(af[kc], bfr, acc, 0, 0, 0);
            }
            #pragma unroll
            for (int r = 0; r < 4; ++r)   // bounce: row = local node, col = output col
                xs[(w * 16 + kg * 4 + r) * X_LD + ct * 16 + row] = rawbf(acc[r]);
        }
        __syncthreads();
        { // store phase: per instruction, block writes ONE contiguous 4KB span
            bf16* dst = (m == 0) ? qo : (m == 1) ? ko : (m == 2) ? vo : skipb;
            #pragma unroll
            for (int u = 0; u < 8; ++u) {
                const int flat = u * 256 + tid;     // 16B unit within 32KB tile
                const int node = flat >> 5;         // 32 units (512B) per node
                const int col8 = (flat & 31) * 8;   // bf16 element offset
                if (n0 + node < N_NODES) {
                    const short8b vdat = *(const short8b*)&xs[node * X_LD + col8];
                    __builtin_nontemporal_store(vdat,
                        (short8b*)(dst + (size_t)(n0 + node) * 256 + col8));
                }
            }
        }
    }
}

// ---------------- k2: segment-owned attention (LDS accumulator, fused finalize) ----------------
#define EA_LD 72
#define EP_LD 264
__global__ __launch_bounds__(256) void k2_seg(
    const int* __restrict__ ssort, const int* __restrict__ dsort,
    const int* __restrict__ eidsort, const int* __restrict__ endptr,
    const float* __restrict__ ea, const bf16* __restrict__ WeT,
    const bf16* __restrict__ q, const bf16* __restrict__ k, const bf16* __restrict__ v,
    const bf16* __restrict__ skipb, float* __restrict__ out_x, bf16* __restrict__ xnb)
{
    __shared__ float acc_s[SEG * 256];            // 32 KB msg accumulator
    __shared__ float den_s[SEG * HEADS];          // 4 KB
    __shared__ unsigned short ea_s[64 * EA_LD];   // 9 KB
    __shared__ unsigned short ep_s[64 * EP_LD];   // 33 KB   (total 78.4 KB -> 2 blk/CU)
    const int tid = threadIdx.x;
    const int n0 = blockIdx.x * SEG;

    for (int i = tid; i < SEG * 256; i += 256) acc_s[i] = 0.f;
    for (int i = tid; i < SEG * HEADS; i += 256) den_s[i] = 0.f;

    const int start = (n0 == 0) ? 0 : endptr[n0 - 1];
    const int nlast = (n0 + SEG <= N_NODES) ? (n0 + SEG - 1) : (N_NODES - 1);
    const int end   = endptr[nlast];
    __syncthreads();

    const int w = tid >> 6, l = tid & 63;
    const int row = l & 15, kg = l >> 4;
    const float scale = 0.35355339059327373f;   // 1/sqrt(8)

    for (int cbase = start; cbase < end; cbase += 64) {
        { // stage ea chunk (fp32 -> bf16), nt loads; zero pad edges
            const int e = tid >> 2, t = tid & 3;
            const int sl = cbase + e;
            unsigned short tmp[16];
            if (sl < end) {
                const int eg = eidsort[sl];
                const f32x4* src = (const f32x4*)(ea + (size_t)eg * 64 + t * 16);
                #pragma unroll
                for (int u = 0; u < 4; ++u) {
                    const f32x4 vv = __builtin_nontemporal_load(src + u);
                    tmp[u * 4 + 0] = rawbf(vv[0]); tmp[u * 4 + 1] = rawbf(vv[1]);
                    tmp[u * 4 + 2] = rawbf(vv[2]); tmp[u * 4 + 3] = rawbf(vv[3]);
                }
            } else {
                #pragma unroll
                for (int u = 0; u < 16; ++u) tmp[u] = 0;
            }
            *(short8b*)&ea_s[e * EA_LD + t * 16]     = *(short8b*)&tmp[0];
            *(short8b*)&ea_s[e * EA_LD + t * 16 + 8] = *(short8b*)&tmp[8];
        }
        __syncthreads();

        { // eproj MFMA: wave w owns chunk edges w*16..+15
            const short8b af0 = *(const short8b*)&ea_s[(w * 16 + row) * EA_LD + kg * 8];
            const short8b af1 = *(const short8b*)&ea_s[(w * 16 + row) * EA_LD + 32 + kg * 8];
            #pragma unroll 4
            for (int ct = 0; ct < 16; ++ct) {
                f32x4 acc = {0.f, 0.f, 0.f, 0.f};
                const short8b b0 = *(const short8b*)(WeT + (size_t)(ct * 16 + row) * 64 + kg * 8);
                const short8b b1 = *(const short8b*)(WeT + (size_t)(ct * 16 + row) * 64 + 32 + kg * 8);
                acc = __builtin_amdgcn_mfma_f32_16x16x32_bf16(af0, b0, acc, 0, 0, 0);
                acc = __builtin_amdgcn_mfma_f32_16x16x32_bf16(af1, b1, acc, 0, 0, 0);
                #pragma unroll
                for (int r = 0; r < 4; ++r)
                    ep_s[(w * 16 + kg * 4 + r) * EP_LD + ct * 16 + row] = rawbf(acc[r]);
            }
        }
        __syncthreads();

        // attention: wave w covers chunk edges [w*16, w*16+cnt)
        const int ebase = cbase + w * 16;
        const int cnt = min(16, end - ebase);
        if (cnt > 0) {
            int sv = 0;
            if (l < 16) { if (l < cnt) sv = ssort[ebase + l]; }
            else if (l < 32) { if (l - 16 < cnt) sv = dsort[ebase + (l - 16)]; }

            float macc[4] = {0.f, 0.f, 0.f, 0.f};
            float dacc = 0.f;
            int dprev = -1;
            ushort4v qv = {0, 0, 0, 0};

            for (int i = 0; i < cnt; ++i) {
                const int s = __shfl(sv, i);
                const int d = __shfl(sv, 16 + i);
                if (d != dprev) {                  // wave-uniform
                    if (dprev >= 0) {
                        const int ld = dprev - n0;
                        #pragma unroll
                        for (int t = 0; t < 4; ++t)
                            atomicAdd(&acc_s[ld * 256 + l * 4 + t], macc[t]);
                        if ((l & 1) == 0)
                            atomicAdd(&den_s[ld * HEADS + (l >> 1)], dacc);
                        macc[0] = macc[1] = macc[2] = macc[3] = 0.f;
                        dacc = 0.f;
                    }
                    qv = *(const ushort4v*)(q + (size_t)d * 256 + l * 4);
                    dprev = d;
                }
                const ushort4v kv = *(const ushort4v*)(k + (size_t)s * 256 + l * 4);
                const ushort4v vv = *(const ushort4v*)(v + (size_t)s * 256 + l * 4);
                const ushort4v ep = *(const ushort4v*)&ep_s[(w * 16 + i) * EP_LD + l * 4];
                float p = 0.f, m4[4];
                #pragma unroll
                for (int t = 0; t < 4; ++t) {
                    const float epf = bfraw(ep[t]);
                    p = fmaf(bfraw(qv[t]), bfraw(kv[t]) + epf, p);
                    m4[t] = bfraw(vv[t]) + epf;
                }
                p += __shfl_xor(p, 1);             // head = l>>1 (2 lanes/head)
                const float ex = __expf(p * scale);
                #pragma unroll
                for (int t = 0; t < 4; ++t) macc[t] = fmaf(m4[t], ex, macc[t]);
                dacc += ex;
            }
            if (dprev >= 0) {
                const int ld = dprev - n0;
                #pragma unroll
                for (int t = 0; t < 4; ++t)
                    atomicAdd(&acc_s[ld * 256 + l * 4 + t], macc[t]);
                if ((l & 1) == 0)
                    atomicAdd(&den_s[ld * HEADS + (l >> 1)], dacc);
            }
        }
        __syncthreads();   // all reads of ea_s/ep_s done before next chunk restages
    }

    // finalize: x_new = leaky(acc/den + skip) -> out_x fp32 + xnb bf16
    #pragma unroll
    for (int u = 0; u < 8; ++u) {
        const int flat4 = u * 256 + tid;        // f32x4 unit; 64 units per node
        const int node = flat4 >> 6;
        const int ch4 = flat4 & 63;             // f32x4 index within row
        const int n = n0 + node;
        if (n < N_NODES) {
            const float den = den_s[node * HEADS + (ch4 >> 1)] + 1e-16f;
            const f32x4 mv = *(const f32x4*)&acc_s[node * 256 + ch4 * 4];
            const ushort4v sk = *(const ushort4v*)(skipb + (size_t)n * 256 + ch4 * 4);
            f32x4 o; ushort4v ob;
            #pragma unroll
            for (int t = 0; t < 4; ++t) {
                const float xn = leaky(mv[t] / den + bfraw(sk[t]));
                o[t] = xn; ob[t] = rawbf(xn);
            }
            __builtin_nontemporal_store(o, (f32x4*)(out_x + (size_t)n * 256 + ch4 * 4));
            *(ushort4v*)(xnb + (size_t)n * 256 + ch4 * 4) = ob;
        }
    }
}

// ---------------- k4: edge MLP via MFMA (sorted tiles) ----------------
#define H_LD 584
__global__ __launch_bounds__(256) void k4_edge_mlp(
    const int* __restrict__ ssort, const int* __restrict__ dsort,
    const int* __restrict__ eidsort,
    const bf16* __restrict__ xnb, const float* __restrict__ ea,
    const bf16* __restrict__ W1Tp, const float* __restrict__ b1,
    const bf16* __restrict__ W2T, const float* __restrict__ b2,
    float* __restrict__ out_e)
{
    __shared__ unsigned short h_s[64 * H_LD];   // 74752 B
    const int tid = threadIdx.x;
    const int e0 = blockIdx.x * 64;

    { // stage h = [ea | x_s | x_d]: 4 threads/edge
        const int e = tid >> 2, t = tid & 3;
        const int sl = e0 + e;
        const int eg = eidsort[sl];
        const int s = ssort[sl], d = dsort[sl];
        const f32x4* pe = (const f32x4*)(ea + (size_t)eg * 64 + t * 16);
        unsigned short tmp[16];
        #pragma unroll
        for (int u = 0; u < 4; ++u) {
            const f32x4 vv = __builtin_nontemporal_load(pe + u);
            tmp[u * 4 + 0] = rawbf(vv[0]); tmp[u * 4 + 1] = rawbf(vv[1]);
            tmp[u * 4 + 2] = rawbf(vv[2]); tmp[u * 4 + 3] = rawbf(vv[3]);
        }
        *(short8b*)&h_s[e * H_LD + t * 16]     = *(short8b*)&tmp[0];
        *(short8b*)&h_s[e * H_LD + t * 16 + 8] = *(short8b*)&tmp[8];
        const short8b* ps = (const short8b*)(xnb + (size_t)s * 256 + t * 64);
        const short8b* pd = (const short8b*)(xnb + (size_t)d * 256 + t * 64);
        #pragma unroll
        for (int u = 0; u < 8; ++u) {
            *(short8b*)&h_s[e * H_LD + 64  + t * 64 + u * 8] = ps[u];
            *(short8b*)&h_s[e * H_LD + 320 + t * 64 + u * 8] = pd[u];
        }
    }
    __syncthreads();

    const int w = tid >> 6, l = tid & 63;
    const int row = l & 15, kg = l >> 4;

    // GEMM1: [16 x 576] @ W1 -> [16 x 64]
    f32x4 acc[4];
    #pragma unroll
    for (int ct = 0; ct < 4; ++ct) {
        const float bvv = b1[ct * 16 + row];
        acc[ct] = (f32x4){bvv, bvv, bvv, bvv};
    }
    for (int kc = 0; kc < 18; ++kc) {
        const short8b af = *(const short8b*)&h_s[(w * 16 + row) * H_LD + kc * 32 + kg * 8];
        #pragma unroll
        for (int ct = 0; ct < 4; ++ct) {
            const short8b bfr = *(const short8b*)(W1Tp + (size_t)(ct * 16 + row) * 576 + kc * 32 + kg * 8);
            acc[ct] = __builtin_amdgcn_mfma_f32_16x16x32_bf16(af, bfr, acc[ct], 0, 0, 0);
        }
    }
    float ear[4][4];
    #pragma unroll
    for (int ct = 0; ct < 4; ++ct)
        #pragma unroll
        for (int r = 0; r < 4; ++r)
            ear[ct][r] = bfraw(h_s[(w * 16 + kg * 4 + r) * H_LD + ct * 16 + row]);
    __syncthreads();   // all GEMM1 LDS reads done before h2 overwrites h

    unsigned short* h2 = &h_s[w * 1152];
    #pragma unroll
    for (int ct = 0; ct < 4; ++ct)
        #pragma unroll
        for (int r = 0; r < 4; ++r)
            h2[(kg * 4 + r) * 72 + ct * 16 + row] = rawbf(leaky(acc[ct][r]));
    // same-wave LDS ops are in-order: no barrier before same-wave reads

    // GEMM2: [16 x 64] @ W2 -> [16 x 64]
    f32x4 a2[4];
    #pragma unroll
    for (int ct = 0; ct < 4; ++ct) {
        const float bvv = b2[ct * 16 + row];
        a2[ct] = (f32x4){bvv, bvv, bvv, bvv};
    }
    #pragma unroll
    for (int kc = 0; kc < 2; ++kc) {
        const short8b af = *(const short8b*)&h2[row * 72 + kc * 32 + kg * 8];
        #pragma unroll
        for (int ct = 0; ct < 4; ++ct) {
            const short8b bfr = *(const short8b*)(W2T + (size_t)(ct * 16 + row) * 64 + kc * 32 + kg * 8);
            a2[ct] = __builtin_amdgcn_mfma_f32_16x16x32_bf16(af, bfr, a2[ct], 0, 0, 0);
        }
    }
    #pragma unroll
    for (int ct = 0; ct < 4; ++ct)
        #pragma unroll
        for (int r = 0; r < 4; ++r) {
            const int eg = eidsort[e0 + w * 16 + kg * 4 + r];
            __builtin_nontemporal_store(leaky(ear[ct][r] + a2[ct][r]),
                                        out_e + (size_t)eg * 64 + ct * 16 + row);
        }
}

extern "C" void kernel_launch(void* const* d_in, const int* in_sizes, int n_in,
                              void* d_out, int out_size, void* d_ws, size_t ws_size,
                              hipStream_t stream)
{
    const float* x  = (const float*)d_in[0];
    const int*   ei = (const int*)d_in[1];
    const float* ea = (const float*)d_in[2];
    const float* Wq = (const float*)d_in[3];
    const float* bq = (const float*)d_in[4];
    const float* Wk = (const float*)d_in[5];
    const float* bk = (const float*)d_in[6];
    const float* Wv = (const float*)d_in[7];
    const float* bv = (const float*)d_in[8];
    const float* We = (const float*)d_in[9];
    const float* Ws = (const float*)d_in[10];
    const float* bs = (const float*)d_in[11];
    const float* W1 = (const float*)d_in[12];
    const float* b1 = (const float*)d_in[13];
    const float* W2 = (const float*)d_in[14];
    const float* b2 = (const float*)d_in[15];

    char* ws = (char*)d_ws;
    int*   flags  = (int*)ws;                       // 4 KB
    int*   ssort  = (int*)(ws + 4096);
    int*   dsort  = (int*)(ws + 1604096);
    int*   eids   = (int*)(ws + 3204096);
    int*   cursor = (int*)(ws + 4804096);           // becomes end-pointers after kct
    bf16*  WeT    = (bf16*)(ws + 5004096);
    bf16*  W1Tp   = (bf16*)(ws + 5036864);
    bf16*  W2T    = (bf16*)(ws + 5110592);
    bf16*  WT4    = (bf16*)(ws + 5118784);
    bf16*  qb     = (bf16*)(ws + 5643072);          // q (live through k2_seg)
    bf16*  kb     = (bf16*)(ws + 31243072);
    bf16*  vb     = (bf16*)(ws + 56843072);
    bf16*  xnb    = (bf16*)(ws + 82443072);         // x_new bf16 (freed msg region)

    float* out_x = (float*)d_out;
    float* out_e = out_x + (size_t)N_NODES * D_NODE;
    bf16*  skipb = (bf16*)out_e;   // bf16 skip staged in edge-out region

    hipMemsetAsync(cursor, 0, N_NODES * 4, stream);       // degree counters only

    k0_detect<<<1, 64, 0, stream>>>(ei, flags);
    kcd_degree<<<(N_EDGES + 255) / 256, 256, 0, stream>>>(ei, flags, cursor);
    kcs_scan<<<1, 1024, 0, stream>>>(cursor);
    kct_scatter<<<(N_EDGES + 255) / 256, 256, 0, stream>>>(ei, flags, cursor, ssort, dsort, eids);

    kT_transpose<<<64, 256, 0, stream>>>(We, W1, W2, Wq, Wk, Wv, Ws, WeT, W1Tp, W2T, WT4);

    k1_node_mfma<<<(N_NODES + 63) / 64, 256, 0, stream>>>(
        x, WT4, bq, bk, bv, bs, qb, kb, vb, skipb);

    k2_seg<<<(N_NODES + SEG - 1) / SEG, 256, 0, stream>>>(
        ssort, dsort, eids, cursor, ea, WeT, qb, kb, vb, skipb, out_x, xnb);

    k4_edge_mlp<<<N_EDGES / 64, 256, 0, stream>>>(
        ssort, dsort, eids, xnb, ea, W1Tp, b1, W2T, b2, out_e);
}

// Round 9
// 949.310 us; speedup vs baseline: 1.1312x; 1.1312x over previous
//
#include <hip/hip_runtime.h>
#include <hip/hip_bf16.h>

// GCNBlock: TransformerConv(32 heads, dim 8, edge_dim 64) + EdgeResidualLayer
// N=50000, E=400000, D_NODE=256, D_EDGE=64. FP32 in/out, int64 edge_index.
// Internals: bf16 MFMA (16x16x32) with fp32 accumulate.
//
// Round 9: barrier-free gather pipelines.
//  k2: ea_s stage deleted -- each lane loads its MFMA A-fragment directly
//      from global ea (fp32->bf16 in regs). ep_s is wave-private (wave w
//      writes/reads only rows 16w..16w+15), so the edge loop has NO barriers;
//      waves free-run, LDS atomics merge runs, single barrier before the
//      fused finalize. SEG 32->16: LDS 51KB -> 3 blk/CU.
//  k4: h_s staging deleted -- A-fragments for [ea|x_s|x_d] gathered per-lane
//      from global; only the 9.2KB wave-private h2 bounce remains -> 16
//      waves/CU and no staging barrier.
// Carried: CSR dst-sort, MFMA everywhere, nt streams, k1 store-span fix.

#define N_NODES 50000
#define N_EDGES 400000
#define D_NODE 256
#define D_EDGE 64
#define HEADS 32
#define LRELU 0.01f
#define SEG 16          // dst nodes per k2 block

typedef __hip_bfloat16 bf16;
typedef __attribute__((ext_vector_type(8))) short short8b;          // 8 bf16
typedef __attribute__((ext_vector_type(4))) float f32x4;
typedef __attribute__((ext_vector_type(4))) unsigned short ushort4v;

__device__ __forceinline__ float bf2f(bf16 v) { return __bfloat162float(v); }
__device__ __forceinline__ bf16 f2bf(float f) { return __float2bfloat16(f); }
__device__ __forceinline__ float bfraw(unsigned short u) {
    return __uint_as_float(((unsigned int)u) << 16);
}
__device__ __forceinline__ unsigned short rawbf(float f) {
    bf16 t = f2bf(f); return *(unsigned short*)&t;
}
__device__ __forceinline__ float leaky(float v) { return v >= 0.f ? v : LRELU * v; }
__device__ __forceinline__ short8b pack8(const f32x4 a, const f32x4 b) {
    short8b r;
    r[0] = (short)rawbf(a[0]); r[1] = (short)rawbf(a[1]);
    r[2] = (short)rawbf(a[2]); r[3] = (short)rawbf(a[3]);
    r[4] = (short)rawbf(b[0]); r[5] = (short)rawbf(b[1]);
    r[6] = (short)rawbf(b[2]); r[7] = (short)rawbf(b[3]);
    return r;
}

// ---------------- k0: index width detection (1 wave) ----------------
__global__ void k0_detect(const int* __restrict__ ei, int* __restrict__ flags)
{
    const int lane = threadIdx.x;
    const unsigned long long mz = __ballot(ei[2 * lane + 1] == 0);
    if (lane == 0) flags[0] = (__popcll(mz) >= 48) ? 1 : 0;   // 1 => int64
}

__device__ __forceinline__ void load_edge(const int* ei, int f, int i, int& s, int& d)
{
    if (f) {
        const long long* e64 = (const long long*)ei;
        s = (int)e64[i]; d = (int)e64[N_EDGES + i];
    } else {
        s = ei[i]; d = ei[N_EDGES + i];
    }
}

// ---------------- CSR build ----------------
__global__ __launch_bounds__(256) void kcd_degree(
    const int* __restrict__ ei, const int* __restrict__ flags, int* __restrict__ deg)
{
    const int i = blockIdx.x * 256 + threadIdx.x;
    if (i >= N_EDGES) return;
    int s, d; load_edge(ei, flags[0], i, s, d);
    atomicAdd(&deg[d], 1);
}

__global__ __launch_bounds__(1024) void kcs_scan(int* __restrict__ cur)  // deg -> excl. offsets
{
    __shared__ int ps[1024];
    const int t = threadIdx.x;
    const int CH = (N_NODES + 1023) / 1024;   // 49
    const int base = t * CH;
    int sum = 0;
    for (int i = 0; i < CH; ++i) {
        const int n = base + i;
        if (n < N_NODES) sum += cur[n];
    }
    ps[t] = sum;
    __syncthreads();
    for (int off = 1; off < 1024; off <<= 1) {
        const int v = (t >= off) ? ps[t - off] : 0;
        __syncthreads();
        ps[t] += v;
        __syncthreads();
    }
    int excl = (t == 0) ? 0 : ps[t - 1];
    for (int i = 0; i < CH; ++i) {
        const int n = base + i;
        if (n < N_NODES) {
            const int d = cur[n];
            cur[n] = excl;
            excl += d;
        }
    }
}

__global__ __launch_bounds__(256) void kct_scatter(
    const int* __restrict__ ei, const int* __restrict__ flags, int* __restrict__ cursor,
    int* __restrict__ ssort, int* __restrict__ dsort, int* __restrict__ eidsort)
{
    const int i = blockIdx.x * 256 + threadIdx.x;
    if (i >= N_EDGES) return;
    int s, d; load_edge(ei, flags[0], i, s, d);
    const int pos = atomicAdd(&cursor[d], 1);
    ssort[pos] = s; dsort[pos] = d; eidsort[pos] = i;
    // after this kernel: cursor[n] == end offset of node n (inclusive)
}

// ---------------- kT: weight transposes (fp32 -> bf16) ----------------
__global__ __launch_bounds__(256) void kT_transpose(
    const float* __restrict__ We, const float* __restrict__ W1, const float* __restrict__ W2,
    const float* __restrict__ Wq, const float* __restrict__ Wk,
    const float* __restrict__ Wv, const float* __restrict__ Ws,
    bf16* __restrict__ WeT, bf16* __restrict__ W1Tp, bf16* __restrict__ W2T,
    bf16* __restrict__ WT4)
{
    const int gid = blockIdx.x * 256 + threadIdx.x;
    const int gsz = gridDim.x * 256;
    for (int i = gid; i < 256 * 64; i += gsz) {
        const int n = i >> 6, k = i & 63;
        WeT[i] = f2bf(We[k * 256 + n]);
    }
    for (int i = gid; i < 64 * 576; i += gsz) {
        const int n = i / 576, kp = i % 576;
        const int k = (kp < 64) ? (512 + kp) : (kp - 64);
        W1Tp[i] = f2bf(W1[k * 64 + n]);
    }
    for (int i = gid; i < 64 * 64; i += gsz) {
        const int n = i >> 6, k = i & 63;
        W2T[i] = f2bf(W2[k * 64 + n]);
    }
    for (int i = gid; i < 4 * 256 * 256; i += gsz) {
        const int m = i >> 16, rem = i & 65535;
        const int n = rem >> 8, kk = rem & 255;
        const float* W = (m == 0) ? Wq : (m == 1) ? Wk : (m == 2) ? Wv : Ws;
        WT4[i] = f2bf(W[kk * 256 + n]);
    }
}

// ---------------- k1: node linears via MFMA (nt streams, LDS store-bounce) ----------------
#define X_LD 264
__global__ __launch_bounds__(256) void k1_node_mfma(
    const float* __restrict__ x, const bf16* __restrict__ WT4,
    const float* __restrict__ bq, const float* __restrict__ bk,
    const float* __restrict__ bv, const float* __restrict__ bs,
    bf16* __restrict__ qo, bf16* __restrict__ ko, bf16* __restrict__ vo,
    bf16* __restrict__ skipb)
{
    __shared__ unsigned short xs[64 * X_LD];   // 33792 B; reused as result bounce
    const int tid = threadIdx.x;
    const int n0 = blockIdx.x * 64;
    const int e = tid >> 2, t = tid & 3;       // node e, quarter t
    const int nmine = n0 + e;

    { // stage x tile (fp32 -> bf16), nontemporal f32x4 loads
        const f32x4* src = (const f32x4*)(x + (size_t)nmine * 256 + t * 64);
        #pragma unroll
        for (int c = 0; c < 4; ++c) {
            unsigned short tmp[16];
            if (nmine < N_NODES) {
                #pragma unroll
                for (int u = 0; u < 4; ++u) {
                    const f32x4 v = __builtin_nontemporal_load(src + c * 4 + u);
                    tmp[u * 4 + 0] = rawbf(v[0]); tmp[u * 4 + 1] = rawbf(v[1]);
                    tmp[u * 4 + 2] = rawbf(v[2]); tmp[u * 4 + 3] = rawbf(v[3]);
                }
            } else {
                #pragma unroll
                for (int u = 0; u < 16; ++u) tmp[u] = 0;
            }
            *(short8b*)&xs[e * X_LD + t * 64 + c * 16]     = *(short8b*)&tmp[0];
            *(short8b*)&xs[e * X_LD + t * 64 + c * 16 + 8] = *(short8b*)&tmp[8];
        }
    }
    __syncthreads();

    const int w = tid >> 6, l = tid & 63;
    const int row = l & 15, kg = l >> 4;
    short8b af[8];
    #pragma unroll
    for (int kc = 0; kc < 8; ++kc)
        af[kc] = *(const short8b*)&xs[(w * 16 + row) * X_LD + kc * 32 + kg * 8];

    for (int m = 0; m < 4; ++m) {
        const bf16* WT = WT4 + (size_t)m * 65536;
        const float* bias = (m == 0) ? bq : (m == 1) ? bk : (m == 2) ? bv : bs;
        __syncthreads();   // prior LDS reads done
        #pragma unroll 4
        for (int ct = 0; ct < 16; ++ct) {
            const float bvv = bias[ct * 16 + row];
            f32x4 acc = {bvv, bvv, bvv, bvv};
            #pragma unroll
            for (int kc = 0; kc < 8; ++kc) {
                const short8b bfr = *(const short8b*)(WT + (size_t)(ct * 16 + row) * 256 + kc * 32 + kg * 8);
                acc = __builtin_amdgcn_mfma_f32_16x16x32_bf16(af[kc], bfr, acc, 0, 0, 0);
            }
            #pragma unroll
            for (int r = 0; r < 4; ++r)   // bounce: row = local node, col = output col
                xs[(w * 16 + kg * 4 + r) * X_LD + ct * 16 + row] = rawbf(acc[r]);
        }
        __syncthreads();
        { // store phase: per instruction, block writes ONE contiguous 4KB span
            bf16* dst = (m == 0) ? qo : (m == 1) ? ko : (m == 2) ? vo : skipb;
            #pragma unroll
            for (int u = 0; u < 8; ++u) {
                const int flat = u * 256 + tid;     // 16B unit within 32KB tile
                const int node = flat >> 5;         // 32 units (512B) per node
                const int col8 = (flat & 31) * 8;   // bf16 element offset
                if (n0 + node < N_NODES) {
                    const short8b vdat = *(const short8b*)&xs[node * X_LD + col8];
                    __builtin_nontemporal_store(vdat,
                        (short8b*)(dst + (size_t)(n0 + node) * 256 + col8));
                }
            }
        }
    }
}

// ---------------- k2: barrier-free segment attention ----------------
#define EP_LD 264
__global__ __launch_bounds__(256) void k2_seg(
    const int* __restrict__ ssort, const int* __restrict__ dsort,
    const int* __restrict__ eidsort, const int* __restrict__ endptr,
    const float* __restrict__ ea, const bf16* __restrict__ WeT,
    const bf16* __restrict__ q, const bf16* __restrict__ k, const bf16* __restrict__ v,
    const bf16* __restrict__ skipb, float* __restrict__ out_x, bf16* __restrict__ xnb)
{
    __shared__ float acc_s[SEG * 256];            // 16 KB msg accumulator
    __shared__ float den_s[SEG * HEADS];          // 2 KB
    __shared__ unsigned short ep_s[64 * EP_LD];   // 33 KB (wave-private rows)
    const int tid = threadIdx.x;
    const int n0 = blockIdx.x * SEG;

    #pragma unroll
    for (int i = 0; i < SEG; ++i) acc_s[i * 256 + tid] = 0.f;
    if (tid < SEG * HEADS - 256) den_s[256 + tid] = 0.f;
    den_s[tid] = 0.f;

    const int start = (n0 == 0) ? 0 : endptr[n0 - 1];
    const int end   = endptr[n0 + SEG - 1];
    __syncthreads();

    const int w = tid >> 6, l = tid & 63;
    const int row = l & 15, kg = l >> 4;
    const float scale = 0.35355339059327373f;   // 1/sqrt(8)

    // each wave free-runs its own 16-edge slices; no barriers in this loop
    for (int sbase = start + w * 16; sbase < end; sbase += 64) {
        const int cnt = min(16, end - sbase);

        // --- A fragments direct from global ea (fp32 -> bf16 in regs) ---
        short8b af0 = {0, 0, 0, 0, 0, 0, 0, 0}, af1 = af0;
        if (row < cnt) {
            const int eg = eidsort[sbase + row];
            const float* pb = ea + (size_t)eg * 64 + kg * 8;
            const f32x4 a0 = __builtin_nontemporal_load((const f32x4*)pb);
            const f32x4 a1 = __builtin_nontemporal_load((const f32x4*)(pb + 4));
            const f32x4 b0 = __builtin_nontemporal_load((const f32x4*)(pb + 32));
            const f32x4 b1 = __builtin_nontemporal_load((const f32x4*)(pb + 36));
            af0 = pack8(a0, a1); af1 = pack8(b0, b1);
        }
        // --- eproj MFMA into wave-private ep rows ---
        #pragma unroll 4
        for (int ct = 0; ct < 16; ++ct) {
            f32x4 acc = {0.f, 0.f, 0.f, 0.f};
            const short8b b0 = *(const short8b*)(WeT + (size_t)(ct * 16 + row) * 64 + kg * 8);
            const short8b b1 = *(const short8b*)(WeT + (size_t)(ct * 16 + row) * 64 + 32 + kg * 8);
            acc = __builtin_amdgcn_mfma_f32_16x16x32_bf16(af0, b0, acc, 0, 0, 0);
            acc = __builtin_amdgcn_mfma_f32_16x16x32_bf16(af1, b1, acc, 0, 0, 0);
            #pragma unroll
            for (int r = 0; r < 4; ++r)
                ep_s[(w * 16 + kg * 4 + r) * EP_LD + ct * 16 + row] = rawbf(acc[r]);
        }
        // same-wave LDS write->read is in-order: no barrier needed

        // --- attention over this wave's cnt edges (run-compressed) ---
        int sv = 0;
        if (l < 16)      { if (l < cnt)      sv = ssort[sbase + l]; }
        else if (l < 32) { if (l - 16 < cnt) sv = dsort[sbase + (l - 16)]; }

        float macc[4] = {0.f, 0.f, 0.f, 0.f};
        float dacc = 0.f;
        int dprev = -1;
        ushort4v qv = {0, 0, 0, 0};

        for (int i = 0; i < cnt; ++i) {
            const int s = __shfl(sv, i);
            const int d = __shfl(sv, 16 + i);
            if (d != dprev) {                  // wave-uniform
                if (dprev >= 0) {
                    const int ld = dprev - n0;
                    #pragma unroll
                    for (int t = 0; t < 4; ++t)
                        atomicAdd(&acc_s[ld * 256 + l * 4 + t], macc[t]);
                    if ((l & 1) == 0)
                        atomicAdd(&den_s[ld * HEADS + (l >> 1)], dacc);
                    macc[0] = macc[1] = macc[2] = macc[3] = 0.f;
                    dacc = 0.f;
                }
                qv = *(const ushort4v*)(q + (size_t)d * 256 + l * 4);
                dprev = d;
            }
            const ushort4v kv = *(const ushort4v*)(k + (size_t)s * 256 + l * 4);
            const ushort4v vv = *(const ushort4v*)(v + (size_t)s * 256 + l * 4);
            const ushort4v ep = *(const ushort4v*)&ep_s[(w * 16 + i) * EP_LD + l * 4];
            float p = 0.f, m4[4];
            #pragma unroll
            for (int t = 0; t < 4; ++t) {
                const float epf = bfraw(ep[t]);
                p = fmaf(bfraw(qv[t]), bfraw(kv[t]) + epf, p);
                m4[t] = bfraw(vv[t]) + epf;
            }
            p += __shfl_xor(p, 1);             // head = l>>1 (2 lanes/head)
            const float ex = __expf(p * scale);
            #pragma unroll
            for (int t = 0; t < 4; ++t) macc[t] = fmaf(m4[t], ex, macc[t]);
            dacc += ex;
        }
        if (dprev >= 0) {
            const int ld = dprev - n0;
            #pragma unroll
            for (int t = 0; t < 4; ++t)
                atomicAdd(&acc_s[ld * 256 + l * 4 + t], macc[t]);
            if ((l & 1) == 0)
                atomicAdd(&den_s[ld * HEADS + (l >> 1)], dacc);
        }
    }
    __syncthreads();   // single barrier: all waves' aggregation done

    // finalize: x_new = leaky(acc/den + skip) -> out_x fp32 + xnb bf16
    #pragma unroll
    for (int u = 0; u < 4; ++u) {
        const int flat4 = u * 256 + tid;        // f32x4 unit; 64 per node
        const int node = flat4 >> 6;
        const int ch4 = flat4 & 63;
        const int n = n0 + node;
        const float den = den_s[node * HEADS + (ch4 >> 1)] + 1e-16f;
        const f32x4 mv = *(const f32x4*)&acc_s[node * 256 + ch4 * 4];
        const ushort4v sk = *(const ushort4v*)(skipb + (size_t)n * 256 + ch4 * 4);
        f32x4 o; ushort4v ob;
        #pragma unroll
        for (int t = 0; t < 4; ++t) {
            const float xn = leaky(mv[t] / den + bfraw(sk[t]));
            o[t] = xn; ob[t] = rawbf(xn);
        }
        __builtin_nontemporal_store(o, (f32x4*)(out_x + (size_t)n * 256 + ch4 * 4));
        *(ushort4v*)(xnb + (size_t)n * 256 + ch4 * 4) = ob;
    }
}

// ---------------- k4: edge MLP, direct-gather A-fragments ----------------
__global__ __launch_bounds__(256) void k4_edge_mlp(
    const int* __restrict__ ssort, const int* __restrict__ dsort,
    const int* __restrict__ eidsort,
    const bf16* __restrict__ xnb, const float* __restrict__ ea,
    const bf16* __restrict__ W1Tp, const float* __restrict__ b1,
    const bf16* __restrict__ W2T, const float* __restrict__ b2,
    float* __restrict__ out_e)
{
    __shared__ unsigned short h2_s[4][16 * 72];   // 9216 B, wave-private
    const int tid = threadIdx.x;
    const int w = tid >> 6, l = tid & 63;
    const int row = l & 15, kg = l >> 4;
    const int e0 = blockIdx.x * 64;
    const int sl = e0 + w * 16 + row;            // this lane's A-row edge
    const int eg = eidsort[sl];
    const int s  = ssort[sl];
    const int d  = dsort[sl];

    // GEMM1: [16 x 576] @ W1 -> [16 x 64]; h row = [ea(64)|x_s(256)|x_d(256)]
    f32x4 acc[4];
    #pragma unroll
    for (int ct = 0; ct < 4; ++ct) {
        const float bvv = b1[ct * 16 + row];
        acc[ct] = (f32x4){bvv, bvv, bvv, bvv};
    }
    #pragma unroll
    for (int kc = 0; kc < 2; ++kc) {   // ea channels (fp32 -> bf16)
        const float* pb = ea + (size_t)eg * 64 + kc * 32 + kg * 8;
        const f32x4 a0 = *(const f32x4*)pb;
        const f32x4 a1 = *(const f32x4*)(pb + 4);
        const short8b af = pack8(a0, a1);
        #pragma unroll
        for (int ct = 0; ct < 4; ++ct) {
            const short8b bfr = *(const short8b*)(W1Tp + (size_t)(ct * 16 + row) * 576 + kc * 32 + kg * 8);
            acc[ct] = __builtin_amdgcn_mfma_f32_16x16x32_bf16(af, bfr, acc[ct], 0, 0, 0);
        }
    }
    #pragma unroll
    for (int kc = 2; kc < 10; ++kc) {  // x_src channels
        const short8b af = *(const short8b*)(xnb + (size_t)s * 256 + (kc - 2) * 32 + kg * 8);
        #pragma unroll
        for (int ct = 0; ct < 4; ++ct) {
            const short8b bfr = *(const short8b*)(W1Tp + (size_t)(ct * 16 + row) * 576 + kc * 32 + kg * 8);
            acc[ct] = __builtin_amdgcn_mfma_f32_16x16x32_bf16(af, bfr, acc[ct], 0, 0, 0);
        }
    }
    #pragma unroll
    for (int kc = 10; kc < 18; ++kc) { // x_dst channels
        const short8b af = *(const short8b*)(xnb + (size_t)d * 256 + (kc - 10) * 32 + kg * 8);
        #pragma unroll
        for (int ct = 0; ct < 4; ++ct) {
            const short8b bfr = *(const short8b*)(W1Tp + (size_t)(ct * 16 + row) * 576 + kc * 32 + kg * 8);
            acc[ct] = __builtin_amdgcn_mfma_f32_16x16x32_bf16(af, bfr, acc[ct], 0, 0, 0);
        }
    }

    // h2 = leaky(acc) -> wave-private LDS bounce (same-wave in-order, no barrier)
    unsigned short* h2 = h2_s[w];
    #pragma unroll
    for (int ct = 0; ct < 4; ++ct)
        #pragma unroll
        for (int r = 0; r < 4; ++r)
            h2[(kg * 4 + r) * 72 + ct * 16 + row] = rawbf(leaky(acc[ct][r]));

    // GEMM2: [16 x 64] @ W2 -> [16 x 64]
    f32x4 a2[4];
    #pragma unroll
    for (int ct = 0; ct < 4; ++ct) {
        const float bvv = b2[ct * 16 + row];
        a2[ct] = (f32x4){bvv, bvv, bvv, bvv};
    }
    #pragma unroll
    for (int kc = 0; kc < 2; ++kc) {
        const short8b af = *(const short8b*)&h2[row * 72 + kc * 32 + kg * 8];
        #pragma unroll
        for (int ct = 0; ct < 4; ++ct) {
            const short8b bfr = *(const short8b*)(W2T + (size_t)(ct * 16 + row) * 64 + kc * 32 + kg * 8);
            a2[ct] = __builtin_amdgcn_mfma_f32_16x16x32_bf16(af, bfr, a2[ct], 0, 0, 0);
        }
    }

    // epilogue: out = leaky(ea + h2@W2+b2); ea residual re-read (L2-warm)
    int eg2[4];
    #pragma unroll
    for (int r = 0; r < 4; ++r) eg2[r] = eidsort[e0 + w * 16 + kg * 4 + r];
    #pragma unroll
    for (int ct = 0; ct < 4; ++ct)
        #pragma unroll
        for (int r = 0; r < 4; ++r) {
            const float eav = ea[(size_t)eg2[r] * 64 + ct * 16 + row];
            __builtin_nontemporal_store(leaky(eav + a2[ct][r]),
                                        out_e + (size_t)eg2[r] * 64 + ct * 16 + row);
        }
}

extern "C" void kernel_launch(void* const* d_in, const int* in_sizes, int n_in,
                              void* d_out, int out_size, void* d_ws, size_t ws_size,
                              hipStream_t stream)
{
    const float* x  = (const float*)d_in[0];
    const int*   ei = (const int*)d_in[1];
    const float* ea = (const float*)d_in[2];
    const float* Wq = (const float*)d_in[3];
    const float* bq = (const float*)d_in[4];
    const float* Wk = (const float*)d_in[5];
    const float* bk = (const float*)d_in[6];
    const float* Wv = (const float*)d_in[7];
    const float* bv = (const float*)d_in[8];
    const float* We = (const float*)d_in[9];
    const float* Ws = (const float*)d_in[10];
    const float* bs = (const float*)d_in[11];
    const float* W1 = (const float*)d_in[12];
    const float* b1 = (const float*)d_in[13];
    const float* W2 = (const float*)d_in[14];
    const float* b2 = (const float*)d_in[15];

    char* ws = (char*)d_ws;
    int*   flags  = (int*)ws;                       // 4 KB
    int*   ssort  = (int*)(ws + 4096);
    int*   dsort  = (int*)(ws + 1604096);
    int*   eids   = (int*)(ws + 3204096);
    int*   cursor = (int*)(ws + 4804096);           // end-pointers after kct
    bf16*  WeT    = (bf16*)(ws + 5004096);
    bf16*  W1Tp   = (bf16*)(ws + 5036864);
    bf16*  W2T    = (bf16*)(ws + 5110592);
    bf16*  WT4    = (bf16*)(ws + 5118784);
    bf16*  qb     = (bf16*)(ws + 5643072);
    bf16*  kb     = (bf16*)(ws + 31243072);
    bf16*  vb     = (bf16*)(ws + 56843072);
    bf16*  xnb    = (bf16*)(ws + 82443072);         // x_new bf16

    float* out_x = (float*)d_out;
    float* out_e = out_x + (size_t)N_NODES * D_NODE;
    bf16*  skipb = (bf16*)out_e;   // bf16 skip staged in edge-out region

    hipMemsetAsync(cursor, 0, N_NODES * 4, stream);       // degree counters

    k0_detect<<<1, 64, 0, stream>>>(ei, flags);
    kcd_degree<<<(N_EDGES + 255) / 256, 256, 0, stream>>>(ei, flags, cursor);
    kcs_scan<<<1, 1024, 0, stream>>>(cursor);
    kct_scatter<<<(N_EDGES + 255) / 256, 256, 0, stream>>>(ei, flags, cursor, ssort, dsort, eids);

    kT_transpose<<<64, 256, 0, stream>>>(We, W1, W2, Wq, Wk, Wv, Ws, WeT, W1Tp, W2T, WT4);

    k1_node_mfma<<<(N_NODES + 63) / 64, 256, 0, stream>>>(
        x, WT4, bq, bk, bv, bs, qb, kb, vb, skipb);

    k2_seg<<<N_NODES / SEG, 256, 0, stream>>>(
        ssort, dsort, eids, cursor, ea, WeT, qb, kb, vb, skipb, out_x, xnb);

    k4_edge_mlp<<<N_EDGES / 64, 256, 0, stream>>>(
        ssort, dsort, eids, xnb, ea, W1Tp, b1, W2T, b2, out_e);
}

// Round 10
// 948.631 us; speedup vs baseline: 1.1320x; 1.0007x over previous
//
#include <hip/hip_runtime.h>
#include <hip/hip_bf16.h>

// GCNBlock: TransformerConv(32 heads, dim 8, edge_dim 64) + EdgeResidualLayer
// N=50000, E=400000, D_NODE=256, D_EDGE=64. FP32 in/out, int64 edge_index.
// Internals: bf16 MFMA (16x16x32) with fp32 accumulate.
//
// Round 10: k4 was latency-bound (303us, hbm 1.19TB/s, MfmaUtil 4%, VGPR 60 --
// one gather in flight per wave). Fix: prefetch ALL 18 A-fragments (ea x2,
// src x8, dst x8 = 72 VGPR) before the MFMA loop -> 18 loads in flight;
// stash bf16 ea tile in wave-private LDS so the residual epilogue stops
// re-reading fp32 ea from global.
// Carried: CSR dst-sort, barrier-free k2 (SEG=16, LDS accumulator, fused
// finalize), MFMA everywhere, nt streams, k1 store-span fix.

#define N_NODES 50000
#define N_EDGES 400000
#define D_NODE 256
#define D_EDGE 64
#define HEADS 32
#define LRELU 0.01f
#define SEG 16          // dst nodes per k2 block

typedef __hip_bfloat16 bf16;
typedef __attribute__((ext_vector_type(8))) short short8b;          // 8 bf16
typedef __attribute__((ext_vector_type(4))) float f32x4;
typedef __attribute__((ext_vector_type(4))) unsigned short ushort4v;

__device__ __forceinline__ float bf2f(bf16 v) { return __bfloat162float(v); }
__device__ __forceinline__ bf16 f2bf(float f) { return __float2bfloat16(f); }
__device__ __forceinline__ float bfraw(unsigned short u) {
    return __uint_as_float(((unsigned int)u) << 16);
}
__device__ __forceinline__ unsigned short rawbf(float f) {
    bf16 t = f2bf(f); return *(unsigned short*)&t;
}
__device__ __forceinline__ float leaky(float v) { return v >= 0.f ? v : LRELU * v; }
__device__ __forceinline__ short8b pack8(const f32x4 a, const f32x4 b) {
    short8b r;
    r[0] = (short)rawbf(a[0]); r[1] = (short)rawbf(a[1]);
    r[2] = (short)rawbf(a[2]); r[3] = (short)rawbf(a[3]);
    r[4] = (short)rawbf(b[0]); r[5] = (short)rawbf(b[1]);
    r[6] = (short)rawbf(b[2]); r[7] = (short)rawbf(b[3]);
    return r;
}

// ---------------- k0: index width detection (1 wave) ----------------
__global__ void k0_detect(const int* __restrict__ ei, int* __restrict__ flags)
{
    const int lane = threadIdx.x;
    const unsigned long long mz = __ballot(ei[2 * lane + 1] == 0);
    if (lane == 0) flags[0] = (__popcll(mz) >= 48) ? 1 : 0;   // 1 => int64
}

__device__ __forceinline__ void load_edge(const int* ei, int f, int i, int& s, int& d)
{
    if (f) {
        const long long* e64 = (const long long*)ei;
        s = (int)e64[i]; d = (int)e64[N_EDGES + i];
    } else {
        s = ei[i]; d = ei[N_EDGES + i];
    }
}

// ---------------- CSR build ----------------
__global__ __launch_bounds__(256) void kcd_degree(
    const int* __restrict__ ei, const int* __restrict__ flags, int* __restrict__ deg)
{
    const int i = blockIdx.x * 256 + threadIdx.x;
    if (i >= N_EDGES) return;
    int s, d; load_edge(ei, flags[0], i, s, d);
    atomicAdd(&deg[d], 1);
}

__global__ __launch_bounds__(1024) void kcs_scan(int* __restrict__ cur)  // deg -> excl. offsets
{
    __shared__ int ps[1024];
    const int t = threadIdx.x;
    const int CH = (N_NODES + 1023) / 1024;   // 49
    const int base = t * CH;
    int sum = 0;
    for (int i = 0; i < CH; ++i) {
        const int n = base + i;
        if (n < N_NODES) sum += cur[n];
    }
    ps[t] = sum;
    __syncthreads();
    for (int off = 1; off < 1024; off <<= 1) {
        const int v = (t >= off) ? ps[t - off] : 0;
        __syncthreads();
        ps[t] += v;
        __syncthreads();
    }
    int excl = (t == 0) ? 0 : ps[t - 1];
    for (int i = 0; i < CH; ++i) {
        const int n = base + i;
        if (n < N_NODES) {
            const int d = cur[n];
            cur[n] = excl;
            excl += d;
        }
    }
}

__global__ __launch_bounds__(256) void kct_scatter(
    const int* __restrict__ ei, const int* __restrict__ flags, int* __restrict__ cursor,
    int* __restrict__ ssort, int* __restrict__ dsort, int* __restrict__ eidsort)
{
    const int i = blockIdx.x * 256 + threadIdx.x;
    if (i >= N_EDGES) return;
    int s, d; load_edge(ei, flags[0], i, s, d);
    const int pos = atomicAdd(&cursor[d], 1);
    ssort[pos] = s; dsort[pos] = d; eidsort[pos] = i;
    // after this kernel: cursor[n] == end offset of node n (inclusive)
}

// ---------------- kT: weight transposes (fp32 -> bf16) ----------------
__global__ __launch_bounds__(256) void kT_transpose(
    const float* __restrict__ We, const float* __restrict__ W1, const float* __restrict__ W2,
    const float* __restrict__ Wq, const float* __restrict__ Wk,
    const float* __restrict__ Wv, const float* __restrict__ Ws,
    bf16* __restrict__ WeT, bf16* __restrict__ W1Tp, bf16* __restrict__ W2T,
    bf16* __restrict__ WT4)
{
    const int gid = blockIdx.x * 256 + threadIdx.x;
    const int gsz = gridDim.x * 256;
    for (int i = gid; i < 256 * 64; i += gsz) {
        const int n = i >> 6, k = i & 63;
        WeT[i] = f2bf(We[k * 256 + n]);
    }
    for (int i = gid; i < 64 * 576; i += gsz) {
        const int n = i / 576, kp = i % 576;
        const int k = (kp < 64) ? (512 + kp) : (kp - 64);
        W1Tp[i] = f2bf(W1[k * 64 + n]);
    }
    for (int i = gid; i < 64 * 64; i += gsz) {
        const int n = i >> 6, k = i & 63;
        W2T[i] = f2bf(W2[k * 64 + n]);
    }
    for (int i = gid; i < 4 * 256 * 256; i += gsz) {
        const int m = i >> 16, rem = i & 65535;
        const int n = rem >> 8, kk = rem & 255;
        const float* W = (m == 0) ? Wq : (m == 1) ? Wk : (m == 2) ? Wv : Ws;
        WT4[i] = f2bf(W[kk * 256 + n]);
    }
}

// ---------------- k1: node linears via MFMA (nt streams, LDS store-bounce) ----------------
#define X_LD 264
__global__ __launch_bounds__(256) void k1_node_mfma(
    const float* __restrict__ x, const bf16* __restrict__ WT4,
    const float* __restrict__ bq, const float* __restrict__ bk,
    const float* __restrict__ bv, const float* __restrict__ bs,
    bf16* __restrict__ qo, bf16* __restrict__ ko, bf16* __restrict__ vo,
    bf16* __restrict__ skipb)
{
    __shared__ unsigned short xs[64 * X_LD];   // 33792 B; reused as result bounce
    const int tid = threadIdx.x;
    const int n0 = blockIdx.x * 64;
    const int e = tid >> 2, t = tid & 3;       // node e, quarter t
    const int nmine = n0 + e;

    { // stage x tile (fp32 -> bf16), nontemporal f32x4 loads
        const f32x4* src = (const f32x4*)(x + (size_t)nmine * 256 + t * 64);
        #pragma unroll
        for (int c = 0; c < 4; ++c) {
            unsigned short tmp[16];
            if (nmine < N_NODES) {
                #pragma unroll
                for (int u = 0; u < 4; ++u) {
                    const f32x4 v = __builtin_nontemporal_load(src + c * 4 + u);
                    tmp[u * 4 + 0] = rawbf(v[0]); tmp[u * 4 + 1] = rawbf(v[1]);
                    tmp[u * 4 + 2] = rawbf(v[2]); tmp[u * 4 + 3] = rawbf(v[3]);
                }
            } else {
                #pragma unroll
                for (int u = 0; u < 16; ++u) tmp[u] = 0;
            }
            *(short8b*)&xs[e * X_LD + t * 64 + c * 16]     = *(short8b*)&tmp[0];
            *(short8b*)&xs[e * X_LD + t * 64 + c * 16 + 8] = *(short8b*)&tmp[8];
        }
    }
    __syncthreads();

    const int w = tid >> 6, l = tid & 63;
    const int row = l & 15, kg = l >> 4;
    short8b af[8];
    #pragma unroll
    for (int kc = 0; kc < 8; ++kc)
        af[kc] = *(const short8b*)&xs[(w * 16 + row) * X_LD + kc * 32 + kg * 8];

    for (int m = 0; m < 4; ++m) {
        const bf16* WT = WT4 + (size_t)m * 65536;
        const float* bias = (m == 0) ? bq : (m == 1) ? bk : (m == 2) ? bv : bs;
        __syncthreads();   // prior LDS reads done
        #pragma unroll 4
        for (int ct = 0; ct < 16; ++ct) {
            const float bvv = bias[ct * 16 + row];
            f32x4 acc = {bvv, bvv, bvv, bvv};
            #pragma unroll
            for (int kc = 0; kc < 8; ++kc) {
                const short8b bfr = *(const short8b*)(WT + (size_t)(ct * 16 + row) * 256 + kc * 32 + kg * 8);
                acc = __builtin_amdgcn_mfma_f32_16x16x32_bf16(af[kc], bfr, acc, 0, 0, 0);
            }
            #pragma unroll
            for (int r = 0; r < 4; ++r)   // bounce: row = local node, col = output col
                xs[(w * 16 + kg * 4 + r) * X_LD + ct * 16 + row] = rawbf(acc[r]);
        }
        __syncthreads();
        { // store phase: per instruction, block writes ONE contiguous 4KB span
            bf16* dst = (m == 0) ? qo : (m == 1) ? ko : (m == 2) ? vo : skipb;
            #pragma unroll
            for (int u = 0; u < 8; ++u) {
                const int flat = u * 256 + tid;     // 16B unit within 32KB tile
                const int node = flat >> 5;         // 32 units (512B) per node
                const int col8 = (flat & 31) * 8;   // bf16 element offset
                if (n0 + node < N_NODES) {
                    const short8b vdat = *(const short8b*)&xs[node * X_LD + col8];
                    __builtin_nontemporal_store(vdat,
                        (short8b*)(dst + (size_t)(n0 + node) * 256 + col8));
                }
            }
        }
    }
}

// ---------------- k2: barrier-free segment attention ----------------
#define EP_LD 264
__global__ __launch_bounds__(256) void k2_seg(
    const int* __restrict__ ssort, const int* __restrict__ dsort,
    const int* __restrict__ eidsort, const int* __restrict__ endptr,
    const float* __restrict__ ea, const bf16* __restrict__ WeT,
    const bf16* __restrict__ q, const bf16* __restrict__ k, const bf16* __restrict__ v,
    const bf16* __restrict__ skipb, float* __restrict__ out_x, bf16* __restrict__ xnb)
{
    __shared__ float acc_s[SEG * 256];            // 16 KB msg accumulator
    __shared__ float den_s[SEG * HEADS];          // 2 KB
    __shared__ unsigned short ep_s[64 * EP_LD];   // 33 KB (wave-private rows)
    const int tid = threadIdx.x;
    const int n0 = blockIdx.x * SEG;

    #pragma unroll
    for (int i = 0; i < SEG; ++i) acc_s[i * 256 + tid] = 0.f;
    if (tid < SEG * HEADS - 256) den_s[256 + tid] = 0.f;
    den_s[tid] = 0.f;

    const int start = (n0 == 0) ? 0 : endptr[n0 - 1];
    const int end   = endptr[n0 + SEG - 1];
    __syncthreads();

    const int w = tid >> 6, l = tid & 63;
    const int row = l & 15, kg = l >> 4;
    const float scale = 0.35355339059327373f;   // 1/sqrt(8)

    // each wave free-runs its own 16-edge slices; no barriers in this loop
    for (int sbase = start + w * 16; sbase < end; sbase += 64) {
        const int cnt = min(16, end - sbase);

        // --- A fragments direct from global ea (fp32 -> bf16 in regs) ---
        short8b af0 = {0, 0, 0, 0, 0, 0, 0, 0}, af1 = af0;
        if (row < cnt) {
            const int eg = eidsort[sbase + row];
            const float* pb = ea + (size_t)eg * 64 + kg * 8;
            const f32x4 a0 = __builtin_nontemporal_load((const f32x4*)pb);
            const f32x4 a1 = __builtin_nontemporal_load((const f32x4*)(pb + 4));
            const f32x4 b0 = __builtin_nontemporal_load((const f32x4*)(pb + 32));
            const f32x4 b1 = __builtin_nontemporal_load((const f32x4*)(pb + 36));
            af0 = pack8(a0, a1); af1 = pack8(b0, b1);
        }
        // --- eproj MFMA into wave-private ep rows ---
        #pragma unroll 4
        for (int ct = 0; ct < 16; ++ct) {
            f32x4 acc = {0.f, 0.f, 0.f, 0.f};
            const short8b b0 = *(const short8b*)(WeT + (size_t)(ct * 16 + row) * 64 + kg * 8);
            const short8b b1 = *(const short8b*)(WeT + (size_t)(ct * 16 + row) * 64 + 32 + kg * 8);
            acc = __builtin_amdgcn_mfma_f32_16x16x32_bf16(af0, b0, acc, 0, 0, 0);
            acc = __builtin_amdgcn_mfma_f32_16x16x32_bf16(af1, b1, acc, 0, 0, 0);
            #pragma unroll
            for (int r = 0; r < 4; ++r)
                ep_s[(w * 16 + kg * 4 + r) * EP_LD + ct * 16 + row] = rawbf(acc[r]);
        }
        // same-wave LDS write->read is in-order: no barrier needed

        // --- attention over this wave's cnt edges (run-compressed) ---
        int sv = 0;
        if (l < 16)      { if (l < cnt)      sv = ssort[sbase + l]; }
        else if (l < 32) { if (l - 16 < cnt) sv = dsort[sbase + (l - 16)]; }

        float macc[4] = {0.f, 0.f, 0.f, 0.f};
        float dacc = 0.f;
        int dprev = -1;
        ushort4v qv = {0, 0, 0, 0};

        for (int i = 0; i < cnt; ++i) {
            const int s = __shfl(sv, i);
            const int d = __shfl(sv, 16 + i);
            if (d != dprev) {                  // wave-uniform
                if (dprev >= 0) {
                    const int ld = dprev - n0;
                    #pragma unroll
                    for (int t = 0; t < 4; ++t)
                        atomicAdd(&acc_s[ld * 256 + l * 4 + t], macc[t]);
                    if ((l & 1) == 0)
                        atomicAdd(&den_s[ld * HEADS + (l >> 1)], dacc);
                    macc[0] = macc[1] = macc[2] = macc[3] = 0.f;
                    dacc = 0.f;
                }
                qv = *(const ushort4v*)(q + (size_t)d * 256 + l * 4);
                dprev = d;
            }
            const ushort4v kv = *(const ushort4v*)(k + (size_t)s * 256 + l * 4);
            const ushort4v vv = *(const ushort4v*)(v + (size_t)s * 256 + l * 4);
            const ushort4v ep = *(const ushort4v*)&ep_s[(w * 16 + i) * EP_LD + l * 4];
            float p = 0.f, m4[4];
            #pragma unroll
            for (int t = 0; t < 4; ++t) {
                const float epf = bfraw(ep[t]);
                p = fmaf(bfraw(qv[t]), bfraw(kv[t]) + epf, p);
                m4[t] = bfraw(vv[t]) + epf;
            }
            p += __shfl_xor(p, 1);             // head = l>>1 (2 lanes/head)
            const float ex = __expf(p * scale);
            #pragma unroll
            for (int t = 0; t < 4; ++t) macc[t] = fmaf(m4[t], ex, macc[t]);
            dacc += ex;
        }
        if (dprev >= 0) {
            const int ld = dprev - n0;
            #pragma unroll
            for (int t = 0; t < 4; ++t)
                atomicAdd(&acc_s[ld * 256 + l * 4 + t], macc[t]);
            if ((l & 1) == 0)
                atomicAdd(&den_s[ld * HEADS + (l >> 1)], dacc);
        }
    }
    __syncthreads();   // single barrier: all waves' aggregation done

    // finalize: x_new = leaky(acc/den + skip) -> out_x fp32 + xnb bf16
    #pragma unroll
    for (int u = 0; u < 4; ++u) {
        const int flat4 = u * 256 + tid;        // f32x4 unit; 64 per node
        const int node = flat4 >> 6;
        const int ch4 = flat4 & 63;
        const int n = n0 + node;
        const float den = den_s[node * HEADS + (ch4 >> 1)] + 1e-16f;
        const f32x4 mv = *(const f32x4*)&acc_s[node * 256 + ch4 * 4];
        const ushort4v sk = *(const ushort4v*)(skipb + (size_t)n * 256 + ch4 * 4);
        f32x4 o; ushort4v ob;
        #pragma unroll
        for (int t = 0; t < 4; ++t) {
            const float xn = leaky(mv[t] / den + bfraw(sk[t]));
            o[t] = xn; ob[t] = rawbf(xn);
        }
        __builtin_nontemporal_store(o, (f32x4*)(out_x + (size_t)n * 256 + ch4 * 4));
        *(ushort4v*)(xnb + (size_t)n * 256 + ch4 * 4) = ob;
    }
}

// ---------------- k4: edge MLP, full A-prefetch + LDS ea stash ----------------
__global__ __launch_bounds__(256) void k4_edge_mlp(
    const int* __restrict__ ssort, const int* __restrict__ dsort,
    const int* __restrict__ eidsort,
    const bf16* __restrict__ xnb, const float* __restrict__ ea,
    const bf16* __restrict__ W1Tp, const float* __restrict__ b1,
    const bf16* __restrict__ W2T, const float* __restrict__ b2,
    float* __restrict__ out_e)
{
    __shared__ unsigned short h2_s[4][16 * 72];   // 9216 B, wave-private
    __shared__ unsigned short ea_s[4][16 * 72];   // 9216 B, wave-private ea stash
    const int tid = threadIdx.x;
    const int w = tid >> 6, l = tid & 63;
    const int row = l & 15, kg = l >> 4;
    const int e0 = blockIdx.x * 64;
    const int sl = e0 + w * 16 + row;            // this lane's A-row edge
    const int eg = eidsort[sl];
    const int s  = ssort[sl];
    const int d  = dsort[sl];

    // ---- prefetch ALL 18 A fragments (72 VGPR) -> 18 loads in flight ----
    short8b afr[18];
    {
        const float* pb = ea + (size_t)eg * 64 + kg * 8;
        const f32x4 a0 = __builtin_nontemporal_load((const f32x4*)pb);
        const f32x4 a1 = __builtin_nontemporal_load((const f32x4*)(pb + 4));
        const f32x4 c0 = __builtin_nontemporal_load((const f32x4*)(pb + 32));
        const f32x4 c1 = __builtin_nontemporal_load((const f32x4*)(pb + 36));
        afr[0] = pack8(a0, a1);
        afr[1] = pack8(c0, c1);
    }
    #pragma unroll
    for (int j = 0; j < 8; ++j)
        afr[2 + j] = *(const short8b*)(xnb + (size_t)s * 256 + j * 32 + kg * 8);
    #pragma unroll
    for (int j = 0; j < 8; ++j)
        afr[10 + j] = *(const short8b*)(xnb + (size_t)d * 256 + j * 32 + kg * 8);

    // stash bf16 ea tile for the residual epilogue (same-wave in-order)
    *(short8b*)&ea_s[w][row * 72 + kg * 8]      = afr[0];
    *(short8b*)&ea_s[w][row * 72 + 32 + kg * 8] = afr[1];

    // ---- GEMM1: [16 x 576] @ W1 -> [16 x 64] ----
    f32x4 acc[4];
    #pragma unroll
    for (int ct = 0; ct < 4; ++ct) {
        const float bvv = b1[ct * 16 + row];
        acc[ct] = (f32x4){bvv, bvv, bvv, bvv};
    }
    #pragma unroll
    for (int kc = 0; kc < 18; ++kc) {
        #pragma unroll
        for (int ct = 0; ct < 4; ++ct) {
            const short8b bfr = *(const short8b*)(W1Tp + (size_t)(ct * 16 + row) * 576 + kc * 32 + kg * 8);
            acc[ct] = __builtin_amdgcn_mfma_f32_16x16x32_bf16(afr[kc], bfr, acc[ct], 0, 0, 0);
        }
    }

    // h2 = leaky(acc) -> wave-private LDS bounce (same-wave in-order)
    unsigned short* h2 = h2_s[w];
    #pragma unroll
    for (int ct = 0; ct < 4; ++ct)
        #pragma unroll
        for (int r = 0; r < 4; ++r)
            h2[(kg * 4 + r) * 72 + ct * 16 + row] = rawbf(leaky(acc[ct][r]));

    // ---- GEMM2: [16 x 64] @ W2 -> [16 x 64] ----
    f32x4 a2[4];
    #pragma unroll
    for (int ct = 0; ct < 4; ++ct) {
        const float bvv = b2[ct * 16 + row];
        a2[ct] = (f32x4){bvv, bvv, bvv, bvv};
    }
    #pragma unroll
    for (int kc = 0; kc < 2; ++kc) {
        const short8b af = *(const short8b*)&h2[row * 72 + kc * 32 + kg * 8];
        #pragma unroll
        for (int ct = 0; ct < 4; ++ct) {
            const short8b bfr = *(const short8b*)(W2T + (size_t)(ct * 16 + row) * 64 + kc * 32 + kg * 8);
            a2[ct] = __builtin_amdgcn_mfma_f32_16x16x32_bf16(af, bfr, a2[ct], 0, 0, 0);
        }
    }

    // epilogue: out = leaky(ea + h2@W2+b2); ea residual from LDS stash
    int eg2[4];
    #pragma unroll
    for (int r = 0; r < 4; ++r) eg2[r] = eidsort[e0 + w * 16 + kg * 4 + r];
    #pragma unroll
    for (int ct = 0; ct < 4; ++ct)
        #pragma unroll
        for (int r = 0; r < 4; ++r) {
            const float eav = bfraw(ea_s[w][(kg * 4 + r) * 72 + ct * 16 + row]);
            __builtin_nontemporal_store(leaky(eav + a2[ct][r]),
                                        out_e + (size_t)eg2[r] * 64 + ct * 16 + row);
        }
}

extern "C" void kernel_launch(void* const* d_in, const int* in_sizes, int n_in,
                              void* d_out, int out_size, void* d_ws, size_t ws_size,
                              hipStream_t stream)
{
    const float* x  = (const float*)d_in[0];
    const int*   ei = (const int*)d_in[1];
    const float* ea = (const float*)d_in[2];
    const float* Wq = (const float*)d_in[3];
    const float* bq = (const float*)d_in[4];
    const float* Wk = (const float*)d_in[5];
    const float* bk = (const float*)d_in[6];
    const float* Wv = (const float*)d_in[7];
    const float* bv = (const float*)d_in[8];
    const float* We = (const float*)d_in[9];
    const float* Ws = (const float*)d_in[10];
    const float* bs = (const float*)d_in[11];
    const float* W1 = (const float*)d_in[12];
    const float* b1 = (const float*)d_in[13];
    const float* W2 = (const float*)d_in[14];
    const float* b2 = (const float*)d_in[15];

    char* ws = (char*)d_ws;
    int*   flags  = (int*)ws;                       // 4 KB
    int*   ssort  = (int*)(ws + 4096);
    int*   dsort  = (int*)(ws + 1604096);
    int*   eids   = (int*)(ws + 3204096);
    int*   cursor = (int*)(ws + 4804096);           // end-pointers after kct
    bf16*  WeT    = (bf16*)(ws + 5004096);
    bf16*  W1Tp   = (bf16*)(ws + 5036864);
    bf16*  W2T    = (bf16*)(ws + 5110592);
    bf16*  WT4    = (bf16*)(ws + 5118784);
    bf16*  qb     = (bf16*)(ws + 5643072);
    bf16*  kb     = (bf16*)(ws + 31243072);
    bf16*  vb     = (bf16*)(ws + 56843072);
    bf16*  xnb    = (bf16*)(ws + 82443072);         // x_new bf16

    float* out_x = (float*)d_out;
    float* out_e = out_x + (size_t)N_NODES * D_NODE;
    bf16*  skipb = (bf16*)out_e;   // bf16 skip staged in edge-out region

    hipMemsetAsync(cursor, 0, N_NODES * 4, stream);       // degree counters

    k0_detect<<<1, 64, 0, stream>>>(ei, flags);
    kcd_degree<<<(N_EDGES + 255) / 256, 256, 0, stream>>>(ei, flags, cursor);
    kcs_scan<<<1, 1024, 0, stream>>>(cursor);
    kct_scatter<<<(N_EDGES + 255) / 256, 256, 0, stream>>>(ei, flags, cursor, ssort, dsort, eids);

    kT_transpose<<<64, 256, 0, stream>>>(We, W1, W2, Wq, Wk, Wv, Ws, WeT, W1Tp, W2T, WT4);

    k1_node_mfma<<<(N_NODES + 63) / 64, 256, 0, stream>>>(
        x, WT4, bq, bk, bv, bs, qb, kb, vb, skipb);

    k2_seg<<<N_NODES / SEG, 256, 0, stream>>>(
        ssort, dsort, eids, cursor, ea, WeT, qb, kb, vb, skipb, out_x, xnb);

    k4_edge_mlp<<<N_EDGES / 64, 256, 0, stream>>>(
        ssort, dsort, eids, xnb, ea, W1Tp, b1, W2T, b2, out_e);
}

// Round 11
// 810.311 us; speedup vs baseline: 1.3253x; 1.1707x over previous
//
#include <hip/hip_runtime.h>
#include <hip/hip_bf16.h>

// GCNBlock: TransformerConv(32 heads, dim 8, edge_dim 64) + EdgeResidualLayer
// N=50000, E=400000, D_NODE=256, D_EDGE=64. FP32 in/out, int64 edge_index.
// Internals: bf16 MFMA (16x16x32) with fp32 accumulate.
//
// Round 11: factorize k4's first GEMM. h@W1 is linear over [x_s|x_d|ea], so
// k3b precomputes P[n] = [xn@W1_s | xn@W1_d] ([N,128] bf16) once per NODE;
// k4 per edge then needs only ea@W1_ea (K=64 MFMA) + two 128B P-row gathers
// (was two 512B xnb rows) + b1. 4x less gather traffic, 9x fewer GEMM1 MFMAs.
// P slices come from the existing W1Tp permuted layout (cols 64..319 = src,
// 320..575 = dst) -- no new transpose.
// Carried: CSR dst-sort, barrier-free k2 (SEG=16, LDS accumulator, fused
// finalize), MFMA everywhere, nt streams, k1 store-span fix.

#define N_NODES 50000
#define N_EDGES 400000
#define D_NODE 256
#define D_EDGE 64
#define HEADS 32
#define LRELU 0.01f
#define SEG 16          // dst nodes per k2 block

typedef __hip_bfloat16 bf16;
typedef __attribute__((ext_vector_type(8))) short short8b;          // 8 bf16
typedef __attribute__((ext_vector_type(4))) float f32x4;
typedef __attribute__((ext_vector_type(4))) unsigned short ushort4v;

__device__ __forceinline__ float bf2f(bf16 v) { return __bfloat162float(v); }
__device__ __forceinline__ bf16 f2bf(float f) { return __float2bfloat16(f); }
__device__ __forceinline__ float bfraw(unsigned short u) {
    return __uint_as_float(((unsigned int)u) << 16);
}
__device__ __forceinline__ unsigned short rawbf(float f) {
    bf16 t = f2bf(f); return *(unsigned short*)&t;
}
__device__ __forceinline__ float leaky(float v) { return v >= 0.f ? v : LRELU * v; }
__device__ __forceinline__ short8b pack8(const f32x4 a, const f32x4 b) {
    short8b r;
    r[0] = (short)rawbf(a[0]); r[1] = (short)rawbf(a[1]);
    r[2] = (short)rawbf(a[2]); r[3] = (short)rawbf(a[3]);
    r[4] = (short)rawbf(b[0]); r[5] = (short)rawbf(b[1]);
    r[6] = (short)rawbf(b[2]); r[7] = (short)rawbf(b[3]);
    return r;
}

// ---------------- k0: index width detection (1 wave) ----------------
__global__ void k0_detect(const int* __restrict__ ei, int* __restrict__ flags)
{
    const int lane = threadIdx.x;
    const unsigned long long mz = __ballot(ei[2 * lane + 1] == 0);
    if (lane == 0) flags[0] = (__popcll(mz) >= 48) ? 1 : 0;   // 1 => int64
}

__device__ __forceinline__ void load_edge(const int* ei, int f, int i, int& s, int& d)
{
    if (f) {
        const long long* e64 = (const long long*)ei;
        s = (int)e64[i]; d = (int)e64[N_EDGES + i];
    } else {
        s = ei[i]; d = ei[N_EDGES + i];
    }
}

// ---------------- CSR build ----------------
__global__ __launch_bounds__(256) void kcd_degree(
    const int* __restrict__ ei, const int* __restrict__ flags, int* __restrict__ deg)
{
    const int i = blockIdx.x * 256 + threadIdx.x;
    if (i >= N_EDGES) return;
    int s, d; load_edge(ei, flags[0], i, s, d);
    atomicAdd(&deg[d], 1);
}

__global__ __launch_bounds__(1024) void kcs_scan(int* __restrict__ cur)  // deg -> excl. offsets
{
    __shared__ int ps[1024];
    const int t = threadIdx.x;
    const int CH = (N_NODES + 1023) / 1024;   // 49
    const int base = t * CH;
    int sum = 0;
    for (int i = 0; i < CH; ++i) {
        const int n = base + i;
        if (n < N_NODES) sum += cur[n];
    }
    ps[t] = sum;
    __syncthreads();
    for (int off = 1; off < 1024; off <<= 1) {
        const int v = (t >= off) ? ps[t - off] : 0;
        __syncthreads();
        ps[t] += v;
        __syncthreads();
    }
    int excl = (t == 0) ? 0 : ps[t - 1];
    for (int i = 0; i < CH; ++i) {
        const int n = base + i;
        if (n < N_NODES) {
            const int d = cur[n];
            cur[n] = excl;
            excl += d;
        }
    }
}

__global__ __launch_bounds__(256) void kct_scatter(
    const int* __restrict__ ei, const int* __restrict__ flags, int* __restrict__ cursor,
    int* __restrict__ ssort, int* __restrict__ dsort, int* __restrict__ eidsort)
{
    const int i = blockIdx.x * 256 + threadIdx.x;
    if (i >= N_EDGES) return;
    int s, d; load_edge(ei, flags[0], i, s, d);
    const int pos = atomicAdd(&cursor[d], 1);
    ssort[pos] = s; dsort[pos] = d; eidsort[pos] = i;
    // after this kernel: cursor[n] == end offset of node n (inclusive)
}

// ---------------- kT: weight transposes (fp32 -> bf16) ----------------
__global__ __launch_bounds__(256) void kT_transpose(
    const float* __restrict__ We, const float* __restrict__ W1, const float* __restrict__ W2,
    const float* __restrict__ Wq, const float* __restrict__ Wk,
    const float* __restrict__ Wv, const float* __restrict__ Ws,
    bf16* __restrict__ WeT, bf16* __restrict__ W1Tp, bf16* __restrict__ W2T,
    bf16* __restrict__ WT4)
{
    const int gid = blockIdx.x * 256 + threadIdx.x;
    const int gsz = gridDim.x * 256;
    for (int i = gid; i < 256 * 64; i += gsz) {
        const int n = i >> 6, k = i & 63;
        WeT[i] = f2bf(We[k * 256 + n]);
    }
    for (int i = gid; i < 64 * 576; i += gsz) {
        const int n = i / 576, kp = i % 576;
        const int k = (kp < 64) ? (512 + kp) : (kp - 64);
        W1Tp[i] = f2bf(W1[k * 64 + n]);
    }
    for (int i = gid; i < 64 * 64; i += gsz) {
        const int n = i >> 6, k = i & 63;
        W2T[i] = f2bf(W2[k * 64 + n]);
    }
    for (int i = gid; i < 4 * 256 * 256; i += gsz) {
        const int m = i >> 16, rem = i & 65535;
        const int n = rem >> 8, kk = rem & 255;
        const float* W = (m == 0) ? Wq : (m == 1) ? Wk : (m == 2) ? Wv : Ws;
        WT4[i] = f2bf(W[kk * 256 + n]);
    }
}

// ---------------- k1: node linears via MFMA (nt streams, LDS store-bounce) ----------------
#define X_LD 264
__global__ __launch_bounds__(256) void k1_node_mfma(
    const float* __restrict__ x, const bf16* __restrict__ WT4,
    const float* __restrict__ bq, const float* __restrict__ bk,
    const float* __restrict__ bv, const float* __restrict__ bs,
    bf16* __restrict__ qo, bf16* __restrict__ ko, bf16* __restrict__ vo,
    bf16* __restrict__ skipb)
{
    __shared__ unsigned short xs[64 * X_LD];   // 33792 B; reused as result bounce
    const int tid = threadIdx.x;
    const int n0 = blockIdx.x * 64;
    const int e = tid >> 2, t = tid & 3;       // node e, quarter t
    const int nmine = n0 + e;

    { // stage x tile (fp32 -> bf16), nontemporal f32x4 loads
        const f32x4* src = (const f32x4*)(x + (size_t)nmine * 256 + t * 64);
        #pragma unroll
        for (int c = 0; c < 4; ++c) {
            unsigned short tmp[16];
            if (nmine < N_NODES) {
                #pragma unroll
                for (int u = 0; u < 4; ++u) {
                    const f32x4 v = __builtin_nontemporal_load(src + c * 4 + u);
                    tmp[u * 4 + 0] = rawbf(v[0]); tmp[u * 4 + 1] = rawbf(v[1]);
                    tmp[u * 4 + 2] = rawbf(v[2]); tmp[u * 4 + 3] = rawbf(v[3]);
                }
            } else {
                #pragma unroll
                for (int u = 0; u < 16; ++u) tmp[u] = 0;
            }
            *(short8b*)&xs[e * X_LD + t * 64 + c * 16]     = *(short8b*)&tmp[0];
            *(short8b*)&xs[e * X_LD + t * 64 + c * 16 + 8] = *(short8b*)&tmp[8];
        }
    }
    __syncthreads();

    const int w = tid >> 6, l = tid & 63;
    const int row = l & 15, kg = l >> 4;
    short8b af[8];
    #pragma unroll
    for (int kc = 0; kc < 8; ++kc)
        af[kc] = *(const short8b*)&xs[(w * 16 + row) * X_LD + kc * 32 + kg * 8];

    for (int m = 0; m < 4; ++m) {
        const bf16* WT = WT4 + (size_t)m * 65536;
        const float* bias = (m == 0) ? bq : (m == 1) ? bk : (m == 2) ? bv : bs;
        __syncthreads();   // prior LDS reads done
        #pragma unroll 4
        for (int ct = 0; ct < 16; ++ct) {
            const float bvv = bias[ct * 16 + row];
            f32x4 acc = {bvv, bvv, bvv, bvv};
            #pragma unroll
            for (int kc = 0; kc < 8; ++kc) {
                const short8b bfr = *(const short8b*)(WT + (size_t)(ct * 16 + row) * 256 + kc * 32 + kg * 8);
                acc = __builtin_amdgcn_mfma_f32_16x16x32_bf16(af[kc], bfr, acc, 0, 0, 0);
            }
            #pragma unroll
            for (int r = 0; r < 4; ++r)   // bounce: row = local node, col = output col
                xs[(w * 16 + kg * 4 + r) * X_LD + ct * 16 + row] = rawbf(acc[r]);
        }
        __syncthreads();
        { // store phase: per instruction, block writes ONE contiguous 4KB span
            bf16* dst = (m == 0) ? qo : (m == 1) ? ko : (m == 2) ? vo : skipb;
            #pragma unroll
            for (int u = 0; u < 8; ++u) {
                const int flat = u * 256 + tid;     // 16B unit within 32KB tile
                const int node = flat >> 5;         // 32 units (512B) per node
                const int col8 = (flat & 31) * 8;   // bf16 element offset
                if (n0 + node < N_NODES) {
                    const short8b vdat = *(const short8b*)&xs[node * X_LD + col8];
                    __builtin_nontemporal_store(vdat,
                        (short8b*)(dst + (size_t)(n0 + node) * 256 + col8));
                }
            }
        }
    }
}

// ---------------- k2: barrier-free segment attention ----------------
#define EP_LD 264
__global__ __launch_bounds__(256) void k2_seg(
    const int* __restrict__ ssort, const int* __restrict__ dsort,
    const int* __restrict__ eidsort, const int* __restrict__ endptr,
    const float* __restrict__ ea, const bf16* __restrict__ WeT,
    const bf16* __restrict__ q, const bf16* __restrict__ k, const bf16* __restrict__ v,
    const bf16* __restrict__ skipb, float* __restrict__ out_x, bf16* __restrict__ xnb)
{
    __shared__ float acc_s[SEG * 256];            // 16 KB msg accumulator
    __shared__ float den_s[SEG * HEADS];          // 2 KB
    __shared__ unsigned short ep_s[64 * EP_LD];   // 33 KB (wave-private rows)
    const int tid = threadIdx.x;
    const int n0 = blockIdx.x * SEG;

    #pragma unroll
    for (int i = 0; i < SEG; ++i) acc_s[i * 256 + tid] = 0.f;
    if (tid < SEG * HEADS - 256) den_s[256 + tid] = 0.f;
    den_s[tid] = 0.f;

    const int start = (n0 == 0) ? 0 : endptr[n0 - 1];
    const int end   = endptr[n0 + SEG - 1];
    __syncthreads();

    const int w = tid >> 6, l = tid & 63;
    const int row = l & 15, kg = l >> 4;
    const float scale = 0.35355339059327373f;   // 1/sqrt(8)

    // each wave free-runs its own 16-edge slices; no barriers in this loop
    for (int sbase = start + w * 16; sbase < end; sbase += 64) {
        const int cnt = min(16, end - sbase);

        // --- A fragments direct from global ea (fp32 -> bf16 in regs) ---
        short8b af0 = {0, 0, 0, 0, 0, 0, 0, 0}, af1 = af0;
        if (row < cnt) {
            const int eg = eidsort[sbase + row];
            const float* pb = ea + (size_t)eg * 64 + kg * 8;
            const f32x4 a0 = __builtin_nontemporal_load((const f32x4*)pb);
            const f32x4 a1 = __builtin_nontemporal_load((const f32x4*)(pb + 4));
            const f32x4 b0 = __builtin_nontemporal_load((const f32x4*)(pb + 32));
            const f32x4 b1 = __builtin_nontemporal_load((const f32x4*)(pb + 36));
            af0 = pack8(a0, a1); af1 = pack8(b0, b1);
        }
        // --- eproj MFMA into wave-private ep rows ---
        #pragma unroll 4
        for (int ct = 0; ct < 16; ++ct) {
            f32x4 acc = {0.f, 0.f, 0.f, 0.f};
            const short8b b0 = *(const short8b*)(WeT + (size_t)(ct * 16 + row) * 64 + kg * 8);
            const short8b b1 = *(const short8b*)(WeT + (size_t)(ct * 16 + row) * 64 + 32 + kg * 8);
            acc = __builtin_amdgcn_mfma_f32_16x16x32_bf16(af0, b0, acc, 0, 0, 0);
            acc = __builtin_amdgcn_mfma_f32_16x16x32_bf16(af1, b1, acc, 0, 0, 0);
            #pragma unroll
            for (int r = 0; r < 4; ++r)
                ep_s[(w * 16 + kg * 4 + r) * EP_LD + ct * 16 + row] = rawbf(acc[r]);
        }
        // same-wave LDS write->read is in-order: no barrier needed

        // --- attention over this wave's cnt edges (run-compressed) ---
        int sv = 0;
        if (l < 16)      { if (l < cnt)      sv = ssort[sbase + l]; }
        else if (l < 32) { if (l - 16 < cnt) sv = dsort[sbase + (l - 16)]; }

        float macc[4] = {0.f, 0.f, 0.f, 0.f};
        float dacc = 0.f;
        int dprev = -1;
        ushort4v qv = {0, 0, 0, 0};

        for (int i = 0; i < cnt; ++i) {
            const int s = __shfl(sv, i);
            const int d = __shfl(sv, 16 + i);
            if (d != dprev) {                  // wave-uniform
                if (dprev >= 0) {
                    const int ld = dprev - n0;
                    #pragma unroll
                    for (int t = 0; t < 4; ++t)
                        atomicAdd(&acc_s[ld * 256 + l * 4 + t], macc[t]);
                    if ((l & 1) == 0)
                        atomicAdd(&den_s[ld * HEADS + (l >> 1)], dacc);
                    macc[0] = macc[1] = macc[2] = macc[3] = 0.f;
                    dacc = 0.f;
                }
                qv = *(const ushort4v*)(q + (size_t)d * 256 + l * 4);
                dprev = d;
            }
            const ushort4v kv = *(const ushort4v*)(k + (size_t)s * 256 + l * 4);
            const ushort4v vv = *(const ushort4v*)(v + (size_t)s * 256 + l * 4);
            const ushort4v ep = *(const ushort4v*)&ep_s[(w * 16 + i) * EP_LD + l * 4];
            float p = 0.f, m4[4];
            #pragma unroll
            for (int t = 0; t < 4; ++t) {
                const float epf = bfraw(ep[t]);
                p = fmaf(bfraw(qv[t]), bfraw(kv[t]) + epf, p);
                m4[t] = bfraw(vv[t]) + epf;
            }
            p += __shfl_xor(p, 1);             // head = l>>1 (2 lanes/head)
            const float ex = __expf(p * scale);
            #pragma unroll
            for (int t = 0; t < 4; ++t) macc[t] = fmaf(m4[t], ex, macc[t]);
            dacc += ex;
        }
        if (dprev >= 0) {
            const int ld = dprev - n0;
            #pragma unroll
            for (int t = 0; t < 4; ++t)
                atomicAdd(&acc_s[ld * 256 + l * 4 + t], macc[t]);
            if ((l & 1) == 0)
                atomicAdd(&den_s[ld * HEADS + (l >> 1)], dacc);
        }
    }
    __syncthreads();   // single barrier: all waves' aggregation done

    // finalize: x_new = leaky(acc/den + skip) -> out_x fp32 + xnb bf16
    #pragma unroll
    for (int u = 0; u < 4; ++u) {
        const int flat4 = u * 256 + tid;        // f32x4 unit; 64 per node
        const int node = flat4 >> 6;
        const int ch4 = flat4 & 63;
        const int n = n0 + node;
        const float den = den_s[node * HEADS + (ch4 >> 1)] + 1e-16f;
        const f32x4 mv = *(const f32x4*)&acc_s[node * 256 + ch4 * 4];
        const ushort4v sk = *(const ushort4v*)(skipb + (size_t)n * 256 + ch4 * 4);
        f32x4 o; ushort4v ob;
        #pragma unroll
        for (int t = 0; t < 4; ++t) {
            const float xn = leaky(mv[t] / den + bfraw(sk[t]));
            o[t] = xn; ob[t] = rawbf(xn);
        }
        __builtin_nontemporal_store(o, (f32x4*)(out_x + (size_t)n * 256 + ch4 * 4));
        *(ushort4v*)(xnb + (size_t)n * 256 + ch4 * 4) = ob;
    }
}

// ---------------- k3b: per-node MLP projections P = [xn@W1_s | xn@W1_d] ----------------
#define PB_LD 136
__global__ __launch_bounds__(256) void k3b_nodeproj(
    const bf16* __restrict__ xnb, const bf16* __restrict__ W1Tp,
    bf16* __restrict__ P)
{
    __shared__ unsigned short ps_s[64 * PB_LD];   // 17408 B
    const int tid = threadIdx.x;
    const int n0 = blockIdx.x * 64;
    const int w = tid >> 6, l = tid & 63;
    const int row = l & 15, kg = l >> 4;

    // A fragments: node w*16+row (bf16 direct; clamp OOB reads, stores guarded)
    const int nmine = n0 + w * 16 + row;
    const size_t nbase = (size_t)min(nmine, N_NODES - 1) * 256;
    short8b af[8];
    #pragma unroll
    for (int kc = 0; kc < 8; ++kc)
        af[kc] = *(const short8b*)(xnb + nbase + kc * 32 + kg * 8);

    #pragma unroll
    for (int m = 0; m < 2; ++m) {   // 0: src-proj (W1Tp cols 64..319), 1: dst (320..575)
        const int koff = (m == 0) ? 64 : 320;
        #pragma unroll
        for (int ct = 0; ct < 4; ++ct) {
            f32x4 acc = {0.f, 0.f, 0.f, 0.f};
            #pragma unroll
            for (int kc = 0; kc < 8; ++kc) {
                const short8b bfr = *(const short8b*)(W1Tp + (size_t)(ct * 16 + row) * 576 + koff + kc * 32 + kg * 8);
                acc = __builtin_amdgcn_mfma_f32_16x16x32_bf16(af[kc], bfr, acc, 0, 0, 0);
            }
            #pragma unroll
            for (int r = 0; r < 4; ++r)
                ps_s[(w * 16 + kg * 4 + r) * PB_LD + m * 64 + ct * 16 + row] = rawbf(acc[r]);
        }
    }
    __syncthreads();
    // store: per node 128 bf16 = 256B contiguous (cacheable -- k4 gathers it)
    #pragma unroll
    for (int u = 0; u < 4; ++u) {
        const int flat = u * 256 + tid;      // 16B unit; 16 units per node
        const int node = flat >> 4;
        const int c8 = (flat & 15) * 8;
        if (n0 + node < N_NODES) {
            const short8b vdat = *(const short8b*)&ps_s[node * PB_LD + c8];
            *(short8b*)(P + (size_t)(n0 + node) * 128 + c8) = vdat;
        }
    }
}

// ---------------- k4: edge MLP, factorized GEMM1 (K=64) + P gathers ----------------
__global__ __launch_bounds__(256) void k4_edge_mlp(
    const int* __restrict__ ssort, const int* __restrict__ dsort,
    const int* __restrict__ eidsort,
    const bf16* __restrict__ P, const float* __restrict__ ea,
    const bf16* __restrict__ W1Tp, const float* __restrict__ b1,
    const bf16* __restrict__ W2T, const float* __restrict__ b2,
    float* __restrict__ out_e)
{
    __shared__ unsigned short h2_s[4][16 * 72];   // 9216 B, wave-private
    __shared__ unsigned short ea_s[4][16 * 72];   // 9216 B, wave-private ea stash
    const int tid = threadIdx.x;
    const int w = tid >> 6, l = tid & 63;
    const int row = l & 15, kg = l >> 4;
    const int e0 = blockIdx.x * 64;
    const int sl = e0 + w * 16 + row;            // this lane's A-row edge
    const int eg = eidsort[sl];

    int s2[4], d2[4], eg2[4];                    // C-row edges (kg*4+r)
    #pragma unroll
    for (int r = 0; r < 4; ++r) {
        const int cr = e0 + w * 16 + kg * 4 + r;
        s2[r] = ssort[cr]; d2[r] = dsort[cr]; eg2[r] = eidsort[cr];
    }

    // ---- issue all loads up front: 4 ea (nt) + 32 P gathers ----
    const float* pb = ea + (size_t)eg * 64 + kg * 8;
    const f32x4 a0 = __builtin_nontemporal_load((const f32x4*)pb);
    const f32x4 a1 = __builtin_nontemporal_load((const f32x4*)(pb + 4));
    const f32x4 c0 = __builtin_nontemporal_load((const f32x4*)(pb + 32));
    const f32x4 c1 = __builtin_nontemporal_load((const f32x4*)(pb + 36));

    const unsigned short* Pu = (const unsigned short*)P;
    unsigned short psv[4][4], pdv[4][4];
    #pragma unroll
    for (int ct = 0; ct < 4; ++ct)
        #pragma unroll
        for (int r = 0; r < 4; ++r) {
            psv[ct][r] = Pu[(size_t)s2[r] * 128 + ct * 16 + row];
            pdv[ct][r] = Pu[(size_t)d2[r] * 128 + 64 + ct * 16 + row];
        }
    __builtin_amdgcn_sched_barrier(0);   // pin: all loads issued before compute

    const short8b afr0 = pack8(a0, a1);
    const short8b afr1 = pack8(c0, c1);
    // stash bf16 ea tile for the residual epilogue (same-wave in-order)
    *(short8b*)&ea_s[w][row * 72 + kg * 8]      = afr0;
    *(short8b*)&ea_s[w][row * 72 + 32 + kg * 8] = afr1;

    // ---- GEMM1: ea part only, [16 x 64] @ W1_ea -> [16 x 64] ----
    f32x4 acc[4];
    #pragma unroll
    for (int ct = 0; ct < 4; ++ct) {
        const float bvv = b1[ct * 16 + row];
        acc[ct] = (f32x4){bvv, bvv, bvv, bvv};
    }
    #pragma unroll
    for (int kc = 0; kc < 2; ++kc) {
        const short8b af = (kc == 0) ? afr0 : afr1;
        #pragma unroll
        for (int ct = 0; ct < 4; ++ct) {
            const short8b bfr = *(const short8b*)(W1Tp + (size_t)(ct * 16 + row) * 576 + kc * 32 + kg * 8);
            acc[ct] = __builtin_amdgcn_mfma_f32_16x16x32_bf16(af, bfr, acc[ct], 0, 0, 0);
        }
    }
    // add precomputed node projections
    #pragma unroll
    for (int ct = 0; ct < 4; ++ct)
        #pragma unroll
        for (int r = 0; r < 4; ++r)
            acc[ct][r] += bfraw(psv[ct][r]) + bfraw(pdv[ct][r]);

    // h2 = leaky(acc) -> wave-private LDS bounce (same-wave in-order)
    unsigned short* h2 = h2_s[w];
    #pragma unroll
    for (int ct = 0; ct < 4; ++ct)
        #pragma unroll
        for (int r = 0; r < 4; ++r)
            h2[(kg * 4 + r) * 72 + ct * 16 + row] = rawbf(leaky(acc[ct][r]));

    // ---- GEMM2: [16 x 64] @ W2 -> [16 x 64] ----
    f32x4 a2[4];
    #pragma unroll
    for (int ct = 0; ct < 4; ++ct) {
        const float bvv = b2[ct * 16 + row];
        a2[ct] = (f32x4){bvv, bvv, bvv, bvv};
    }
    #pragma unroll
    for (int kc = 0; kc < 2; ++kc) {
        const short8b af = *(const short8b*)&h2[row * 72 + kc * 32 + kg * 8];
        #pragma unroll
        for (int ct = 0; ct < 4; ++ct) {
            const short8b bfr = *(const short8b*)(W2T + (size_t)(ct * 16 + row) * 64 + kc * 32 + kg * 8);
            a2[ct] = __builtin_amdgcn_mfma_f32_16x16x32_bf16(af, bfr, a2[ct], 0, 0, 0);
        }
    }

    // epilogue: out = leaky(ea + h2@W2+b2); ea residual from LDS stash
    #pragma unroll
    for (int ct = 0; ct < 4; ++ct)
        #pragma unroll
        for (int r = 0; r < 4; ++r) {
            const float eav = bfraw(ea_s[w][(kg * 4 + r) * 72 + ct * 16 + row]);
            __builtin_nontemporal_store(leaky(eav + a2[ct][r]),
                                        out_e + (size_t)eg2[r] * 64 + ct * 16 + row);
        }
}

extern "C" void kernel_launch(void* const* d_in, const int* in_sizes, int n_in,
                              void* d_out, int out_size, void* d_ws, size_t ws_size,
                              hipStream_t stream)
{
    const float* x  = (const float*)d_in[0];
    const int*   ei = (const int*)d_in[1];
    const float* ea = (const float*)d_in[2];
    const float* Wq = (const float*)d_in[3];
    const float* bq = (const float*)d_in[4];
    const float* Wk = (const float*)d_in[5];
    const float* bk = (const float*)d_in[6];
    const float* Wv = (const float*)d_in[7];
    const float* bv = (const float*)d_in[8];
    const float* We = (const float*)d_in[9];
    const float* Ws = (const float*)d_in[10];
    const float* bs = (const float*)d_in[11];
    const float* W1 = (const float*)d_in[12];
    const float* b1 = (const float*)d_in[13];
    const float* W2 = (const float*)d_in[14];
    const float* b2 = (const float*)d_in[15];

    char* ws = (char*)d_ws;
    int*   flags  = (int*)ws;                       // 4 KB
    int*   ssort  = (int*)(ws + 4096);
    int*   dsort  = (int*)(ws + 1604096);
    int*   eids   = (int*)(ws + 3204096);
    int*   cursor = (int*)(ws + 4804096);           // end-pointers after kct
    bf16*  WeT    = (bf16*)(ws + 5004096);
    bf16*  W1Tp   = (bf16*)(ws + 5036864);
    bf16*  W2T    = (bf16*)(ws + 5110592);
    bf16*  WT4    = (bf16*)(ws + 5118784);
    bf16*  qb     = (bf16*)(ws + 5643072);
    bf16*  kb     = (bf16*)(ws + 31243072);
    bf16*  vb     = (bf16*)(ws + 56843072);
    bf16*  xnb    = (bf16*)(ws + 82443072);         // x_new bf16 (25.6 MB)
    bf16*  Pp     = (bf16*)(ws + 108100000);        // node projections (12.8 MB)

    float* out_x = (float*)d_out;
    float* out_e = out_x + (size_t)N_NODES * D_NODE;
    bf16*  skipb = (bf16*)out_e;   // bf16 skip staged in edge-out region

    hipMemsetAsync(cursor, 0, N_NODES * 4, stream);       // degree counters

    k0_detect<<<1, 64, 0, stream>>>(ei, flags);
    kcd_degree<<<(N_EDGES + 255) / 256, 256, 0, stream>>>(ei, flags, cursor);
    kcs_scan<<<1, 1024, 0, stream>>>(cursor);
    kct_scatter<<<(N_EDGES + 255) / 256, 256, 0, stream>>>(ei, flags, cursor, ssort, dsort, eids);

    kT_transpose<<<64, 256, 0, stream>>>(We, W1, W2, Wq, Wk, Wv, Ws, WeT, W1Tp, W2T, WT4);

    k1_node_mfma<<<(N_NODES + 63) / 64, 256, 0, stream>>>(
        x, WT4, bq, bk, bv, bs, qb, kb, vb, skipb);

    k2_seg<<<N_NODES / SEG, 256, 0, stream>>>(
        ssort, dsort, eids, cursor, ea, WeT, qb, kb, vb, skipb, out_x, xnb);

    k3b_nodeproj<<<(N_NODES + 63) / 64, 256, 0, stream>>>(xnb, W1Tp, Pp);

    k4_edge_mlp<<<N_EDGES / 64, 256, 0, stream>>>(
        ssort, dsort, eids, Pp, ea, W1Tp, b1, W2T, b2, out_e);
}

// Round 12
// 786.796 us; speedup vs baseline: 1.3649x; 1.0299x over previous
//
#include <hip/hip_runtime.h>
#include <hip/hip_bf16.h>

// GCNBlock: TransformerConv(32 heads, dim 8, edge_dim 64) + EdgeResidualLayer
// N=50000, E=400000, D_NODE=256, D_EDGE=64. FP32 in/out, int64 edge_index.
// Internals: bf16 MFMA (16x16x32) with fp32 accumulate.
//
// Round 12: k2 was latency-bound (272us, 23% of achievable BW, ~2 loads in
// flight per wave in the serial 16-edge attention loop). Fix: prefetch ALL
// 32 k/v row-slices for the wave's 16 edges before the compute loop (64
// VGPR, static unroll via clamped tail indices) + sched_barrier(0) pin --
// same pattern that fixed k4 in round 11.
// Carried: CSR dst-sort, barrier-free k2 (SEG=16, LDS accumulator, fused
// finalize), factorized k4 (k3b node projections), MFMA everywhere, nt
// streams, k1 store-span fix.

#define N_NODES 50000
#define N_EDGES 400000
#define D_NODE 256
#define D_EDGE 64
#define HEADS 32
#define LRELU 0.01f
#define SEG 16          // dst nodes per k2 block

typedef __hip_bfloat16 bf16;
typedef __attribute__((ext_vector_type(8))) short short8b;          // 8 bf16
typedef __attribute__((ext_vector_type(4))) float f32x4;
typedef __attribute__((ext_vector_type(4))) unsigned short ushort4v;

__device__ __forceinline__ float bf2f(bf16 v) { return __bfloat162float(v); }
__device__ __forceinline__ bf16 f2bf(float f) { return __float2bfloat16(f); }
__device__ __forceinline__ float bfraw(unsigned short u) {
    return __uint_as_float(((unsigned int)u) << 16);
}
__device__ __forceinline__ unsigned short rawbf(float f) {
    bf16 t = f2bf(f); return *(unsigned short*)&t;
}
__device__ __forceinline__ float leaky(float v) { return v >= 0.f ? v : LRELU * v; }
__device__ __forceinline__ short8b pack8(const f32x4 a, const f32x4 b) {
    short8b r;
    r[0] = (short)rawbf(a[0]); r[1] = (short)rawbf(a[1]);
    r[2] = (short)rawbf(a[2]); r[3] = (short)rawbf(a[3]);
    r[4] = (short)rawbf(b[0]); r[5] = (short)rawbf(b[1]);
    r[6] = (short)rawbf(b[2]); r[7] = (short)rawbf(b[3]);
    return r;
}

// ---------------- k0: index width detection (1 wave) ----------------
__global__ void k0_detect(const int* __restrict__ ei, int* __restrict__ flags)
{
    const int lane = threadIdx.x;
    const unsigned long long mz = __ballot(ei[2 * lane + 1] == 0);
    if (lane == 0) flags[0] = (__popcll(mz) >= 48) ? 1 : 0;   // 1 => int64
}

__device__ __forceinline__ void load_edge(const int* ei, int f, int i, int& s, int& d)
{
    if (f) {
        const long long* e64 = (const long long*)ei;
        s = (int)e64[i]; d = (int)e64[N_EDGES + i];
    } else {
        s = ei[i]; d = ei[N_EDGES + i];
    }
}

// ---------------- CSR build ----------------
__global__ __launch_bounds__(256) void kcd_degree(
    const int* __restrict__ ei, const int* __restrict__ flags, int* __restrict__ deg)
{
    const int i = blockIdx.x * 256 + threadIdx.x;
    if (i >= N_EDGES) return;
    int s, d; load_edge(ei, flags[0], i, s, d);
    atomicAdd(&deg[d], 1);
}

__global__ __launch_bounds__(1024) void kcs_scan(int* __restrict__ cur)  // deg -> excl. offsets
{
    __shared__ int ps[1024];
    const int t = threadIdx.x;
    const int CH = (N_NODES + 1023) / 1024;   // 49
    const int base = t * CH;
    int sum = 0;
    for (int i = 0; i < CH; ++i) {
        const int n = base + i;
        if (n < N_NODES) sum += cur[n];
    }
    ps[t] = sum;
    __syncthreads();
    for (int off = 1; off < 1024; off <<= 1) {
        const int v = (t >= off) ? ps[t - off] : 0;
        __syncthreads();
        ps[t] += v;
        __syncthreads();
    }
    int excl = (t == 0) ? 0 : ps[t - 1];
    for (int i = 0; i < CH; ++i) {
        const int n = base + i;
        if (n < N_NODES) {
            const int d = cur[n];
            cur[n] = excl;
            excl += d;
        }
    }
}

__global__ __launch_bounds__(256) void kct_scatter(
    const int* __restrict__ ei, const int* __restrict__ flags, int* __restrict__ cursor,
    int* __restrict__ ssort, int* __restrict__ dsort, int* __restrict__ eidsort)
{
    const int i = blockIdx.x * 256 + threadIdx.x;
    if (i >= N_EDGES) return;
    int s, d; load_edge(ei, flags[0], i, s, d);
    const int pos = atomicAdd(&cursor[d], 1);
    ssort[pos] = s; dsort[pos] = d; eidsort[pos] = i;
    // after this kernel: cursor[n] == end offset of node n (inclusive)
}

// ---------------- kT: weight transposes (fp32 -> bf16) ----------------
__global__ __launch_bounds__(256) void kT_transpose(
    const float* __restrict__ We, const float* __restrict__ W1, const float* __restrict__ W2,
    const float* __restrict__ Wq, const float* __restrict__ Wk,
    const float* __restrict__ Wv, const float* __restrict__ Ws,
    bf16* __restrict__ WeT, bf16* __restrict__ W1Tp, bf16* __restrict__ W2T,
    bf16* __restrict__ WT4)
{
    const int gid = blockIdx.x * 256 + threadIdx.x;
    const int gsz = gridDim.x * 256;
    for (int i = gid; i < 256 * 64; i += gsz) {
        const int n = i >> 6, k = i & 63;
        WeT[i] = f2bf(We[k * 256 + n]);
    }
    for (int i = gid; i < 64 * 576; i += gsz) {
        const int n = i / 576, kp = i % 576;
        const int k = (kp < 64) ? (512 + kp) : (kp - 64);
        W1Tp[i] = f2bf(W1[k * 64 + n]);
    }
    for (int i = gid; i < 64 * 64; i += gsz) {
        const int n = i >> 6, k = i & 63;
        W2T[i] = f2bf(W2[k * 64 + n]);
    }
    for (int i = gid; i < 4 * 256 * 256; i += gsz) {
        const int m = i >> 16, rem = i & 65535;
        const int n = rem >> 8, kk = rem & 255;
        const float* W = (m == 0) ? Wq : (m == 1) ? Wk : (m == 2) ? Wv : Ws;
        WT4[i] = f2bf(W[kk * 256 + n]);
    }
}

// ---------------- k1: node linears via MFMA (nt streams, LDS store-bounce) ----------------
#define X_LD 264
__global__ __launch_bounds__(256) void k1_node_mfma(
    const float* __restrict__ x, const bf16* __restrict__ WT4,
    const float* __restrict__ bq, const float* __restrict__ bk,
    const float* __restrict__ bv, const float* __restrict__ bs,
    bf16* __restrict__ qo, bf16* __restrict__ ko, bf16* __restrict__ vo,
    bf16* __restrict__ skipb)
{
    __shared__ unsigned short xs[64 * X_LD];   // 33792 B; reused as result bounce
    const int tid = threadIdx.x;
    const int n0 = blockIdx.x * 64;
    const int e = tid >> 2, t = tid & 3;       // node e, quarter t
    const int nmine = n0 + e;

    { // stage x tile (fp32 -> bf16), nontemporal f32x4 loads
        const f32x4* src = (const f32x4*)(x + (size_t)nmine * 256 + t * 64);
        #pragma unroll
        for (int c = 0; c < 4; ++c) {
            unsigned short tmp[16];
            if (nmine < N_NODES) {
                #pragma unroll
                for (int u = 0; u < 4; ++u) {
                    const f32x4 v = __builtin_nontemporal_load(src + c * 4 + u);
                    tmp[u * 4 + 0] = rawbf(v[0]); tmp[u * 4 + 1] = rawbf(v[1]);
                    tmp[u * 4 + 2] = rawbf(v[2]); tmp[u * 4 + 3] = rawbf(v[3]);
                }
            } else {
                #pragma unroll
                for (int u = 0; u < 16; ++u) tmp[u] = 0;
            }
            *(short8b*)&xs[e * X_LD + t * 64 + c * 16]     = *(short8b*)&tmp[0];
            *(short8b*)&xs[e * X_LD + t * 64 + c * 16 + 8] = *(short8b*)&tmp[8];
        }
    }
    __syncthreads();

    const int w = tid >> 6, l = tid & 63;
    const int row = l & 15, kg = l >> 4;
    short8b af[8];
    #pragma unroll
    for (int kc = 0; kc < 8; ++kc)
        af[kc] = *(const short8b*)&xs[(w * 16 + row) * X_LD + kc * 32 + kg * 8];

    for (int m = 0; m < 4; ++m) {
        const bf16* WT = WT4 + (size_t)m * 65536;
        const float* bias = (m == 0) ? bq : (m == 1) ? bk : (m == 2) ? bv : bs;
        __syncthreads();   // prior LDS reads done
        #pragma unroll 4
        for (int ct = 0; ct < 16; ++ct) {
            const float bvv = bias[ct * 16 + row];
            f32x4 acc = {bvv, bvv, bvv, bvv};
            #pragma unroll
            for (int kc = 0; kc < 8; ++kc) {
                const short8b bfr = *(const short8b*)(WT + (size_t)(ct * 16 + row) * 256 + kc * 32 + kg * 8);
                acc = __builtin_amdgcn_mfma_f32_16x16x32_bf16(af[kc], bfr, acc, 0, 0, 0);
            }
            #pragma unroll
            for (int r = 0; r < 4; ++r)   // bounce: row = local node, col = output col
                xs[(w * 16 + kg * 4 + r) * X_LD + ct * 16 + row] = rawbf(acc[r]);
        }
        __syncthreads();
        { // store phase: per instruction, block writes ONE contiguous 4KB span
            bf16* dst = (m == 0) ? qo : (m == 1) ? ko : (m == 2) ? vo : skipb;
            #pragma unroll
            for (int u = 0; u < 8; ++u) {
                const int flat = u * 256 + tid;     // 16B unit within 32KB tile
                const int node = flat >> 5;         // 32 units (512B) per node
                const int col8 = (flat & 31) * 8;   // bf16 element offset
                if (n0 + node < N_NODES) {
                    const short8b vdat = *(const short8b*)&xs[node * X_LD + col8];
                    __builtin_nontemporal_store(vdat,
                        (short8b*)(dst + (size_t)(n0 + node) * 256 + col8));
                }
            }
        }
    }
}

// ---------------- k2: barrier-free segment attention (k/v prefetch) ----------------
#define EP_LD 264
__global__ __launch_bounds__(256) void k2_seg(
    const int* __restrict__ ssort, const int* __restrict__ dsort,
    const int* __restrict__ eidsort, const int* __restrict__ endptr,
    const float* __restrict__ ea, const bf16* __restrict__ WeT,
    const bf16* __restrict__ q, const bf16* __restrict__ k, const bf16* __restrict__ v,
    const bf16* __restrict__ skipb, float* __restrict__ out_x, bf16* __restrict__ xnb)
{
    __shared__ float acc_s[SEG * 256];            // 16 KB msg accumulator
    __shared__ float den_s[SEG * HEADS];          // 2 KB
    __shared__ unsigned short ep_s[64 * EP_LD];   // 33 KB (wave-private rows)
    const int tid = threadIdx.x;
    const int n0 = blockIdx.x * SEG;

    #pragma unroll
    for (int i = 0; i < SEG; ++i) acc_s[i * 256 + tid] = 0.f;
    if (tid < SEG * HEADS - 256) den_s[256 + tid] = 0.f;
    den_s[tid] = 0.f;

    const int start = (n0 == 0) ? 0 : endptr[n0 - 1];
    const int end   = endptr[n0 + SEG - 1];
    __syncthreads();

    const int w = tid >> 6, l = tid & 63;
    const int row = l & 15, kg = l >> 4;
    const float scale = 0.35355339059327373f;   // 1/sqrt(8)

    // each wave free-runs its own 16-edge slices; no barriers in this loop
    for (int sbase = start + w * 16; sbase < end; sbase += 64) {
        const int cnt = min(16, end - sbase);   // >= 1

        // --- A fragments direct from global ea (fp32 -> bf16 in regs) ---
        short8b af0 = {0, 0, 0, 0, 0, 0, 0, 0}, af1 = af0;
        if (row < cnt) {
            const int eg = eidsort[sbase + row];
            const float* pb = ea + (size_t)eg * 64 + kg * 8;
            const f32x4 a0 = __builtin_nontemporal_load((const f32x4*)pb);
            const f32x4 a1 = __builtin_nontemporal_load((const f32x4*)(pb + 4));
            const f32x4 b0 = __builtin_nontemporal_load((const f32x4*)(pb + 32));
            const f32x4 b1 = __builtin_nontemporal_load((const f32x4*)(pb + 36));
            af0 = pack8(a0, a1); af1 = pack8(b0, b1);
        }

        // --- edge indices for this wave's slice ---
        int sv = 0;
        if (l < 16)      { if (l < cnt)      sv = ssort[sbase + l]; }
        else if (l < 32) { if (l - 16 < cnt) sv = dsort[sbase + (l - 16)]; }

        // --- prefetch ALL 32 k/v row-slices (clamped tail -> static unroll) ---
        ushort4v kvv[16], vvv[16];
        #pragma unroll
        for (int i = 0; i < 16; ++i) {
            const int s = __shfl(sv, min(i, cnt - 1));
            kvv[i] = *(const ushort4v*)(k + (size_t)s * 256 + l * 4);
            vvv[i] = *(const ushort4v*)(v + (size_t)s * 256 + l * 4);
        }
        __builtin_amdgcn_sched_barrier(0);   // pin: all gathers issued

        // --- eproj MFMA into wave-private ep rows ---
        #pragma unroll 4
        for (int ct = 0; ct < 16; ++ct) {
            f32x4 acc = {0.f, 0.f, 0.f, 0.f};
            const short8b b0 = *(const short8b*)(WeT + (size_t)(ct * 16 + row) * 64 + kg * 8);
            const short8b b1 = *(const short8b*)(WeT + (size_t)(ct * 16 + row) * 64 + 32 + kg * 8);
            acc = __builtin_amdgcn_mfma_f32_16x16x32_bf16(af0, b0, acc, 0, 0, 0);
            acc = __builtin_amdgcn_mfma_f32_16x16x32_bf16(af1, b1, acc, 0, 0, 0);
            #pragma unroll
            for (int r = 0; r < 4; ++r)
                ep_s[(w * 16 + kg * 4 + r) * EP_LD + ct * 16 + row] = rawbf(acc[r]);
        }
        // same-wave LDS write->read is in-order: no barrier needed

        // --- attention (run-compressed); all gathers already in regs ---
        float macc[4] = {0.f, 0.f, 0.f, 0.f};
        float dacc = 0.f;
        int dprev = -1;
        ushort4v qv = {0, 0, 0, 0};

        #pragma unroll
        for (int i = 0; i < 16; ++i) {
            const int d = __shfl(sv, 16 + min(i, cnt - 1));
            if (d != dprev) {                  // wave-uniform
                if (dprev >= 0) {
                    const int ld = dprev - n0;
                    #pragma unroll
                    for (int t = 0; t < 4; ++t)
                        atomicAdd(&acc_s[ld * 256 + l * 4 + t], macc[t]);
                    if ((l & 1) == 0)
                        atomicAdd(&den_s[ld * HEADS + (l >> 1)], dacc);
                    macc[0] = macc[1] = macc[2] = macc[3] = 0.f;
                    dacc = 0.f;
                }
                qv = *(const ushort4v*)(q + (size_t)d * 256 + l * 4);
                dprev = d;
            }
            const ushort4v ep = *(const ushort4v*)&ep_s[(w * 16 + i) * EP_LD + l * 4];
            float p = 0.f, m4[4];
            #pragma unroll
            for (int t = 0; t < 4; ++t) {
                const float epf = bfraw(ep[t]);
                p = fmaf(bfraw(qv[t]), bfraw(kvv[i][t]) + epf, p);
                m4[t] = bfraw(vvv[i][t]) + epf;
            }
            p += __shfl_xor(p, 1);             // head = l>>1 (2 lanes/head)
            const float ex = (i < cnt) ? __expf(p * scale) : 0.f;
            #pragma unroll
            for (int t = 0; t < 4; ++t) macc[t] = fmaf(m4[t], ex, macc[t]);
            dacc += ex;
        }
        {
            const int ld = dprev - n0;
            #pragma unroll
            for (int t = 0; t < 4; ++t)
                atomicAdd(&acc_s[ld * 256 + l * 4 + t], macc[t]);
            if ((l & 1) == 0)
                atomicAdd(&den_s[ld * HEADS + (l >> 1)], dacc);
        }
    }
    __syncthreads();   // single barrier: all waves' aggregation done

    // finalize: x_new = leaky(acc/den + skip) -> out_x fp32 + xnb bf16
    #pragma unroll
    for (int u = 0; u < 4; ++u) {
        const int flat4 = u * 256 + tid;        // f32x4 unit; 64 per node
        const int node = flat4 >> 6;
        const int ch4 = flat4 & 63;
        const int n = n0 + node;
        const float den = den_s[node * HEADS + (ch4 >> 1)] + 1e-16f;
        const f32x4 mv = *(const f32x4*)&acc_s[node * 256 + ch4 * 4];
        const ushort4v sk = *(const ushort4v*)(skipb + (size_t)n * 256 + ch4 * 4);
        f32x4 o; ushort4v ob;
        #pragma unroll
        for (int t = 0; t < 4; ++t) {
            const float xn = leaky(mv[t] / den + bfraw(sk[t]));
            o[t] = xn; ob[t] = rawbf(xn);
        }
        __builtin_nontemporal_store(o, (f32x4*)(out_x + (size_t)n * 256 + ch4 * 4));
        *(ushort4v*)(xnb + (size_t)n * 256 + ch4 * 4) = ob;
    }
}

// ---------------- k3b: per-node MLP projections P = [xn@W1_s | xn@W1_d] ----------------
#define PB_LD 136
__global__ __launch_bounds__(256) void k3b_nodeproj(
    const bf16* __restrict__ xnb, const bf16* __restrict__ W1Tp,
    bf16* __restrict__ P)
{
    __shared__ unsigned short ps_s[64 * PB_LD];   // 17408 B
    const int tid = threadIdx.x;
    const int n0 = blockIdx.x * 64;
    const int w = tid >> 6, l = tid & 63;
    const int row = l & 15, kg = l >> 4;

    // A fragments: node w*16+row (bf16 direct; clamp OOB reads, stores guarded)
    const int nmine = n0 + w * 16 + row;
    const size_t nbase = (size_t)min(nmine, N_NODES - 1) * 256;
    short8b af[8];
    #pragma unroll
    for (int kc = 0; kc < 8; ++kc)
        af[kc] = *(const short8b*)(xnb + nbase + kc * 32 + kg * 8);

    #pragma unroll
    for (int m = 0; m < 2; ++m) {   // 0: src-proj (W1Tp cols 64..319), 1: dst (320..575)
        const int koff = (m == 0) ? 64 : 320;
        #pragma unroll
        for (int ct = 0; ct < 4; ++ct) {
            f32x4 acc = {0.f, 0.f, 0.f, 0.f};
            #pragma unroll
            for (int kc = 0; kc < 8; ++kc) {
                const short8b bfr = *(const short8b*)(W1Tp + (size_t)(ct * 16 + row) * 576 + koff + kc * 32 + kg * 8);
                acc = __builtin_amdgcn_mfma_f32_16x16x32_bf16(af[kc], bfr, acc, 0, 0, 0);
            }
            #pragma unroll
            for (int r = 0; r < 4; ++r)
                ps_s[(w * 16 + kg * 4 + r) * PB_LD + m * 64 + ct * 16 + row] = rawbf(acc[r]);
        }
    }
    __syncthreads();
    // store: per node 128 bf16 = 256B contiguous (cacheable -- k4 gathers it)
    #pragma unroll
    for (int u = 0; u < 4; ++u) {
        const int flat = u * 256 + tid;      // 16B unit; 16 units per node
        const int node = flat >> 4;
        const int c8 = (flat & 15) * 8;
        if (n0 + node < N_NODES) {
            const short8b vdat = *(const short8b*)&ps_s[node * PB_LD + c8];
            *(short8b*)(P + (size_t)(n0 + node) * 128 + c8) = vdat;
        }
    }
}

// ---------------- k4: edge MLP, factorized GEMM1 (K=64) + P gathers ----------------
__global__ __launch_bounds__(256) void k4_edge_mlp(
    const int* __restrict__ ssort, const int* __restrict__ dsort,
    const int* __restrict__ eidsort,
    const bf16* __restrict__ P, const float* __restrict__ ea,
    const bf16* __restrict__ W1Tp, const float* __restrict__ b1,
    const bf16* __restrict__ W2T, const float* __restrict__ b2,
    float* __restrict__ out_e)
{
    __shared__ unsigned short h2_s[4][16 * 72];   // 9216 B, wave-private
    __shared__ unsigned short ea_s[4][16 * 72];   // 9216 B, wave-private ea stash
    const int tid = threadIdx.x;
    const int w = tid >> 6, l = tid & 63;
    const int row = l & 15, kg = l >> 4;
    const int e0 = blockIdx.x * 64;
    const int sl = e0 + w * 16 + row;            // this lane's A-row edge
    const int eg = eidsort[sl];

    int s2[4], d2[4], eg2[4];                    // C-row edges (kg*4+r)
    #pragma unroll
    for (int r = 0; r < 4; ++r) {
        const int cr = e0 + w * 16 + kg * 4 + r;
        s2[r] = ssort[cr]; d2[r] = dsort[cr]; eg2[r] = eidsort[cr];
    }

    // ---- issue all loads up front: 4 ea (nt) + 32 P gathers ----
    const float* pb = ea + (size_t)eg * 64 + kg * 8;
    const f32x4 a0 = __builtin_nontemporal_load((const f32x4*)pb);
    const f32x4 a1 = __builtin_nontemporal_load((const f32x4*)(pb + 4));
    const f32x4 c0 = __builtin_nontemporal_load((const f32x4*)(pb + 32));
    const f32x4 c1 = __builtin_nontemporal_load((const f32x4*)(pb + 36));

    const unsigned short* Pu = (const unsigned short*)P;
    unsigned short psv[4][4], pdv[4][4];
    #pragma unroll
    for (int ct = 0; ct < 4; ++ct)
        #pragma unroll
        for (int r = 0; r < 4; ++r) {
            psv[ct][r] = Pu[(size_t)s2[r] * 128 + ct * 16 + row];
            pdv[ct][r] = Pu[(size_t)d2[r] * 128 + 64 + ct * 16 + row];
        }
    __builtin_amdgcn_sched_barrier(0);   // pin: all loads issued before compute

    const short8b afr0 = pack8(a0, a1);
    const short8b afr1 = pack8(c0, c1);
    // stash bf16 ea tile for the residual epilogue (same-wave in-order)
    *(short8b*)&ea_s[w][row * 72 + kg * 8]      = afr0;
    *(short8b*)&ea_s[w][row * 72 + 32 + kg * 8] = afr1;

    // ---- GEMM1: ea part only, [16 x 64] @ W1_ea -> [16 x 64] ----
    f32x4 acc[4];
    #pragma unroll
    for (int ct = 0; ct < 4; ++ct) {
        const float bvv = b1[ct * 16 + row];
        acc[ct] = (f32x4){bvv, bvv, bvv, bvv};
    }
    #pragma unroll
    for (int kc = 0; kc < 2; ++kc) {
        const short8b af = (kc == 0) ? afr0 : afr1;
        #pragma unroll
        for (int ct = 0; ct < 4; ++ct) {
            const short8b bfr = *(const short8b*)(W1Tp + (size_t)(ct * 16 + row) * 576 + kc * 32 + kg * 8);
            acc[ct] = __builtin_amdgcn_mfma_f32_16x16x32_bf16(af, bfr, acc[ct], 0, 0, 0);
        }
    }
    // add precomputed node projections
    #pragma unroll
    for (int ct = 0; ct < 4; ++ct)
        #pragma unroll
        for (int r = 0; r < 4; ++r)
            acc[ct][r] += bfraw(psv[ct][r]) + bfraw(pdv[ct][r]);

    // h2 = leaky(acc) -> wave-private LDS bounce (same-wave in-order)
    unsigned short* h2 = h2_s[w];
    #pragma unroll
    for (int ct = 0; ct < 4; ++ct)
        #pragma unroll
        for (int r = 0; r < 4; ++r)
            h2[(kg * 4 + r) * 72 + ct * 16 + row] = rawbf(leaky(acc[ct][r]));

    // ---- GEMM2: [16 x 64] @ W2 -> [16 x 64] ----
    f32x4 a2[4];
    #pragma unroll
    for (int ct = 0; ct < 4; ++ct) {
        const float bvv = b2[ct * 16 + row];
        a2[ct] = (f32x4){bvv, bvv, bvv, bvv};
    }
    #pragma unroll
    for (int kc = 0; kc < 2; ++kc) {
        const short8b af = *(const short8b*)&h2[row * 72 + kc * 32 + kg * 8];
        #pragma unroll
        for (int ct = 0; ct < 4; ++ct) {
            const short8b bfr = *(const short8b*)(W2T + (size_t)(ct * 16 + row) * 64 + kc * 32 + kg * 8);
            a2[ct] = __builtin_amdgcn_mfma_f32_16x16x32_bf16(af, bfr, a2[ct], 0, 0, 0);
        }
    }

    // epilogue: out = leaky(ea + h2@W2+b2); ea residual from LDS stash
    #pragma unroll
    for (int ct = 0; ct < 4; ++ct)
        #pragma unroll
        for (int r = 0; r < 4; ++r) {
            const float eav = bfraw(ea_s[w][(kg * 4 + r) * 72 + ct * 16 + row]);
            __builtin_nontemporal_store(leaky(eav + a2[ct][r]),
                                        out_e + (size_t)eg2[r] * 64 + ct * 16 + row);
        }
}

extern "C" void kernel_launch(void* const* d_in, const int* in_sizes, int n_in,
                              void* d_out, int out_size, void* d_ws, size_t ws_size,
                              hipStream_t stream)
{
    const float* x  = (const float*)d_in[0];
    const int*   ei = (const int*)d_in[1];
    const float* ea = (const float*)d_in[2];
    const float* Wq = (const float*)d_in[3];
    const float* bq = (const float*)d_in[4];
    const float* Wk = (const float*)d_in[5];
    const float* bk = (const float*)d_in[6];
    const float* Wv = (const float*)d_in[7];
    const float* bv = (const float*)d_in[8];
    const float* We = (const float*)d_in[9];
    const float* Ws = (const float*)d_in[10];
    const float* bs = (const float*)d_in[11];
    const float* W1 = (const float*)d_in[12];
    const float* b1 = (const float*)d_in[13];
    const float* W2 = (const float*)d_in[14];
    const float* b2 = (const float*)d_in[15];

    char* ws = (char*)d_ws;
    int*   flags  = (int*)ws;                       // 4 KB
    int*   ssort  = (int*)(ws + 4096);
    int*   dsort  = (int*)(ws + 1604096);
    int*   eids   = (int*)(ws + 3204096);
    int*   cursor = (int*)(ws + 4804096);           // end-pointers after kct
    bf16*  WeT    = (bf16*)(ws + 5004096);
    bf16*  W1Tp   = (bf16*)(ws + 5036864);
    bf16*  W2T    = (bf16*)(ws + 5110592);
    bf16*  WT4    = (bf16*)(ws + 5118784);
    bf16*  qb     = (bf16*)(ws + 5643072);
    bf16*  kb     = (bf16*)(ws + 31243072);
    bf16*  vb     = (bf16*)(ws + 56843072);
    bf16*  xnb    = (bf16*)(ws + 82443072);         // x_new bf16 (25.6 MB)
    bf16*  Pp     = (bf16*)(ws + 108100000);        // node projections (12.8 MB)

    float* out_x = (float*)d_out;
    float* out_e = out_x + (size_t)N_NODES * D_NODE;
    bf16*  skipb = (bf16*)out_e;   // bf16 skip staged in edge-out region

    hipMemsetAsync(cursor, 0, N_NODES * 4, stream);       // degree counters

    k0_detect<<<1, 64, 0, stream>>>(ei, flags);
    kcd_degree<<<(N_EDGES + 255) / 256, 256, 0, stream>>>(ei, flags, cursor);
    kcs_scan<<<1, 1024, 0, stream>>>(cursor);
    kct_scatter<<<(N_EDGES + 255) / 256, 256, 0, stream>>>(ei, flags, cursor, ssort, dsort, eids);

    kT_transpose<<<64, 256, 0, stream>>>(We, W1, W2, Wq, Wk, Wv, Ws, WeT, W1Tp, W2T, WT4);

    k1_node_mfma<<<(N_NODES + 63) / 64, 256, 0, stream>>>(
        x, WT4, bq, bk, bv, bs, qb, kb, vb, skipb);

    k2_seg<<<N_NODES / SEG, 256, 0, stream>>>(
        ssort, dsort, eids, cursor, ea, WeT, qb, kb, vb, skipb, out_x, xnb);

    k3b_nodeproj<<<(N_NODES + 63) / 64, 256, 0, stream>>>(xnb, W1Tp, Pp);

    k4_edge_mlp<<<N_EDGES / 64, 256, 0, stream>>>(
        ssort, dsort, eids, Pp, ea, W1Tp, b1, W2T, b2, out_e);
}

// Round 13
// 786.517 us; speedup vs baseline: 1.3654x; 1.0004x over previous
//
#include <hip/hip_runtime.h>
#include <hip/hip_bf16.h>

// GCNBlock: TransformerConv(32 heads, dim 8, edge_dim 64) + EdgeResidualLayer
// N=50000, E=400000, D_NODE=256, D_EDGE=64. FP32 in/out, int64 edge_index.
// Internals: bf16 MFMA (16x16x32) with fp32 accumulate.
//
// Round 13: barrier-free k1. All LDS use in k1 is wave-private (staging
// thread tid covers node tid>>2 in its own wave's rows; af reads and the
// MFMA bounce touch the same 16 rows), and the store phase is re-indexed
// per-wave (flat=u*64+l -> 1KB contiguous per instruction). All 9
// __syncthreads deleted -- no more vmcnt(0) barrier drains of ~900cy nt
// stores; 4 waves free-run per block (k1 was 258us at 9% BW, MfmaUtil 4%).
// Carried: CSR dst-sort, barrier-free k2 (SEG=16, k/v prefetch, LDS
// accumulator, fused finalize), factorized k4 (k3b node projections),
// MFMA everywhere, nt streams.

#define N_NODES 50000
#define N_EDGES 400000
#define D_NODE 256
#define D_EDGE 64
#define HEADS 32
#define LRELU 0.01f
#define SEG 16          // dst nodes per k2 block

typedef __hip_bfloat16 bf16;
typedef __attribute__((ext_vector_type(8))) short short8b;          // 8 bf16
typedef __attribute__((ext_vector_type(4))) float f32x4;
typedef __attribute__((ext_vector_type(4))) unsigned short ushort4v;

__device__ __forceinline__ float bf2f(bf16 v) { return __bfloat162float(v); }
__device__ __forceinline__ bf16 f2bf(float f) { return __float2bfloat16(f); }
__device__ __forceinline__ float bfraw(unsigned short u) {
    return __uint_as_float(((unsigned int)u) << 16);
}
__device__ __forceinline__ unsigned short rawbf(float f) {
    bf16 t = f2bf(f); return *(unsigned short*)&t;
}
__device__ __forceinline__ float leaky(float v) { return v >= 0.f ? v : LRELU * v; }
__device__ __forceinline__ short8b pack8(const f32x4 a, const f32x4 b) {
    short8b r;
    r[0] = (short)rawbf(a[0]); r[1] = (short)rawbf(a[1]);
    r[2] = (short)rawbf(a[2]); r[3] = (short)rawbf(a[3]);
    r[4] = (short)rawbf(b[0]); r[5] = (short)rawbf(b[1]);
    r[6] = (short)rawbf(b[2]); r[7] = (short)rawbf(b[3]);
    return r;
}

// ---------------- k0: index width detection (1 wave) ----------------
__global__ void k0_detect(const int* __restrict__ ei, int* __restrict__ flags)
{
    const int lane = threadIdx.x;
    const unsigned long long mz = __ballot(ei[2 * lane + 1] == 0);
    if (lane == 0) flags[0] = (__popcll(mz) >= 48) ? 1 : 0;   // 1 => int64
}

__device__ __forceinline__ void load_edge(const int* ei, int f, int i, int& s, int& d)
{
    if (f) {
        const long long* e64 = (const long long*)ei;
        s = (int)e64[i]; d = (int)e64[N_EDGES + i];
    } else {
        s = ei[i]; d = ei[N_EDGES + i];
    }
}

// ---------------- CSR build ----------------
__global__ __launch_bounds__(256) void kcd_degree(
    const int* __restrict__ ei, const int* __restrict__ flags, int* __restrict__ deg)
{
    const int i = blockIdx.x * 256 + threadIdx.x;
    if (i >= N_EDGES) return;
    int s, d; load_edge(ei, flags[0], i, s, d);
    atomicAdd(&deg[d], 1);
}

__global__ __launch_bounds__(1024) void kcs_scan(int* __restrict__ cur)  // deg -> excl. offsets
{
    __shared__ int ps[1024];
    const int t = threadIdx.x;
    const int CH = (N_NODES + 1023) / 1024;   // 49
    const int base = t * CH;
    int sum = 0;
    for (int i = 0; i < CH; ++i) {
        const int n = base + i;
        if (n < N_NODES) sum += cur[n];
    }
    ps[t] = sum;
    __syncthreads();
    for (int off = 1; off < 1024; off <<= 1) {
        const int v = (t >= off) ? ps[t - off] : 0;
        __syncthreads();
        ps[t] += v;
        __syncthreads();
    }
    int excl = (t == 0) ? 0 : ps[t - 1];
    for (int i = 0; i < CH; ++i) {
        const int n = base + i;
        if (n < N_NODES) {
            const int d = cur[n];
            cur[n] = excl;
            excl += d;
        }
    }
}

__global__ __launch_bounds__(256) void kct_scatter(
    const int* __restrict__ ei, const int* __restrict__ flags, int* __restrict__ cursor,
    int* __restrict__ ssort, int* __restrict__ dsort, int* __restrict__ eidsort)
{
    const int i = blockIdx.x * 256 + threadIdx.x;
    if (i >= N_EDGES) return;
    int s, d; load_edge(ei, flags[0], i, s, d);
    const int pos = atomicAdd(&cursor[d], 1);
    ssort[pos] = s; dsort[pos] = d; eidsort[pos] = i;
    // after this kernel: cursor[n] == end offset of node n (inclusive)
}

// ---------------- kT: weight transposes (fp32 -> bf16) ----------------
__global__ __launch_bounds__(256) void kT_transpose(
    const float* __restrict__ We, const float* __restrict__ W1, const float* __restrict__ W2,
    const float* __restrict__ Wq, const float* __restrict__ Wk,
    const float* __restrict__ Wv, const float* __restrict__ Ws,
    bf16* __restrict__ WeT, bf16* __restrict__ W1Tp, bf16* __restrict__ W2T,
    bf16* __restrict__ WT4)
{
    const int gid = blockIdx.x * 256 + threadIdx.x;
    const int gsz = gridDim.x * 256;
    for (int i = gid; i < 256 * 64; i += gsz) {
        const int n = i >> 6, k = i & 63;
        WeT[i] = f2bf(We[k * 256 + n]);
    }
    for (int i = gid; i < 64 * 576; i += gsz) {
        const int n = i / 576, kp = i % 576;
        const int k = (kp < 64) ? (512 + kp) : (kp - 64);
        W1Tp[i] = f2bf(W1[k * 64 + n]);
    }
    for (int i = gid; i < 64 * 64; i += gsz) {
        const int n = i >> 6, k = i & 63;
        W2T[i] = f2bf(W2[k * 64 + n]);
    }
    for (int i = gid; i < 4 * 256 * 256; i += gsz) {
        const int m = i >> 16, rem = i & 65535;
        const int n = rem >> 8, kk = rem & 255;
        const float* W = (m == 0) ? Wq : (m == 1) ? Wk : (m == 2) ? Wv : Ws;
        WT4[i] = f2bf(W[kk * 256 + n]);
    }
}

// ---------------- k1: node linears via MFMA (barrier-free, wave-private) ----------------
#define X_LD 264
__global__ __launch_bounds__(256) void k1_node_mfma(
    const float* __restrict__ x, const bf16* __restrict__ WT4,
    const float* __restrict__ bq, const float* __restrict__ bk,
    const float* __restrict__ bv, const float* __restrict__ bs,
    bf16* __restrict__ qo, bf16* __restrict__ ko, bf16* __restrict__ vo,
    bf16* __restrict__ skipb)
{
    __shared__ unsigned short xs[64 * X_LD];   // 33792 B; rows wave-private
    const int tid = threadIdx.x;
    const int n0 = blockIdx.x * 64;
    const int w = tid >> 6, l = tid & 63;
    const int row = l & 15, kg = l >> 4;

    { // stage x tile (fp32 -> bf16), nt loads; node e = w*16+(l>>2) is in
      // this wave's own row range -> wave-private, no barrier needed
        const int e = tid >> 2, t = tid & 3;
        const int nmine = n0 + e;
        const f32x4* src = (const f32x4*)(x + (size_t)nmine * 256 + t * 64);
        #pragma unroll
        for (int c = 0; c < 4; ++c) {
            unsigned short tmp[16];
            if (nmine < N_NODES) {
                #pragma unroll
                for (int u = 0; u < 4; ++u) {
                    const f32x4 v = __builtin_nontemporal_load(src + c * 4 + u);
                    tmp[u * 4 + 0] = rawbf(v[0]); tmp[u * 4 + 1] = rawbf(v[1]);
                    tmp[u * 4 + 2] = rawbf(v[2]); tmp[u * 4 + 3] = rawbf(v[3]);
                }
            } else {
                #pragma unroll
                for (int u = 0; u < 16; ++u) tmp[u] = 0;
            }
            *(short8b*)&xs[e * X_LD + t * 64 + c * 16]     = *(short8b*)&tmp[0];
            *(short8b*)&xs[e * X_LD + t * 64 + c * 16 + 8] = *(short8b*)&tmp[8];
        }
    }
    // same-wave DS ops are in-order: staging writes precede these reads
    short8b af[8];
    #pragma unroll
    for (int kc = 0; kc < 8; ++kc)
        af[kc] = *(const short8b*)&xs[(w * 16 + row) * X_LD + kc * 32 + kg * 8];

    for (int m = 0; m < 4; ++m) {
        const bf16* WT = WT4 + (size_t)m * 65536;
        const float* bias = (m == 0) ? bq : (m == 1) ? bk : (m == 2) ? bv : bs;
        #pragma unroll 4
        for (int ct = 0; ct < 16; ++ct) {
            const float bvv = bias[ct * 16 + row];
            f32x4 acc = {bvv, bvv, bvv, bvv};
            #pragma unroll
            for (int kc = 0; kc < 8; ++kc) {
                const short8b bfr = *(const short8b*)(WT + (size_t)(ct * 16 + row) * 256 + kc * 32 + kg * 8);
                acc = __builtin_amdgcn_mfma_f32_16x16x32_bf16(af[kc], bfr, acc, 0, 0, 0);
            }
            #pragma unroll
            for (int r = 0; r < 4; ++r)   // bounce into this wave's own rows
                xs[(w * 16 + kg * 4 + r) * X_LD + ct * 16 + row] = rawbf(acc[r]);
        }
        { // per-wave store: each instruction writes 1KB contiguous (2 nodes)
            bf16* dst = (m == 0) ? qo : (m == 1) ? ko : (m == 2) ? vo : skipb;
            #pragma unroll
            for (int u = 0; u < 8; ++u) {
                const int flat = u * 64 + l;          // 16B unit in wave's 8KB
                const int node = w * 16 + (flat >> 5);
                const int col8 = (flat & 31) * 8;
                if (n0 + node < N_NODES) {
                    const short8b vdat = *(const short8b*)&xs[node * X_LD + col8];
                    __builtin_nontemporal_store(vdat,
                        (short8b*)(dst + (size_t)(n0 + node) * 256 + col8));
                }
            }
        }
        // no barrier: same-wave DS in-order (store reads before next bounce
        // writes); waves never touch each other's rows
    }
}

// ---------------- k2: barrier-free segment attention (k/v prefetch) ----------------
#define EP_LD 264
__global__ __launch_bounds__(256) void k2_seg(
    const int* __restrict__ ssort, const int* __restrict__ dsort,
    const int* __restrict__ eidsort, const int* __restrict__ endptr,
    const float* __restrict__ ea, const bf16* __restrict__ WeT,
    const bf16* __restrict__ q, const bf16* __restrict__ k, const bf16* __restrict__ v,
    const bf16* __restrict__ skipb, float* __restrict__ out_x, bf16* __restrict__ xnb)
{
    __shared__ float acc_s[SEG * 256];            // 16 KB msg accumulator
    __shared__ float den_s[SEG * HEADS];          // 2 KB
    __shared__ unsigned short ep_s[64 * EP_LD];   // 33 KB (wave-private rows)
    const int tid = threadIdx.x;
    const int n0 = blockIdx.x * SEG;

    #pragma unroll
    for (int i = 0; i < SEG; ++i) acc_s[i * 256 + tid] = 0.f;
    if (tid < SEG * HEADS - 256) den_s[256 + tid] = 0.f;
    den_s[tid] = 0.f;

    const int start = (n0 == 0) ? 0 : endptr[n0 - 1];
    const int end   = endptr[n0 + SEG - 1];
    __syncthreads();

    const int w = tid >> 6, l = tid & 63;
    const int row = l & 15, kg = l >> 4;
    const float scale = 0.35355339059327373f;   // 1/sqrt(8)

    // each wave free-runs its own 16-edge slices; no barriers in this loop
    for (int sbase = start + w * 16; sbase < end; sbase += 64) {
        const int cnt = min(16, end - sbase);   // >= 1

        // --- A fragments direct from global ea (fp32 -> bf16 in regs) ---
        short8b af0 = {0, 0, 0, 0, 0, 0, 0, 0}, af1 = af0;
        if (row < cnt) {
            const int eg = eidsort[sbase + row];
            const float* pb = ea + (size_t)eg * 64 + kg * 8;
            const f32x4 a0 = __builtin_nontemporal_load((const f32x4*)pb);
            const f32x4 a1 = __builtin_nontemporal_load((const f32x4*)(pb + 4));
            const f32x4 b0 = __builtin_nontemporal_load((const f32x4*)(pb + 32));
            const f32x4 b1 = __builtin_nontemporal_load((const f32x4*)(pb + 36));
            af0 = pack8(a0, a1); af1 = pack8(b0, b1);
        }

        // --- edge indices for this wave's slice ---
        int sv = 0;
        if (l < 16)      { if (l < cnt)      sv = ssort[sbase + l]; }
        else if (l < 32) { if (l - 16 < cnt) sv = dsort[sbase + (l - 16)]; }

        // --- prefetch ALL 32 k/v row-slices (clamped tail -> static unroll) ---
        ushort4v kvv[16], vvv[16];
        #pragma unroll
        for (int i = 0; i < 16; ++i) {
            const int s = __shfl(sv, min(i, cnt - 1));
            kvv[i] = *(const ushort4v*)(k + (size_t)s * 256 + l * 4);
            vvv[i] = *(const ushort4v*)(v + (size_t)s * 256 + l * 4);
        }
        __builtin_amdgcn_sched_barrier(0);   // pin: all gathers issued

        // --- eproj MFMA into wave-private ep rows ---
        #pragma unroll 4
        for (int ct = 0; ct < 16; ++ct) {
            f32x4 acc = {0.f, 0.f, 0.f, 0.f};
            const short8b b0 = *(const short8b*)(WeT + (size_t)(ct * 16 + row) * 64 + kg * 8);
            const short8b b1 = *(const short8b*)(WeT + (size_t)(ct * 16 + row) * 64 + 32 + kg * 8);
            acc = __builtin_amdgcn_mfma_f32_16x16x32_bf16(af0, b0, acc, 0, 0, 0);
            acc = __builtin_amdgcn_mfma_f32_16x16x32_bf16(af1, b1, acc, 0, 0, 0);
            #pragma unroll
            for (int r = 0; r < 4; ++r)
                ep_s[(w * 16 + kg * 4 + r) * EP_LD + ct * 16 + row] = rawbf(acc[r]);
        }
        // same-wave LDS write->read is in-order: no barrier needed

        // --- attention (run-compressed); all gathers already in regs ---
        float macc[4] = {0.f, 0.f, 0.f, 0.f};
        float dacc = 0.f;
        int dprev = -1;
        ushort4v qv = {0, 0, 0, 0};

        #pragma unroll
        for (int i = 0; i < 16; ++i) {
            const int d = __shfl(sv, 16 + min(i, cnt - 1));
            if (d != dprev) {                  // wave-uniform
                if (dprev >= 0) {
                    const int ld = dprev - n0;
                    #pragma unroll
                    for (int t = 0; t < 4; ++t)
                        atomicAdd(&acc_s[ld * 256 + l * 4 + t], macc[t]);
                    if ((l & 1) == 0)
                        atomicAdd(&den_s[ld * HEADS + (l >> 1)], dacc);
                    macc[0] = macc[1] = macc[2] = macc[3] = 0.f;
                    dacc = 0.f;
                }
                qv = *(const ushort4v*)(q + (size_t)d * 256 + l * 4);
                dprev = d;
            }
            const ushort4v ep = *(const ushort4v*)&ep_s[(w * 16 + i) * EP_LD + l * 4];
            float p = 0.f, m4[4];
            #pragma unroll
            for (int t = 0; t < 4; ++t) {
                const float epf = bfraw(ep[t]);
                p = fmaf(bfraw(qv[t]), bfraw(kvv[i][t]) + epf, p);
                m4[t] = bfraw(vvv[i][t]) + epf;
            }
            p += __shfl_xor(p, 1);             // head = l>>1 (2 lanes/head)
            const float ex = (i < cnt) ? __expf(p * scale) : 0.f;
            #pragma unroll
            for (int t = 0; t < 4; ++t) macc[t] = fmaf(m4[t], ex, macc[t]);
            dacc += ex;
        }
        {
            const int ld = dprev - n0;
            #pragma unroll
            for (int t = 0; t < 4; ++t)
                atomicAdd(&acc_s[ld * 256 + l * 4 + t], macc[t]);
            if ((l & 1) == 0)
                atomicAdd(&den_s[ld * HEADS + (l >> 1)], dacc);
        }
    }
    __syncthreads();   // single barrier: all waves' aggregation done

    // finalize: x_new = leaky(acc/den + skip) -> out_x fp32 + xnb bf16
    #pragma unroll
    for (int u = 0; u < 4; ++u) {
        const int flat4 = u * 256 + tid;        // f32x4 unit; 64 per node
        const int node = flat4 >> 6;
        const int ch4 = flat4 & 63;
        const int n = n0 + node;
        const float den = den_s[node * HEADS + (ch4 >> 1)] + 1e-16f;
        const f32x4 mv = *(const f32x4*)&acc_s[node * 256 + ch4 * 4];
        const ushort4v sk = *(const ushort4v*)(skipb + (size_t)n * 256 + ch4 * 4);
        f32x4 o; ushort4v ob;
        #pragma unroll
        for (int t = 0; t < 4; ++t) {
            const float xn = leaky(mv[t] / den + bfraw(sk[t]));
            o[t] = xn; ob[t] = rawbf(xn);
        }
        __builtin_nontemporal_store(o, (f32x4*)(out_x + (size_t)n * 256 + ch4 * 4));
        *(ushort4v*)(xnb + (size_t)n * 256 + ch4 * 4) = ob;
    }
}

// ---------------- k3b: per-node MLP projections P = [xn@W1_s | xn@W1_d] ----------------
#define PB_LD 136
__global__ __launch_bounds__(256) void k3b_nodeproj(
    const bf16* __restrict__ xnb, const bf16* __restrict__ W1Tp,
    bf16* __restrict__ P)
{
    __shared__ unsigned short ps_s[64 * PB_LD];   // 17408 B
    const int tid = threadIdx.x;
    const int n0 = blockIdx.x * 64;
    const int w = tid >> 6, l = tid & 63;
    const int row = l & 15, kg = l >> 4;

    // A fragments: node w*16+row (bf16 direct; clamp OOB reads, stores guarded)
    const int nmine = n0 + w * 16 + row;
    const size_t nbase = (size_t)min(nmine, N_NODES - 1) * 256;
    short8b af[8];
    #pragma unroll
    for (int kc = 0; kc < 8; ++kc)
        af[kc] = *(const short8b*)(xnb + nbase + kc * 32 + kg * 8);

    #pragma unroll
    for (int m = 0; m < 2; ++m) {   // 0: src-proj (W1Tp cols 64..319), 1: dst (320..575)
        const int koff = (m == 0) ? 64 : 320;
        #pragma unroll
        for (int ct = 0; ct < 4; ++ct) {
            f32x4 acc = {0.f, 0.f, 0.f, 0.f};
            #pragma unroll
            for (int kc = 0; kc < 8; ++kc) {
                const short8b bfr = *(const short8b*)(W1Tp + (size_t)(ct * 16 + row) * 576 + koff + kc * 32 + kg * 8);
                acc = __builtin_amdgcn_mfma_f32_16x16x32_bf16(af[kc], bfr, acc, 0, 0, 0);
            }
            #pragma unroll
            for (int r = 0; r < 4; ++r)
                ps_s[(w * 16 + kg * 4 + r) * PB_LD + m * 64 + ct * 16 + row] = rawbf(acc[r]);
        }
    }
    __syncthreads();
    // store: per node 128 bf16 = 256B contiguous (cacheable -- k4 gathers it)
    #pragma unroll
    for (int u = 0; u < 4; ++u) {
        const int flat = u * 256 + tid;      // 16B unit; 16 units per node
        const int node = flat >> 4;
        const int c8 = (flat & 15) * 8;
        if (n0 + node < N_NODES) {
            const short8b vdat = *(const short8b*)&ps_s[node * PB_LD + c8];
            *(short8b*)(P + (size_t)(n0 + node) * 128 + c8) = vdat;
        }
    }
}

// ---------------- k4: edge MLP, factorized GEMM1 (K=64) + P gathers ----------------
__global__ __launch_bounds__(256) void k4_edge_mlp(
    const int* __restrict__ ssort, const int* __restrict__ dsort,
    const int* __restrict__ eidsort,
    const bf16* __restrict__ P, const float* __restrict__ ea,
    const bf16* __restrict__ W1Tp, const float* __restrict__ b1,
    const bf16* __restrict__ W2T, const float* __restrict__ b2,
    float* __restrict__ out_e)
{
    __shared__ unsigned short h2_s[4][16 * 72];   // 9216 B, wave-private
    __shared__ unsigned short ea_s[4][16 * 72];   // 9216 B, wave-private ea stash
    const int tid = threadIdx.x;
    const int w = tid >> 6, l = tid & 63;
    const int row = l & 15, kg = l >> 4;
    const int e0 = blockIdx.x * 64;
    const int sl = e0 + w * 16 + row;            // this lane's A-row edge
    const int eg = eidsort[sl];

    int s2[4], d2[4], eg2[4];                    // C-row edges (kg*4+r)
    #pragma unroll
    for (int r = 0; r < 4; ++r) {
        const int cr = e0 + w * 16 + kg * 4 + r;
        s2[r] = ssort[cr]; d2[r] = dsort[cr]; eg2[r] = eidsort[cr];
    }

    // ---- issue all loads up front: 4 ea (nt) + 32 P gathers ----
    const float* pb = ea + (size_t)eg * 64 + kg * 8;
    const f32x4 a0 = __builtin_nontemporal_load((const f32x4*)pb);
    const f32x4 a1 = __builtin_nontemporal_load((const f32x4*)(pb + 4));
    const f32x4 c0 = __builtin_nontemporal_load((const f32x4*)(pb + 32));
    const f32x4 c1 = __builtin_nontemporal_load((const f32x4*)(pb + 36));

    const unsigned short* Pu = (const unsigned short*)P;
    unsigned short psv[4][4], pdv[4][4];
    #pragma unroll
    for (int ct = 0; ct < 4; ++ct)
        #pragma unroll
        for (int r = 0; r < 4; ++r) {
            psv[ct][r] = Pu[(size_t)s2[r] * 128 + ct * 16 + row];
            pdv[ct][r] = Pu[(size_t)d2[r] * 128 + 64 + ct * 16 + row];
        }
    __builtin_amdgcn_sched_barrier(0);   // pin: all loads issued before compute

    const short8b afr0 = pack8(a0, a1);
    const short8b afr1 = pack8(c0, c1);
    // stash bf16 ea tile for the residual epilogue (same-wave in-order)
    *(short8b*)&ea_s[w][row * 72 + kg * 8]      = afr0;
    *(short8b*)&ea_s[w][row * 72 + 32 + kg * 8] = afr1;

    // ---- GEMM1: ea part only, [16 x 64] @ W1_ea -> [16 x 64] ----
    f32x4 acc[4];
    #pragma unroll
    for (int ct = 0; ct < 4; ++ct) {
        const float bvv = b1[ct * 16 + row];
        acc[ct] = (f32x4){bvv, bvv, bvv, bvv};
    }
    #pragma unroll
    for (int kc = 0; kc < 2; ++kc) {
        const short8b af = (kc == 0) ? afr0 : afr1;
        #pragma unroll
        for (int ct = 0; ct < 4; ++ct) {
            const short8b bfr = *(const short8b*)(W1Tp + (size_t)(ct * 16 + row) * 576 + kc * 32 + kg * 8);
            acc[ct] = __builtin_amdgcn_mfma_f32_16x16x32_bf16(af, bfr, acc[ct], 0, 0, 0);
        }
    }
    // add precomputed node projections
    #pragma unroll
    for (int ct = 0; ct < 4; ++ct)
        #pragma unroll
        for (int r = 0; r < 4; ++r)
            acc[ct][r] += bfraw(psv[ct][r]) + bfraw(pdv[ct][r]);

    // h2 = leaky(acc) -> wave-private LDS bounce (same-wave in-order)
    unsigned short* h2 = h2_s[w];
    #pragma unroll
    for (int ct = 0; ct < 4; ++ct)
        #pragma unroll
        for (int r = 0; r < 4; ++r)
            h2[(kg * 4 + r) * 72 + ct * 16 + row] = rawbf(leaky(acc[ct][r]));

    // ---- GEMM2: [16 x 64] @ W2 -> [16 x 64] ----
    f32x4 a2[4];
    #pragma unroll
    for (int ct = 0; ct < 4; ++ct) {
        const float bvv = b2[ct * 16 + row];
        a2[ct] = (f32x4){bvv, bvv, bvv, bvv};
    }
    #pragma unroll
    for (int kc = 0; kc < 2; ++kc) {
        const short8b af = *(const short8b*)&h2[row * 72 + kc * 32 + kg * 8];
        #pragma unroll
        for (int ct = 0; ct < 4; ++ct) {
            const short8b bfr = *(const short8b*)(W2T + (size_t)(ct * 16 + row) * 64 + kc * 32 + kg * 8);
            a2[ct] = __builtin_amdgcn_mfma_f32_16x16x32_bf16(af, bfr, a2[ct], 0, 0, 0);
        }
    }

    // epilogue: out = leaky(ea + h2@W2+b2); ea residual from LDS stash
    #pragma unroll
    for (int ct = 0; ct < 4; ++ct)
        #pragma unroll
        for (int r = 0; r < 4; ++r) {
            const float eav = bfraw(ea_s[w][(kg * 4 + r) * 72 + ct * 16 + row]);
            __builtin_nontemporal_store(leaky(eav + a2[ct][r]),
                                        out_e + (size_t)eg2[r] * 64 + ct * 16 + row);
        }
}

extern "C" void kernel_launch(void* const* d_in, const int* in_sizes, int n_in,
                              void* d_out, int out_size, void* d_ws, size_t ws_size,
                              hipStream_t stream)
{
    const float* x  = (const float*)d_in[0];
    const int*   ei = (const int*)d_in[1];
    const float* ea = (const float*)d_in[2];
    const float* Wq = (const float*)d_in[3];
    const float* bq = (const float*)d_in[4];
    const float* Wk = (const float*)d_in[5];
    const float* bk = (const float*)d_in[6];
    const float* Wv = (const float*)d_in[7];
    const float* bv = (const float*)d_in[8];
    const float* We = (const float*)d_in[9];
    const float* Ws = (const float*)d_in[10];
    const float* bs = (const float*)d_in[11];
    const float* W1 = (const float*)d_in[12];
    const float* b1 = (const float*)d_in[13];
    const float* W2 = (const float*)d_in[14];
    const float* b2 = (const float*)d_in[15];

    char* ws = (char*)d_ws;
    int*   flags  = (int*)ws;                       // 4 KB
    int*   ssort  = (int*)(ws + 4096);
    int*   dsort  = (int*)(ws + 1604096);
    int*   eids   = (int*)(ws + 3204096);
    int*   cursor = (int*)(ws + 4804096);           // end-pointers after kct
    bf16*  WeT    = (bf16*)(ws + 5004096);
    bf16*  W1Tp   = (bf16*)(ws + 5036864);
    bf16*  W2T    = (bf16*)(ws + 5110592);
    bf16*  WT4    = (bf16*)(ws + 5118784);
    bf16*  qb     = (bf16*)(ws + 5643072);
    bf16*  kb     = (bf16*)(ws + 31243072);
    bf16*  vb     = (bf16*)(ws + 56843072);
    bf16*  xnb    = (bf16*)(ws + 82443072);         // x_new bf16 (25.6 MB)
    bf16*  Pp     = (bf16*)(ws + 108100000);        // node projections (12.8 MB)

    float* out_x = (float*)d_out;
    float* out_e = out_x + (size_t)N_NODES * D_NODE;
    bf16*  skipb = (bf16*)out_e;   // bf16 skip staged in edge-out region

    hipMemsetAsync(cursor, 0, N_NODES * 4, stream);       // degree counters

    k0_detect<<<1, 64, 0, stream>>>(ei, flags);
    kcd_degree<<<(N_EDGES + 255) / 256, 256, 0, stream>>>(ei, flags, cursor);
    kcs_scan<<<1, 1024, 0, stream>>>(cursor);
    kct_scatter<<<(N_EDGES + 255) / 256, 256, 0, stream>>>(ei, flags, cursor, ssort, dsort, eids);

    kT_transpose<<<64, 256, 0, stream>>>(We, W1, W2, Wq, Wk, Wv, Ws, WeT, W1Tp, W2T, WT4);

    k1_node_mfma<<<(N_NODES + 63) / 64, 256, 0, stream>>>(
        x, WT4, bq, bk, bv, bs, qb, kb, vb, skipb);

    k2_seg<<<N_NODES / SEG, 256, 0, stream>>>(
        ssort, dsort, eids, cursor, ea, WeT, qb, kb, vb, skipb, out_x, xnb);

    k3b_nodeproj<<<(N_NODES + 63) / 64, 256, 0, stream>>>(xnb, W1Tp, Pp);

    k4_edge_mlp<<<N_EDGES / 64, 256, 0, stream>>>(
        ssort, dsort, eids, Pp, ea, W1Tp, b1, W2T, b2, out_e);
}

// Round 14
// 770.973 us; speedup vs baseline: 1.3929x; 1.0202x over previous
//
#include <hip/hip_runtime.h>
#include <hip/hip_bf16.h>

// GCNBlock: TransformerConv(32 heads, dim 8, edge_dim 64) + EdgeResidualLayer
// N=50000, E=400000, D_NODE=256, D_EDGE=64. FP32 in/out, int64 edge_index.
// Internals: bf16 MFMA (16x16x32) with fp32 accumulate.
//
// Round 14: nt-store -> cached-store everywhere. k1 stuck at ~260us with
// WRITE 103MB at 0.40 TB/s = the nt direct-to-HBM outstanding-write queue
// ceiling (nt bypasses L2 write-combining; ~16 lines in flight x 900cy).
// Cached stores complete into L2 and write back at full BW. nt LOADS stay
// (they fixed the round-5 weight eviction: FETCH 499->35MB).
// Carried: CSR dst-sort, barrier-free k1/k2, k/v + P prefetch w/
// sched_barrier pin, factorized k4 (k3b node projections), MFMA everywhere.

#define N_NODES 50000
#define N_EDGES 400000
#define D_NODE 256
#define D_EDGE 64
#define HEADS 32
#define LRELU 0.01f
#define SEG 16          // dst nodes per k2 block

typedef __hip_bfloat16 bf16;
typedef __attribute__((ext_vector_type(8))) short short8b;          // 8 bf16
typedef __attribute__((ext_vector_type(4))) float f32x4;
typedef __attribute__((ext_vector_type(4))) unsigned short ushort4v;

__device__ __forceinline__ float bf2f(bf16 v) { return __bfloat162float(v); }
__device__ __forceinline__ bf16 f2bf(float f) { return __float2bfloat16(f); }
__device__ __forceinline__ float bfraw(unsigned short u) {
    return __uint_as_float(((unsigned int)u) << 16);
}
__device__ __forceinline__ unsigned short rawbf(float f) {
    bf16 t = f2bf(f); return *(unsigned short*)&t;
}
__device__ __forceinline__ float leaky(float v) { return v >= 0.f ? v : LRELU * v; }
__device__ __forceinline__ short8b pack8(const f32x4 a, const f32x4 b) {
    short8b r;
    r[0] = (short)rawbf(a[0]); r[1] = (short)rawbf(a[1]);
    r[2] = (short)rawbf(a[2]); r[3] = (short)rawbf(a[3]);
    r[4] = (short)rawbf(b[0]); r[5] = (short)rawbf(b[1]);
    r[6] = (short)rawbf(b[2]); r[7] = (short)rawbf(b[3]);
    return r;
}

// ---------------- k0: index width detection (1 wave) ----------------
__global__ void k0_detect(const int* __restrict__ ei, int* __restrict__ flags)
{
    const int lane = threadIdx.x;
    const unsigned long long mz = __ballot(ei[2 * lane + 1] == 0);
    if (lane == 0) flags[0] = (__popcll(mz) >= 48) ? 1 : 0;   // 1 => int64
}

__device__ __forceinline__ void load_edge(const int* ei, int f, int i, int& s, int& d)
{
    if (f) {
        const long long* e64 = (const long long*)ei;
        s = (int)e64[i]; d = (int)e64[N_EDGES + i];
    } else {
        s = ei[i]; d = ei[N_EDGES + i];
    }
}

// ---------------- CSR build ----------------
__global__ __launch_bounds__(256) void kcd_degree(
    const int* __restrict__ ei, const int* __restrict__ flags, int* __restrict__ deg)
{
    const int i = blockIdx.x * 256 + threadIdx.x;
    if (i >= N_EDGES) return;
    int s, d; load_edge(ei, flags[0], i, s, d);
    atomicAdd(&deg[d], 1);
}

__global__ __launch_bounds__(1024) void kcs_scan(int* __restrict__ cur)  // deg -> excl. offsets
{
    __shared__ int ps[1024];
    const int t = threadIdx.x;
    const int CH = (N_NODES + 1023) / 1024;   // 49
    const int base = t * CH;
    int sum = 0;
    for (int i = 0; i < CH; ++i) {
        const int n = base + i;
        if (n < N_NODES) sum += cur[n];
    }
    ps[t] = sum;
    __syncthreads();
    for (int off = 1; off < 1024; off <<= 1) {
        const int v = (t >= off) ? ps[t - off] : 0;
        __syncthreads();
        ps[t] += v;
        __syncthreads();
    }
    int excl = (t == 0) ? 0 : ps[t - 1];
    for (int i = 0; i < CH; ++i) {
        const int n = base + i;
        if (n < N_NODES) {
            const int d = cur[n];
            cur[n] = excl;
            excl += d;
        }
    }
}

__global__ __launch_bounds__(256) void kct_scatter(
    const int* __restrict__ ei, const int* __restrict__ flags, int* __restrict__ cursor,
    int* __restrict__ ssort, int* __restrict__ dsort, int* __restrict__ eidsort)
{
    const int i = blockIdx.x * 256 + threadIdx.x;
    if (i >= N_EDGES) return;
    int s, d; load_edge(ei, flags[0], i, s, d);
    const int pos = atomicAdd(&cursor[d], 1);
    ssort[pos] = s; dsort[pos] = d; eidsort[pos] = i;
    // after this kernel: cursor[n] == end offset of node n (inclusive)
}

// ---------------- kT: weight transposes (fp32 -> bf16) ----------------
__global__ __launch_bounds__(256) void kT_transpose(
    const float* __restrict__ We, const float* __restrict__ W1, const float* __restrict__ W2,
    const float* __restrict__ Wq, const float* __restrict__ Wk,
    const float* __restrict__ Wv, const float* __restrict__ Ws,
    bf16* __restrict__ WeT, bf16* __restrict__ W1Tp, bf16* __restrict__ W2T,
    bf16* __restrict__ WT4)
{
    const int gid = blockIdx.x * 256 + threadIdx.x;
    const int gsz = gridDim.x * 256;
    for (int i = gid; i < 256 * 64; i += gsz) {
        const int n = i >> 6, k = i & 63;
        WeT[i] = f2bf(We[k * 256 + n]);
    }
    for (int i = gid; i < 64 * 576; i += gsz) {
        const int n = i / 576, kp = i % 576;
        const int k = (kp < 64) ? (512 + kp) : (kp - 64);
        W1Tp[i] = f2bf(W1[k * 64 + n]);
    }
    for (int i = gid; i < 64 * 64; i += gsz) {
        const int n = i >> 6, k = i & 63;
        W2T[i] = f2bf(W2[k * 64 + n]);
    }
    for (int i = gid; i < 4 * 256 * 256; i += gsz) {
        const int m = i >> 16, rem = i & 65535;
        const int n = rem >> 8, kk = rem & 255;
        const float* W = (m == 0) ? Wq : (m == 1) ? Wk : (m == 2) ? Wv : Ws;
        WT4[i] = f2bf(W[kk * 256 + n]);
    }
}

// ---------------- k1: node linears via MFMA (barrier-free, cached stores) ----------------
#define X_LD 264
__global__ __launch_bounds__(256) void k1_node_mfma(
    const float* __restrict__ x, const bf16* __restrict__ WT4,
    const float* __restrict__ bq, const float* __restrict__ bk,
    const float* __restrict__ bv, const float* __restrict__ bs,
    bf16* __restrict__ qo, bf16* __restrict__ ko, bf16* __restrict__ vo,
    bf16* __restrict__ skipb)
{
    __shared__ unsigned short xs[64 * X_LD];   // 33792 B; rows wave-private
    const int tid = threadIdx.x;
    const int n0 = blockIdx.x * 64;
    const int w = tid >> 6, l = tid & 63;
    const int row = l & 15, kg = l >> 4;

    { // stage x tile (fp32 -> bf16), nt loads; wave-private rows
        const int e = tid >> 2, t = tid & 3;
        const int nmine = n0 + e;
        const f32x4* src = (const f32x4*)(x + (size_t)nmine * 256 + t * 64);
        #pragma unroll
        for (int c = 0; c < 4; ++c) {
            unsigned short tmp[16];
            if (nmine < N_NODES) {
                #pragma unroll
                for (int u = 0; u < 4; ++u) {
                    const f32x4 v = __builtin_nontemporal_load(src + c * 4 + u);
                    tmp[u * 4 + 0] = rawbf(v[0]); tmp[u * 4 + 1] = rawbf(v[1]);
                    tmp[u * 4 + 2] = rawbf(v[2]); tmp[u * 4 + 3] = rawbf(v[3]);
                }
            } else {
                #pragma unroll
                for (int u = 0; u < 16; ++u) tmp[u] = 0;
            }
            *(short8b*)&xs[e * X_LD + t * 64 + c * 16]     = *(short8b*)&tmp[0];
            *(short8b*)&xs[e * X_LD + t * 64 + c * 16 + 8] = *(short8b*)&tmp[8];
        }
    }
    // same-wave DS ops are in-order: staging writes precede these reads
    short8b af[8];
    #pragma unroll
    for (int kc = 0; kc < 8; ++kc)
        af[kc] = *(const short8b*)&xs[(w * 16 + row) * X_LD + kc * 32 + kg * 8];

    for (int m = 0; m < 4; ++m) {
        const bf16* WT = WT4 + (size_t)m * 65536;
        const float* bias = (m == 0) ? bq : (m == 1) ? bk : (m == 2) ? bv : bs;
        #pragma unroll 4
        for (int ct = 0; ct < 16; ++ct) {
            const float bvv = bias[ct * 16 + row];
            f32x4 acc = {bvv, bvv, bvv, bvv};
            #pragma unroll
            for (int kc = 0; kc < 8; ++kc) {
                const short8b bfr = *(const short8b*)(WT + (size_t)(ct * 16 + row) * 256 + kc * 32 + kg * 8);
                acc = __builtin_amdgcn_mfma_f32_16x16x32_bf16(af[kc], bfr, acc, 0, 0, 0);
            }
            #pragma unroll
            for (int r = 0; r < 4; ++r)   // bounce into this wave's own rows
                xs[(w * 16 + kg * 4 + r) * X_LD + ct * 16 + row] = rawbf(acc[r]);
        }
        { // per-wave CACHED store: each instruction writes 1KB contiguous
            bf16* dst = (m == 0) ? qo : (m == 1) ? ko : (m == 2) ? vo : skipb;
            #pragma unroll
            for (int u = 0; u < 8; ++u) {
                const int flat = u * 64 + l;          // 16B unit in wave's 8KB
                const int node = w * 16 + (flat >> 5);
                const int col8 = (flat & 31) * 8;
                if (n0 + node < N_NODES) {
                    const short8b vdat = *(const short8b*)&xs[node * X_LD + col8];
                    *(short8b*)(dst + (size_t)(n0 + node) * 256 + col8) = vdat;
                }
            }
        }
        // no barrier: same-wave DS in-order; waves never share rows
    }
}

// ---------------- k2: barrier-free segment attention (k/v prefetch) ----------------
#define EP_LD 264
__global__ __launch_bounds__(256) void k2_seg(
    const int* __restrict__ ssort, const int* __restrict__ dsort,
    const int* __restrict__ eidsort, const int* __restrict__ endptr,
    const float* __restrict__ ea, const bf16* __restrict__ WeT,
    const bf16* __restrict__ q, const bf16* __restrict__ k, const bf16* __restrict__ v,
    const bf16* __restrict__ skipb, float* __restrict__ out_x, bf16* __restrict__ xnb)
{
    __shared__ float acc_s[SEG * 256];            // 16 KB msg accumulator
    __shared__ float den_s[SEG * HEADS];          // 2 KB
    __shared__ unsigned short ep_s[64 * EP_LD];   // 33 KB (wave-private rows)
    const int tid = threadIdx.x;
    const int n0 = blockIdx.x * SEG;

    #pragma unroll
    for (int i = 0; i < SEG; ++i) acc_s[i * 256 + tid] = 0.f;
    if (tid < SEG * HEADS - 256) den_s[256 + tid] = 0.f;
    den_s[tid] = 0.f;

    const int start = (n0 == 0) ? 0 : endptr[n0 - 1];
    const int end   = endptr[n0 + SEG - 1];
    __syncthreads();

    const int w = tid >> 6, l = tid & 63;
    const int row = l & 15, kg = l >> 4;
    const float scale = 0.35355339059327373f;   // 1/sqrt(8)

    // each wave free-runs its own 16-edge slices; no barriers in this loop
    for (int sbase = start + w * 16; sbase < end; sbase += 64) {
        const int cnt = min(16, end - sbase);   // >= 1

        // --- A fragments direct from global ea (fp32 -> bf16 in regs) ---
        short8b af0 = {0, 0, 0, 0, 0, 0, 0, 0}, af1 = af0;
        if (row < cnt) {
            const int eg = eidsort[sbase + row];
            const float* pb = ea + (size_t)eg * 64 + kg * 8;
            const f32x4 a0 = __builtin_nontemporal_load((const f32x4*)pb);
            const f32x4 a1 = __builtin_nontemporal_load((const f32x4*)(pb + 4));
            const f32x4 b0 = __builtin_nontemporal_load((const f32x4*)(pb + 32));
            const f32x4 b1 = __builtin_nontemporal_load((const f32x4*)(pb + 36));
            af0 = pack8(a0, a1); af1 = pack8(b0, b1);
        }

        // --- edge indices for this wave's slice ---
        int sv = 0;
        if (l < 16)      { if (l < cnt)      sv = ssort[sbase + l]; }
        else if (l < 32) { if (l - 16 < cnt) sv = dsort[sbase + (l - 16)]; }

        // --- prefetch ALL 32 k/v row-slices (clamped tail -> static unroll) ---
        ushort4v kvv[16], vvv[16];
        #pragma unroll
        for (int i = 0; i < 16; ++i) {
            const int s = __shfl(sv, min(i, cnt - 1));
            kvv[i] = *(const ushort4v*)(k + (size_t)s * 256 + l * 4);
            vvv[i] = *(const ushort4v*)(v + (size_t)s * 256 + l * 4);
        }
        __builtin_amdgcn_sched_barrier(0);   // pin: all gathers issued

        // --- eproj MFMA into wave-private ep rows ---
        #pragma unroll 4
        for (int ct = 0; ct < 16; ++ct) {
            f32x4 acc = {0.f, 0.f, 0.f, 0.f};
            const short8b b0 = *(const short8b*)(WeT + (size_t)(ct * 16 + row) * 64 + kg * 8);
            const short8b b1 = *(const short8b*)(WeT + (size_t)(ct * 16 + row) * 64 + 32 + kg * 8);
            acc = __builtin_amdgcn_mfma_f32_16x16x32_bf16(af0, b0, acc, 0, 0, 0);
            acc = __builtin_amdgcn_mfma_f32_16x16x32_bf16(af1, b1, acc, 0, 0, 0);
            #pragma unroll
            for (int r = 0; r < 4; ++r)
                ep_s[(w * 16 + kg * 4 + r) * EP_LD + ct * 16 + row] = rawbf(acc[r]);
        }
        // same-wave LDS write->read is in-order: no barrier needed

        // --- attention (run-compressed); all gathers already in regs ---
        float macc[4] = {0.f, 0.f, 0.f, 0.f};
        float dacc = 0.f;
        int dprev = -1;
        ushort4v qv = {0, 0, 0, 0};

        #pragma unroll
        for (int i = 0; i < 16; ++i) {
            const int d = __shfl(sv, 16 + min(i, cnt - 1));
            if (d != dprev) {                  // wave-uniform
                if (dprev >= 0) {
                    const int ld = dprev - n0;
                    #pragma unroll
                    for (int t = 0; t < 4; ++t)
                        atomicAdd(&acc_s[ld * 256 + l * 4 + t], macc[t]);
                    if ((l & 1) == 0)
                        atomicAdd(&den_s[ld * HEADS + (l >> 1)], dacc);
                    macc[0] = macc[1] = macc[2] = macc[3] = 0.f;
                    dacc = 0.f;
                }
                qv = *(const ushort4v*)(q + (size_t)d * 256 + l * 4);
                dprev = d;
            }
            const ushort4v ep = *(const ushort4v*)&ep_s[(w * 16 + i) * EP_LD + l * 4];
            float p = 0.f, m4[4];
            #pragma unroll
            for (int t = 0; t < 4; ++t) {
                const float epf = bfraw(ep[t]);
                p = fmaf(bfraw(qv[t]), bfraw(kvv[i][t]) + epf, p);
                m4[t] = bfraw(vvv[i][t]) + epf;
            }
            p += __shfl_xor(p, 1);             // head = l>>1 (2 lanes/head)
            const float ex = (i < cnt) ? __expf(p * scale) : 0.f;
            #pragma unroll
            for (int t = 0; t < 4; ++t) macc[t] = fmaf(m4[t], ex, macc[t]);
            dacc += ex;
        }
        {
            const int ld = dprev - n0;
            #pragma unroll
            for (int t = 0; t < 4; ++t)
                atomicAdd(&acc_s[ld * 256 + l * 4 + t], macc[t]);
            if ((l & 1) == 0)
                atomicAdd(&den_s[ld * HEADS + (l >> 1)], dacc);
        }
    }
    __syncthreads();   // single barrier: all waves' aggregation done

    // finalize: x_new = leaky(acc/den + skip) -> out_x fp32 + xnb bf16 (cached)
    #pragma unroll
    for (int u = 0; u < 4; ++u) {
        const int flat4 = u * 256 + tid;        // f32x4 unit; 64 per node
        const int node = flat4 >> 6;
        const int ch4 = flat4 & 63;
        const int n = n0 + node;
        const float den = den_s[node * HEADS + (ch4 >> 1)] + 1e-16f;
        const f32x4 mv = *(const f32x4*)&acc_s[node * 256 + ch4 * 4];
        const ushort4v sk = *(const ushort4v*)(skipb + (size_t)n * 256 + ch4 * 4);
        f32x4 o; ushort4v ob;
        #pragma unroll
        for (int t = 0; t < 4; ++t) {
            const float xn = leaky(mv[t] / den + bfraw(sk[t]));
            o[t] = xn; ob[t] = rawbf(xn);
        }
        *(f32x4*)(out_x + (size_t)n * 256 + ch4 * 4) = o;
        *(ushort4v*)(xnb + (size_t)n * 256 + ch4 * 4) = ob;
    }
}

// ---------------- k3b: per-node MLP projections P = [xn@W1_s | xn@W1_d] ----------------
#define PB_LD 136
__global__ __launch_bounds__(256) void k3b_nodeproj(
    const bf16* __restrict__ xnb, const bf16* __restrict__ W1Tp,
    bf16* __restrict__ P)
{
    __shared__ unsigned short ps_s[64 * PB_LD];   // 17408 B
    const int tid = threadIdx.x;
    const int n0 = blockIdx.x * 64;
    const int w = tid >> 6, l = tid & 63;
    const int row = l & 15, kg = l >> 4;

    // A fragments: node w*16+row (bf16 direct; clamp OOB reads, stores guarded)
    const int nmine = n0 + w * 16 + row;
    const size_t nbase = (size_t)min(nmine, N_NODES - 1) * 256;
    short8b af[8];
    #pragma unroll
    for (int kc = 0; kc < 8; ++kc)
        af[kc] = *(const short8b*)(xnb + nbase + kc * 32 + kg * 8);

    #pragma unroll
    for (int m = 0; m < 2; ++m) {   // 0: src-proj (W1Tp cols 64..319), 1: dst (320..575)
        const int koff = (m == 0) ? 64 : 320;
        #pragma unroll
        for (int ct = 0; ct < 4; ++ct) {
            f32x4 acc = {0.f, 0.f, 0.f, 0.f};
            #pragma unroll
            for (int kc = 0; kc < 8; ++kc) {
                const short8b bfr = *(const short8b*)(W1Tp + (size_t)(ct * 16 + row) * 576 + koff + kc * 32 + kg * 8);
                acc = __builtin_amdgcn_mfma_f32_16x16x32_bf16(af[kc], bfr, acc, 0, 0, 0);
            }
            #pragma unroll
            for (int r = 0; r < 4; ++r)
                ps_s[(w * 16 + kg * 4 + r) * PB_LD + m * 64 + ct * 16 + row] = rawbf(acc[r]);
        }
    }
    __syncthreads();
    // store: per node 128 bf16 = 256B contiguous (cacheable -- k4 gathers it)
    #pragma unroll
    for (int u = 0; u < 4; ++u) {
        const int flat = u * 256 + tid;      // 16B unit; 16 units per node
        const int node = flat >> 4;
        const int c8 = (flat & 15) * 8;
        if (n0 + node < N_NODES) {
            const short8b vdat = *(const short8b*)&ps_s[node * PB_LD + c8];
            *(short8b*)(P + (size_t)(n0 + node) * 128 + c8) = vdat;
        }
    }
}

// ---------------- k4: edge MLP, factorized GEMM1 (K=64) + P gathers ----------------
__global__ __launch_bounds__(256) void k4_edge_mlp(
    const int* __restrict__ ssort, const int* __restrict__ dsort,
    const int* __restrict__ eidsort,
    const bf16* __restrict__ P, const float* __restrict__ ea,
    const bf16* __restrict__ W1Tp, const float* __restrict__ b1,
    const bf16* __restrict__ W2T, const float* __restrict__ b2,
    float* __restrict__ out_e)
{
    __shared__ unsigned short h2_s[4][16 * 72];   // 9216 B, wave-private
    __shared__ unsigned short ea_s[4][16 * 72];   // 9216 B, wave-private ea stash
    const int tid = threadIdx.x;
    const int w = tid >> 6, l = tid & 63;
    const int row = l & 15, kg = l >> 4;
    const int e0 = blockIdx.x * 64;
    const int sl = e0 + w * 16 + row;            // this lane's A-row edge
    const int eg = eidsort[sl];

    int s2[4], d2[4], eg2[4];                    // C-row edges (kg*4+r)
    #pragma unroll
    for (int r = 0; r < 4; ++r) {
        const int cr = e0 + w * 16 + kg * 4 + r;
        s2[r] = ssort[cr]; d2[r] = dsort[cr]; eg2[r] = eidsort[cr];
    }

    // ---- issue all loads up front: 4 ea (nt) + 32 P gathers ----
    const float* pb = ea + (size_t)eg * 64 + kg * 8;
    const f32x4 a0 = __builtin_nontemporal_load((const f32x4*)pb);
    const f32x4 a1 = __builtin_nontemporal_load((const f32x4*)(pb + 4));
    const f32x4 c0 = __builtin_nontemporal_load((const f32x4*)(pb + 32));
    const f32x4 c1 = __builtin_nontemporal_load((const f32x4*)(pb + 36));

    const unsigned short* Pu = (const unsigned short*)P;
    unsigned short psv[4][4], pdv[4][4];
    #pragma unroll
    for (int ct = 0; ct < 4; ++ct)
        #pragma unroll
        for (int r = 0; r < 4; ++r) {
            psv[ct][r] = Pu[(size_t)s2[r] * 128 + ct * 16 + row];
            pdv[ct][r] = Pu[(size_t)d2[r] * 128 + 64 + ct * 16 + row];
        }
    __builtin_amdgcn_sched_barrier(0);   // pin: all loads issued before compute

    const short8b afr0 = pack8(a0, a1);
    const short8b afr1 = pack8(c0, c1);
    // stash bf16 ea tile for the residual epilogue (same-wave in-order)
    *(short8b*)&ea_s[w][row * 72 + kg * 8]      = afr0;
    *(short8b*)&ea_s[w][row * 72 + 32 + kg * 8] = afr1;

    // ---- GEMM1: ea part only, [16 x 64] @ W1_ea -> [16 x 64] ----
    f32x4 acc[4];
    #pragma unroll
    for (int ct = 0; ct < 4; ++ct) {
        const float bvv = b1[ct * 16 + row];
        acc[ct] = (f32x4){bvv, bvv, bvv, bvv};
    }
    #pragma unroll
    for (int kc = 0; kc < 2; ++kc) {
        const short8b af = (kc == 0) ? afr0 : afr1;
        #pragma unroll
        for (int ct = 0; ct < 4; ++ct) {
            const short8b bfr = *(const short8b*)(W1Tp + (size_t)(ct * 16 + row) * 576 + kc * 32 + kg * 8);
            acc[ct] = __builtin_amdgcn_mfma_f32_16x16x32_bf16(af, bfr, acc[ct], 0, 0, 0);
        }
    }
    // add precomputed node projections
    #pragma unroll
    for (int ct = 0; ct < 4; ++ct)
        #pragma unroll
        for (int r = 0; r < 4; ++r)
            acc[ct][r] += bfraw(psv[ct][r]) + bfraw(pdv[ct][r]);

    // h2 = leaky(acc) -> wave-private LDS bounce (same-wave in-order)
    unsigned short* h2 = h2_s[w];
    #pragma unroll
    for (int ct = 0; ct < 4; ++ct)
        #pragma unroll
        for (int r = 0; r < 4; ++r)
            h2[(kg * 4 + r) * 72 + ct * 16 + row] = rawbf(leaky(acc[ct][r]));

    // ---- GEMM2: [16 x 64] @ W2 -> [16 x 64] ----
    f32x4 a2[4];
    #pragma unroll
    for (int ct = 0; ct < 4; ++ct) {
        const float bvv = b2[ct * 16 + row];
        a2[ct] = (f32x4){bvv, bvv, bvv, bvv};
    }
    #pragma unroll
    for (int kc = 0; kc < 2; ++kc) {
        const short8b af = *(const short8b*)&h2[row * 72 + kc * 32 + kg * 8];
        #pragma unroll
        for (int ct = 0; ct < 4; ++ct) {
            const short8b bfr = *(const short8b*)(W2T + (size_t)(ct * 16 + row) * 64 + kc * 32 + kg * 8);
            a2[ct] = __builtin_amdgcn_mfma_f32_16x16x32_bf16(af, bfr, a2[ct], 0, 0, 0);
        }
    }

    // epilogue: out = leaky(ea + h2@W2+b2); ea residual from LDS stash (cached stores)
    #pragma unroll
    for (int ct = 0; ct < 4; ++ct)
        #pragma unroll
        for (int r = 0; r < 4; ++r) {
            const float eav = bfraw(ea_s[w][(kg * 4 + r) * 72 + ct * 16 + row]);
            out_e[(size_t)eg2[r] * 64 + ct * 16 + row] = leaky(eav + a2[ct][r]);
        }
}

extern "C" void kernel_launch(void* const* d_in, const int* in_sizes, int n_in,
                              void* d_out, int out_size, void* d_ws, size_t ws_size,
                              hipStream_t stream)
{
    const float* x  = (const float*)d_in[0];
    const int*   ei = (const int*)d_in[1];
    const float* ea = (const float*)d_in[2];
    const float* Wq = (const float*)d_in[3];
    const float* bq = (const float*)d_in[4];
    const float* Wk = (const float*)d_in[5];
    const float* bk = (const float*)d_in[6];
    const float* Wv = (const float*)d_in[7];
    const float* bv = (const float*)d_in[8];
    const float* We = (const float*)d_in[9];
    const float* Ws = (const float*)d_in[10];
    const float* bs = (const float*)d_in[11];
    const float* W1 = (const float*)d_in[12];
    const float* b1 = (const float*)d_in[13];
    const float* W2 = (const float*)d_in[14];
    const float* b2 = (const float*)d_in[15];

    char* ws = (char*)d_ws;
    int*   flags  = (int*)ws;                       // 4 KB
    int*   ssort  = (int*)(ws + 4096);
    int*   dsort  = (int*)(ws + 1604096);
    int*   eids   = (int*)(ws + 3204096);
    int*   cursor = (int*)(ws + 4804096);           // end-pointers after kct
    bf16*  WeT    = (bf16*)(ws + 5004096);
    bf16*  W1Tp   = (bf16*)(ws + 5036864);
    bf16*  W2T    = (bf16*)(ws + 5110592);
    bf16*  WT4    = (bf16*)(ws + 5118784);
    bf16*  qb     = (bf16*)(ws + 5643072);
    bf16*  kb     = (bf16*)(ws + 31243072);
    bf16*  vb     = (bf16*)(ws + 56843072);
    bf16*  xnb    = (bf16*)(ws + 82443072);         // x_new bf16 (25.6 MB)
    bf16*  Pp     = (bf16*)(ws + 108100000);        // node projections (12.8 MB)

    float* out_x = (float*)d_out;
    float* out_e = out_x + (size_t)N_NODES * D_NODE;
    bf16*  skipb = (bf16*)out_e;   // bf16 skip staged in edge-out region

    hipMemsetAsync(cursor, 0, N_NODES * 4, stream);       // degree counters

    k0_detect<<<1, 64, 0, stream>>>(ei, flags);
    kcd_degree<<<(N_EDGES + 255) / 256, 256, 0, stream>>>(ei, flags, cursor);
    kcs_scan<<<1, 1024, 0, stream>>>(cursor);
    kct_scatter<<<(N_EDGES + 255) / 256, 256, 0, stream>>>(ei, flags, cursor, ssort, dsort, eids);

    kT_transpose<<<64, 256, 0, stream>>>(We, W1, W2, Wq, Wk, Wv, Ws, WeT, W1Tp, W2T, WT4);

    k1_node_mfma<<<(N_NODES + 63) / 64, 256, 0, stream>>>(
        x, WT4, bq, bk, bv, bs, qb, kb, vb, skipb);

    k2_seg<<<N_NODES / SEG, 256, 0, stream>>>(
        ssort, dsort, eids, cursor, ea, WeT, qb, kb, vb, skipb, out_x, xnb);

    k3b_nodeproj<<<(N_NODES + 63) / 64, 256, 0, stream>>>(xnb, W1Tp, Pp);

    k4_edge_mlp<<<N_EDGES / 64, 256, 0, stream>>>(
        ssort, dsort, eids, Pp, ea, W1Tp, b1, W2T, b2, out_e);
}

// Round 15
// 576.677 us; speedup vs baseline: 1.8622x; 1.3369x over previous
//
#include <hip/hip_runtime.h>
#include <hip/hip_bf16.h>

// GCNBlock: TransformerConv(32 heads, dim 8, edge_dim 64) + EdgeResidualLayer
// N=50000, E=400000, D_NODE=256, D_EDGE=64. FP32 in/out, int64 edge_index.
// Internals: bf16 MFMA (16x16x32) with fp32 accumulate.
//
// Round 15: fragment-major B-operand layout. Every GEMM B load was a
// 16-line gather ((ct*16+row)*LD + kg*8: rows 512B apart per lane) --
// ~1.6M loads x 16 L1 transactions in k1 alone = the 260us wall (MfmaUtil
// 4%, BW 7%: L1-port serialization). kT now emits weights in the exact
// [.. ][ct][kc][lane][8] order the MFMA fragments consume, so each B load
// is uniform_base + lane*16B = one coalesced 1KB instruction.
// Carried: CSR dst-sort, barrier-free k1/k2, k/v + P prefetch pins,
// factorized k4 (k3b node projections), nt loads, cached stores.

#define N_NODES 50000
#define N_EDGES 400000
#define D_NODE 256
#define D_EDGE 64
#define HEADS 32
#define LRELU 0.01f
#define SEG 16          // dst nodes per k2 block

typedef __hip_bfloat16 bf16;
typedef __attribute__((ext_vector_type(8))) short short8b;          // 8 bf16
typedef __attribute__((ext_vector_type(4))) float f32x4;
typedef __attribute__((ext_vector_type(4))) unsigned short ushort4v;

__device__ __forceinline__ float bf2f(bf16 v) { return __bfloat162float(v); }
__device__ __forceinline__ bf16 f2bf(float f) { return __float2bfloat16(f); }
__device__ __forceinline__ float bfraw(unsigned short u) {
    return __uint_as_float(((unsigned int)u) << 16);
}
__device__ __forceinline__ unsigned short rawbf(float f) {
    bf16 t = f2bf(f); return *(unsigned short*)&t;
}
__device__ __forceinline__ float leaky(float v) { return v >= 0.f ? v : LRELU * v; }
__device__ __forceinline__ short8b pack8(const f32x4 a, const f32x4 b) {
    short8b r;
    r[0] = (short)rawbf(a[0]); r[1] = (short)rawbf(a[1]);
    r[2] = (short)rawbf(a[2]); r[3] = (short)rawbf(a[3]);
    r[4] = (short)rawbf(b[0]); r[5] = (short)rawbf(b[1]);
    r[6] = (short)rawbf(b[2]); r[7] = (short)rawbf(b[3]);
    return r;
}

// ---------------- k0: index width detection (1 wave) ----------------
__global__ void k0_detect(const int* __restrict__ ei, int* __restrict__ flags)
{
    const int lane = threadIdx.x;
    const unsigned long long mz = __ballot(ei[2 * lane + 1] == 0);
    if (lane == 0) flags[0] = (__popcll(mz) >= 48) ? 1 : 0;   // 1 => int64
}

__device__ __forceinline__ void load_edge(const int* ei, int f, int i, int& s, int& d)
{
    if (f) {
        const long long* e64 = (const long long*)ei;
        s = (int)e64[i]; d = (int)e64[N_EDGES + i];
    } else {
        s = ei[i]; d = ei[N_EDGES + i];
    }
}

// ---------------- CSR build ----------------
__global__ __launch_bounds__(256) void kcd_degree(
    const int* __restrict__ ei, const int* __restrict__ flags, int* __restrict__ deg)
{
    const int i = blockIdx.x * 256 + threadIdx.x;
    if (i >= N_EDGES) return;
    int s, d; load_edge(ei, flags[0], i, s, d);
    atomicAdd(&deg[d], 1);
}

__global__ __launch_bounds__(1024) void kcs_scan(int* __restrict__ cur)  // deg -> excl. offsets
{
    __shared__ int ps[1024];
    const int t = threadIdx.x;
    const int CH = (N_NODES + 1023) / 1024;   // 49
    const int base = t * CH;
    int sum = 0;
    for (int i = 0; i < CH; ++i) {
        const int n = base + i;
        if (n < N_NODES) sum += cur[n];
    }
    ps[t] = sum;
    __syncthreads();
    for (int off = 1; off < 1024; off <<= 1) {
        const int v = (t >= off) ? ps[t - off] : 0;
        __syncthreads();
        ps[t] += v;
        __syncthreads();
    }
    int excl = (t == 0) ? 0 : ps[t - 1];
    for (int i = 0; i < CH; ++i) {
        const int n = base + i;
        if (n < N_NODES) {
            const int d = cur[n];
            cur[n] = excl;
            excl += d;
        }
    }
}

__global__ __launch_bounds__(256) void kct_scatter(
    const int* __restrict__ ei, const int* __restrict__ flags, int* __restrict__ cursor,
    int* __restrict__ ssort, int* __restrict__ dsort, int* __restrict__ eidsort)
{
    const int i = blockIdx.x * 256 + threadIdx.x;
    if (i >= N_EDGES) return;
    int s, d; load_edge(ei, flags[0], i, s, d);
    const int pos = atomicAdd(&cursor[d], 1);
    ssort[pos] = s; dsort[pos] = d; eidsort[pos] = i;
    // after this kernel: cursor[n] == end offset of node n (inclusive)
}

// ---------------- kT: fragment-major weight layouts (fp32 -> bf16) ----------------
// For MFMA B-fragment consumed by lane l (row=l&15, kg=l>>4) at (ct,kc):
// element j lives at W[k][n] with n=ct*16+row, k=kbase+kc*32+kg*8+j.
// Fragment-major: out[(group*512) + l*8 + j], group = linear (.., ct, kc).
__global__ __launch_bounds__(256) void kT_transpose(
    const float* __restrict__ We, const float* __restrict__ W1, const float* __restrict__ W2,
    const float* __restrict__ Wq, const float* __restrict__ Wk,
    const float* __restrict__ Wv, const float* __restrict__ Ws,
    bf16* __restrict__ WeTf, bf16* __restrict__ W1sdf, bf16* __restrict__ W1eaf,
    bf16* __restrict__ W2Tf, bf16* __restrict__ WT4f)
{
    const int gid = blockIdx.x * 256 + threadIdx.x;
    const int gsz = gridDim.x * 256;
    // WT4f: [m(4)][ct(16)][kc(8)][l(64)][j(8)]  (q,k,v,s; 256x256 each)
    for (int i = gid; i < 4 * 16 * 8 * 512; i += gsz) {
        const int j = i & 7, l = (i >> 3) & 63, kc = (i >> 9) & 7;
        const int ct = (i >> 12) & 15, m = i >> 16;
        const int row = l & 15, kg = l >> 4;
        const int n = ct * 16 + row, k = kc * 32 + kg * 8 + j;
        const float* W = (m == 0) ? Wq : (m == 1) ? Wk : (m == 2) ? Wv : Ws;
        WT4f[i] = f2bf(W[k * 256 + n]);
    }
    // WeTf: [ct(16)][kc(2)][l][j]  (We: 64x256)
    for (int i = gid; i < 16 * 2 * 512; i += gsz) {
        const int j = i & 7, l = (i >> 3) & 63, kc = (i >> 9) & 1, ct = i >> 10;
        const int row = l & 15, kg = l >> 4;
        const int n = ct * 16 + row, k = kc * 32 + kg * 8 + j;
        WeTf[i] = f2bf(We[k * 256 + n]);
    }
    // W1sdf: [m2(2)][ct(4)][kc(8)][l][j]  (W1 rows 0..255 = x_s, 256..511 = x_d)
    for (int i = gid; i < 2 * 4 * 8 * 512; i += gsz) {
        const int j = i & 7, l = (i >> 3) & 63, kc = (i >> 9) & 7;
        const int ct = (i >> 12) & 3, m2 = i >> 14;
        const int row = l & 15, kg = l >> 4;
        const int n = ct * 16 + row;
        const int k = m2 * 256 + kc * 32 + kg * 8 + j;
        W1sdf[i] = f2bf(W1[k * 64 + n]);
    }
    // W1eaf: [ct(4)][kc(2)][l][j]  (W1 rows 512..575 = ea)
    for (int i = gid; i < 4 * 2 * 512; i += gsz) {
        const int j = i & 7, l = (i >> 3) & 63, kc = (i >> 9) & 1, ct = i >> 10;
        const int row = l & 15, kg = l >> 4;
        const int n = ct * 16 + row;
        const int k = 512 + kc * 32 + kg * 8 + j;
        W1eaf[i] = f2bf(W1[k * 64 + n]);
    }
    // W2Tf: [ct(4)][kc(2)][l][j]  (W2: 64x64)
    for (int i = gid; i < 4 * 2 * 512; i += gsz) {
        const int j = i & 7, l = (i >> 3) & 63, kc = (i >> 9) & 1, ct = i >> 10;
        const int row = l & 15, kg = l >> 4;
        const int n = ct * 16 + row, k = kc * 32 + kg * 8 + j;
        W2Tf[i] = f2bf(W2[k * 64 + n]);
    }
}

// ---------------- k1: node linears via MFMA (coalesced B-fragments) ----------------
#define X_LD 264
__global__ __launch_bounds__(256) void k1_node_mfma(
    const float* __restrict__ x, const bf16* __restrict__ WT4f,
    const float* __restrict__ bq, const float* __restrict__ bk,
    const float* __restrict__ bv, const float* __restrict__ bs,
    bf16* __restrict__ qo, bf16* __restrict__ ko, bf16* __restrict__ vo,
    bf16* __restrict__ skipb)
{
    __shared__ unsigned short xs[64 * X_LD];   // 33792 B; rows wave-private
    const int tid = threadIdx.x;
    const int n0 = blockIdx.x * 64;
    const int w = tid >> 6, l = tid & 63;
    const int row = l & 15, kg = l >> 4;

    { // stage x tile (fp32 -> bf16), nt loads; wave-private rows
        const int e = tid >> 2, t = tid & 3;
        const int nmine = n0 + e;
        const f32x4* src = (const f32x4*)(x + (size_t)nmine * 256 + t * 64);
        #pragma unroll
        for (int c = 0; c < 4; ++c) {
            unsigned short tmp[16];
            if (nmine < N_NODES) {
                #pragma unroll
                for (int u = 0; u < 4; ++u) {
                    const f32x4 v = __builtin_nontemporal_load(src + c * 4 + u);
                    tmp[u * 4 + 0] = rawbf(v[0]); tmp[u * 4 + 1] = rawbf(v[1]);
                    tmp[u * 4 + 2] = rawbf(v[2]); tmp[u * 4 + 3] = rawbf(v[3]);
                }
            } else {
                #pragma unroll
                for (int u = 0; u < 16; ++u) tmp[u] = 0;
            }
            *(short8b*)&xs[e * X_LD + t * 64 + c * 16]     = *(short8b*)&tmp[0];
            *(short8b*)&xs[e * X_LD + t * 64 + c * 16 + 8] = *(short8b*)&tmp[8];
        }
    }
    // same-wave DS ops are in-order: staging writes precede these reads
    short8b af[8];
    #pragma unroll
    for (int kc = 0; kc < 8; ++kc)
        af[kc] = *(const short8b*)&xs[(w * 16 + row) * X_LD + kc * 32 + kg * 8];

    for (int m = 0; m < 4; ++m) {
        const float* bias = (m == 0) ? bq : (m == 1) ? bk : (m == 2) ? bv : bs;
        #pragma unroll 4
        for (int ct = 0; ct < 16; ++ct) {
            const float bvv = bias[ct * 16 + row];
            f32x4 acc = {bvv, bvv, bvv, bvv};
            #pragma unroll
            for (int kc = 0; kc < 8; ++kc) {
                const short8b bfr = *(const short8b*)(WT4f + (((size_t)((m * 16 + ct) * 8 + kc)) << 9) + l * 8);
                acc = __builtin_amdgcn_mfma_f32_16x16x32_bf16(af[kc], bfr, acc, 0, 0, 0);
            }
            #pragma unroll
            for (int r = 0; r < 4; ++r)   // bounce into this wave's own rows
                xs[(w * 16 + kg * 4 + r) * X_LD + ct * 16 + row] = rawbf(acc[r]);
        }
        { // per-wave cached store: each instruction writes 1KB contiguous
            bf16* dst = (m == 0) ? qo : (m == 1) ? ko : (m == 2) ? vo : skipb;
            #pragma unroll
            for (int u = 0; u < 8; ++u) {
                const int flat = u * 64 + l;          // 16B unit in wave's 8KB
                const int node = w * 16 + (flat >> 5);
                const int col8 = (flat & 31) * 8;
                if (n0 + node < N_NODES) {
                    const short8b vdat = *(const short8b*)&xs[node * X_LD + col8];
                    *(short8b*)(dst + (size_t)(n0 + node) * 256 + col8) = vdat;
                }
            }
        }
        // no barrier: same-wave DS in-order; waves never share rows
    }
}

// ---------------- k2: barrier-free segment attention (k/v prefetch) ----------------
#define EP_LD 264
__global__ __launch_bounds__(256) void k2_seg(
    const int* __restrict__ ssort, const int* __restrict__ dsort,
    const int* __restrict__ eidsort, const int* __restrict__ endptr,
    const float* __restrict__ ea, const bf16* __restrict__ WeTf,
    const bf16* __restrict__ q, const bf16* __restrict__ k, const bf16* __restrict__ v,
    const bf16* __restrict__ skipb, float* __restrict__ out_x, bf16* __restrict__ xnb)
{
    __shared__ float acc_s[SEG * 256];            // 16 KB msg accumulator
    __shared__ float den_s[SEG * HEADS];          // 2 KB
    __shared__ unsigned short ep_s[64 * EP_LD];   // 33 KB (wave-private rows)
    const int tid = threadIdx.x;
    const int n0 = blockIdx.x * SEG;

    #pragma unroll
    for (int i = 0; i < SEG; ++i) acc_s[i * 256 + tid] = 0.f;
    if (tid < SEG * HEADS - 256) den_s[256 + tid] = 0.f;
    den_s[tid] = 0.f;

    const int start = (n0 == 0) ? 0 : endptr[n0 - 1];
    const int end   = endptr[n0 + SEG - 1];
    __syncthreads();

    const int w = tid >> 6, l = tid & 63;
    const int row = l & 15, kg = l >> 4;
    const float scale = 0.35355339059327373f;   // 1/sqrt(8)

    // each wave free-runs its own 16-edge slices; no barriers in this loop
    for (int sbase = start + w * 16; sbase < end; sbase += 64) {
        const int cnt = min(16, end - sbase);   // >= 1

        // --- A fragments direct from global ea (fp32 -> bf16 in regs) ---
        short8b af0 = {0, 0, 0, 0, 0, 0, 0, 0}, af1 = af0;
        if (row < cnt) {
            const int eg = eidsort[sbase + row];
            const float* pb = ea + (size_t)eg * 64 + kg * 8;
            const f32x4 a0 = __builtin_nontemporal_load((const f32x4*)pb);
            const f32x4 a1 = __builtin_nontemporal_load((const f32x4*)(pb + 4));
            const f32x4 b0 = __builtin_nontemporal_load((const f32x4*)(pb + 32));
            const f32x4 b1 = __builtin_nontemporal_load((const f32x4*)(pb + 36));
            af0 = pack8(a0, a1); af1 = pack8(b0, b1);
        }

        // --- edge indices for this wave's slice ---
        int sv = 0;
        if (l < 16)      { if (l < cnt)      sv = ssort[sbase + l]; }
        else if (l < 32) { if (l - 16 < cnt) sv = dsort[sbase + (l - 16)]; }

        // --- prefetch ALL 32 k/v row-slices (clamped tail -> static unroll) ---
        ushort4v kvv[16], vvv[16];
        #pragma unroll
        for (int i = 0; i < 16; ++i) {
            const int s = __shfl(sv, min(i, cnt - 1));
            kvv[i] = *(const ushort4v*)(k + (size_t)s * 256 + l * 4);
            vvv[i] = *(const ushort4v*)(v + (size_t)s * 256 + l * 4);
        }
        __builtin_amdgcn_sched_barrier(0);   // pin: all gathers issued

        // --- eproj MFMA into wave-private ep rows (coalesced B) ---
        #pragma unroll 4
        for (int ct = 0; ct < 16; ++ct) {
            f32x4 acc = {0.f, 0.f, 0.f, 0.f};
            const short8b b0 = *(const short8b*)(WeTf + (ct * 2 + 0) * 512 + l * 8);
            const short8b b1 = *(const short8b*)(WeTf + (ct * 2 + 1) * 512 + l * 8);
            acc = __builtin_amdgcn_mfma_f32_16x16x32_bf16(af0, b0, acc, 0, 0, 0);
            acc = __builtin_amdgcn_mfma_f32_16x16x32_bf16(af1, b1, acc, 0, 0, 0);
            #pragma unroll
            for (int r = 0; r < 4; ++r)
                ep_s[(w * 16 + kg * 4 + r) * EP_LD + ct * 16 + row] = rawbf(acc[r]);
        }
        // same-wave LDS write->read is in-order: no barrier needed

        // --- attention (run-compressed); all gathers already in regs ---
        float macc[4] = {0.f, 0.f, 0.f, 0.f};
        float dacc = 0.f;
        int dprev = -1;
        ushort4v qv = {0, 0, 0, 0};

        #pragma unroll
        for (int i = 0; i < 16; ++i) {
            const int d = __shfl(sv, 16 + min(i, cnt - 1));
            if (d != dprev) {                  // wave-uniform
                if (dprev >= 0) {
                    const int ld = dprev - n0;
                    #pragma unroll
                    for (int t = 0; t < 4; ++t)
                        atomicAdd(&acc_s[ld * 256 + l * 4 + t], macc[t]);
                    if ((l & 1) == 0)
                        atomicAdd(&den_s[ld * HEADS + (l >> 1)], dacc);
                    macc[0] = macc[1] = macc[2] = macc[3] = 0.f;
                    dacc = 0.f;
                }
                qv = *(const ushort4v*)(q + (size_t)d * 256 + l * 4);
                dprev = d;
            }
            const ushort4v ep = *(const ushort4v*)&ep_s[(w * 16 + i) * EP_LD + l * 4];
            float p = 0.f, m4[4];
            #pragma unroll
            for (int t = 0; t < 4; ++t) {
                const float epf = bfraw(ep[t]);
                p = fmaf(bfraw(qv[t]), bfraw(kvv[i][t]) + epf, p);
                m4[t] = bfraw(vvv[i][t]) + epf;
            }
            p += __shfl_xor(p, 1);             // head = l>>1 (2 lanes/head)
            const float ex = (i < cnt) ? __expf(p * scale) : 0.f;
            #pragma unroll
            for (int t = 0; t < 4; ++t) macc[t] = fmaf(m4[t], ex, macc[t]);
            dacc += ex;
        }
        {
            const int ld = dprev - n0;
            #pragma unroll
            for (int t = 0; t < 4; ++t)
                atomicAdd(&acc_s[ld * 256 + l * 4 + t], macc[t]);
            if ((l & 1) == 0)
                atomicAdd(&den_s[ld * HEADS + (l >> 1)], dacc);
        }
    }
    __syncthreads();   // single barrier: all waves' aggregation done

    // finalize: x_new = leaky(acc/den + skip) -> out_x fp32 + xnb bf16 (cached)
    #pragma unroll
    for (int u = 0; u < 4; ++u) {
        const int flat4 = u * 256 + tid;        // f32x4 unit; 64 per node
        const int node = flat4 >> 6;
        const int ch4 = flat4 & 63;
        const int n = n0 + node;
        const float den = den_s[node * HEADS + (ch4 >> 1)] + 1e-16f;
        const f32x4 mv = *(const f32x4*)&acc_s[node * 256 + ch4 * 4];
        const ushort4v sk = *(const ushort4v*)(skipb + (size_t)n * 256 + ch4 * 4);
        f32x4 o; ushort4v ob;
        #pragma unroll
        for (int t = 0; t < 4; ++t) {
            const float xn = leaky(mv[t] / den + bfraw(sk[t]));
            o[t] = xn; ob[t] = rawbf(xn);
        }
        *(f32x4*)(out_x + (size_t)n * 256 + ch4 * 4) = o;
        *(ushort4v*)(xnb + (size_t)n * 256 + ch4 * 4) = ob;
    }
}

// ---------------- k3b: per-node MLP projections P = [xn@W1_s | xn@W1_d] ----------------
#define PB_LD 136
__global__ __launch_bounds__(256) void k3b_nodeproj(
    const bf16* __restrict__ xnb, const bf16* __restrict__ W1sdf,
    bf16* __restrict__ P)
{
    __shared__ unsigned short ps_s[64 * PB_LD];   // 17408 B
    const int tid = threadIdx.x;
    const int n0 = blockIdx.x * 64;
    const int w = tid >> 6, l = tid & 63;
    const int row = l & 15, kg = l >> 4;

    // A fragments: node w*16+row (bf16 direct; clamp OOB reads, stores guarded)
    const int nmine = n0 + w * 16 + row;
    const size_t nbase = (size_t)min(nmine, N_NODES - 1) * 256;
    short8b af[8];
    #pragma unroll
    for (int kc = 0; kc < 8; ++kc)
        af[kc] = *(const short8b*)(xnb + nbase + kc * 32 + kg * 8);

    #pragma unroll
    for (int m = 0; m < 2; ++m) {   // 0: src-proj, 1: dst-proj (coalesced B)
        #pragma unroll
        for (int ct = 0; ct < 4; ++ct) {
            f32x4 acc = {0.f, 0.f, 0.f, 0.f};
            #pragma unroll
            for (int kc = 0; kc < 8; ++kc) {
                const short8b bfr = *(const short8b*)(W1sdf + ((m * 4 + ct) * 8 + kc) * 512 + l * 8);
                acc = __builtin_amdgcn_mfma_f32_16x16x32_bf16(af[kc], bfr, acc, 0, 0, 0);
            }
            #pragma unroll
            for (int r = 0; r < 4; ++r)
                ps_s[(w * 16 + kg * 4 + r) * PB_LD + m * 64 + ct * 16 + row] = rawbf(acc[r]);
        }
    }
    __syncthreads();
    // store: per node 128 bf16 = 256B contiguous (cacheable -- k4 gathers it)
    #pragma unroll
    for (int u = 0; u < 4; ++u) {
        const int flat = u * 256 + tid;      // 16B unit; 16 units per node
        const int node = flat >> 4;
        const int c8 = (flat & 15) * 8;
        if (n0 + node < N_NODES) {
            const short8b vdat = *(const short8b*)&ps_s[node * PB_LD + c8];
            *(short8b*)(P + (size_t)(n0 + node) * 128 + c8) = vdat;
        }
    }
}

// ---------------- k4: edge MLP, factorized GEMM1 (K=64) + P gathers ----------------
__global__ __launch_bounds__(256) void k4_edge_mlp(
    const int* __restrict__ ssort, const int* __restrict__ dsort,
    const int* __restrict__ eidsort,
    const bf16* __restrict__ P, const float* __restrict__ ea,
    const bf16* __restrict__ W1eaf, const float* __restrict__ b1,
    const bf16* __restrict__ W2Tf, const float* __restrict__ b2,
    float* __restrict__ out_e)
{
    __shared__ unsigned short h2_s[4][16 * 72];   // 9216 B, wave-private
    __shared__ unsigned short ea_s[4][16 * 72];   // 9216 B, wave-private ea stash
    const int tid = threadIdx.x;
    const int w = tid >> 6, l = tid & 63;
    const int row = l & 15, kg = l >> 4;
    const int e0 = blockIdx.x * 64;
    const int sl = e0 + w * 16 + row;            // this lane's A-row edge
    const int eg = eidsort[sl];

    int s2[4], d2[4], eg2[4];                    // C-row edges (kg*4+r)
    #pragma unroll
    for (int r = 0; r < 4; ++r) {
        const int cr = e0 + w * 16 + kg * 4 + r;
        s2[r] = ssort[cr]; d2[r] = dsort[cr]; eg2[r] = eidsort[cr];
    }

    // ---- issue all loads up front: 4 ea (nt) + 32 P gathers ----
    const float* pb = ea + (size_t)eg * 64 + kg * 8;
    const f32x4 a0 = __builtin_nontemporal_load((const f32x4*)pb);
    const f32x4 a1 = __builtin_nontemporal_load((const f32x4*)(pb + 4));
    const f32x4 c0 = __builtin_nontemporal_load((const f32x4*)(pb + 32));
    const f32x4 c1 = __builtin_nontemporal_load((const f32x4*)(pb + 36));

    const unsigned short* Pu = (const unsigned short*)P;
    unsigned short psv[4][4], pdv[4][4];
    #pragma unroll
    for (int ct = 0; ct < 4; ++ct)
        #pragma unroll
        for (int r = 0; r < 4; ++r) {
            psv[ct][r] = Pu[(size_t)s2[r] * 128 + ct * 16 + row];
            pdv[ct][r] = Pu[(size_t)d2[r] * 128 + 64 + ct * 16 + row];
        }
    __builtin_amdgcn_sched_barrier(0);   // pin: all loads issued before compute

    const short8b afr0 = pack8(a0, a1);
    const short8b afr1 = pack8(c0, c1);
    // stash bf16 ea tile for the residual epilogue (same-wave in-order)
    *(short8b*)&ea_s[w][row * 72 + kg * 8]      = afr0;
    *(short8b*)&ea_s[w][row * 72 + 32 + kg * 8] = afr1;

    // ---- GEMM1: ea part only, [16 x 64] @ W1_ea -> [16 x 64] (coalesced B) ----
    f32x4 acc[4];
    #pragma unroll
    for (int ct = 0; ct < 4; ++ct) {
        const float bvv = b1[ct * 16 + row];
        acc[ct] = (f32x4){bvv, bvv, bvv, bvv};
    }
    #pragma unroll
    for (int kc = 0; kc < 2; ++kc) {
        const short8b af = (kc == 0) ? afr0 : afr1;
        #pragma unroll
        for (int ct = 0; ct < 4; ++ct) {
            const short8b bfr = *(const short8b*)(W1eaf + (ct * 2 + kc) * 512 + l * 8);
            acc[ct] = __builtin_amdgcn_mfma_f32_16x16x32_bf16(af, bfr, acc[ct], 0, 0, 0);
        }
    }
    // add precomputed node projections
    #pragma unroll
    for (int ct = 0; ct < 4; ++ct)
        #pragma unroll
        for (int r = 0; r < 4; ++r)
            acc[ct][r] += bfraw(psv[ct][r]) + bfraw(pdv[ct][r]);

    // h2 = leaky(acc) -> wave-private LDS bounce (same-wave in-order)
    unsigned short* h2 = h2_s[w];
    #pragma unroll
    for (int ct = 0; ct < 4; ++ct)
        #pragma unroll
        for (int r = 0; r < 4; ++r)
            h2[(kg * 4 + r) * 72 + ct * 16 + row] = rawbf(leaky(acc[ct][r]));

    // ---- GEMM2: [16 x 64] @ W2 -> [16 x 64] (coalesced B) ----
    f32x4 a2[4];
    #pragma unroll
    for (int ct = 0; ct < 4; ++ct) {
        const float bvv = b2[ct * 16 + row];
        a2[ct] = (f32x4){bvv, bvv, bvv, bvv};
    }
    #pragma unroll
    for (int kc = 0; kc < 2; ++kc) {
        const short8b af = *(const short8b*)&h2[row * 72 + kc * 32 + kg * 8];
        #pragma unroll
        for (int ct = 0; ct < 4; ++ct) {
            const short8b bfr = *(const short8b*)(W2Tf + (ct * 2 + kc) * 512 + l * 8);
            a2[ct] = __builtin_amdgcn_mfma_f32_16x16x32_bf16(af, bfr, a2[ct], 0, 0, 0);
        }
    }

    // epilogue: out = leaky(ea + h2@W2+b2); ea residual from LDS stash
    #pragma unroll
    for (int ct = 0; ct < 4; ++ct)
        #pragma unroll
        for (int r = 0; r < 4; ++r) {
            const float eav = bfraw(ea_s[w][(kg * 4 + r) * 72 + ct * 16 + row]);
            out_e[(size_t)eg2[r] * 64 + ct * 16 + row] = leaky(eav + a2[ct][r]);
        }
}

extern "C" void kernel_launch(void* const* d_in, const int* in_sizes, int n_in,
                              void* d_out, int out_size, void* d_ws, size_t ws_size,
                              hipStream_t stream)
{
    const float* x  = (const float*)d_in[0];
    const int*   ei = (const int*)d_in[1];
    const float* ea = (const float*)d_in[2];
    const float* Wq = (const float*)d_in[3];
    const float* bq = (const float*)d_in[4];
    const float* Wk = (const float*)d_in[5];
    const float* bk = (const float*)d_in[6];
    const float* Wv = (const float*)d_in[7];
    const float* bv = (const float*)d_in[8];
    const float* We = (const float*)d_in[9];
    const float* Ws = (const float*)d_in[10];
    const float* bs = (const float*)d_in[11];
    const float* W1 = (const float*)d_in[12];
    const float* b1 = (const float*)d_in[13];
    const float* W2 = (const float*)d_in[14];
    const float* b2 = (const float*)d_in[15];

    char* ws = (char*)d_ws;
    int*   flags  = (int*)ws;                       // 4 KB
    int*   ssort  = (int*)(ws + 4096);
    int*   dsort  = (int*)(ws + 1604096);
    int*   eids   = (int*)(ws + 3204096);
    int*   cursor = (int*)(ws + 4804096);           // end-pointers after kct
    bf16*  WeTf   = (bf16*)(ws + 5004096);          // 32 KB
    bf16*  W1sdf  = (bf16*)(ws + 5036864);          // 64 KB
    bf16*  W1eaf  = (bf16*)(ws + 5102400);          // 8 KB
    bf16*  W2Tf   = (bf16*)(ws + 5110592);          // 8 KB
    bf16*  WT4f   = (bf16*)(ws + 5118784);          // 512 KB
    bf16*  qb     = (bf16*)(ws + 5643072);
    bf16*  kb     = (bf16*)(ws + 31243072);
    bf16*  vb     = (bf16*)(ws + 56843072);
    bf16*  xnb    = (bf16*)(ws + 82443072);         // x_new bf16 (25.6 MB)
    bf16*  Pp     = (bf16*)(ws + 108100000);        // node projections (12.8 MB)

    float* out_x = (float*)d_out;
    float* out_e = out_x + (size_t)N_NODES * D_NODE;
    bf16*  skipb = (bf16*)out_e;   // bf16 skip staged in edge-out region

    hipMemsetAsync(cursor, 0, N_NODES * 4, stream);       // degree counters

    k0_detect<<<1, 64, 0, stream>>>(ei, flags);
    kcd_degree<<<(N_EDGES + 255) / 256, 256, 0, stream>>>(ei, flags, cursor);
    kcs_scan<<<1, 1024, 0, stream>>>(cursor);
    kct_scatter<<<(N_EDGES + 255) / 256, 256, 0, stream>>>(ei, flags, cursor, ssort, dsort, eids);

    kT_transpose<<<64, 256, 0, stream>>>(We, W1, W2, Wq, Wk, Wv, Ws,
                                         WeTf, W1sdf, W1eaf, W2Tf, WT4f);

    k1_node_mfma<<<(N_NODES + 63) / 64, 256, 0, stream>>>(
        x, WT4f, bq, bk, bv, bs, qb, kb, vb, skipb);

    k2_seg<<<N_NODES / SEG, 256, 0, stream>>>(
        ssort, dsort, eids, cursor, ea, WeTf, qb, kb, vb, skipb, out_x, xnb);

    k3b_nodeproj<<<(N_NODES + 63) / 64, 256, 0, stream>>>(xnb, W1sdf, Pp);

    k4_edge_mlp<<<N_EDGES / 64, 256, 0, stream>>>(
        ssort, dsort, eids, Pp, ea, W1eaf, b1, W2Tf, b2, out_e);
}